// Round 1
// baseline (985.191 us; speedup 1.0000x reference)
//
#include <hip/hip_runtime.h>
#include <math.h>

#define BB 512
#define TT 49
#define VV 34
#define FF 16
#define HH 64
#define WWIN 4
#define WW 46
#define BW (BB*WW)        /* 23552 */
#define TH3 (3*HH)        /* 192 */
#define TLA_G 8

/* workspace layout (float offsets) */
#define ENC_OFF    0ull
#define ENC_SZ     13647872ull            /* B*T*V*F */
#define MSG_OFF    (ENC_OFF + ENC_SZ)
#define MSG_SZ     12812288ull            /* BW*V*F */
#define CUM_OFF    (MSG_OFF + MSG_SZ)
#define CUM_SZ     852992ull              /* B*T*V */
#define LAST_OFF   (CUM_OFF + CUM_SZ)
#define MEANS_OFF  (LAST_OFF + CUM_SZ)
#define MEANS_SZ   17408ull               /* B*V */
#define MAX_OFF    (MEANS_OFF + MEANS_SZ)
/* ENC region reuse after k_tla: */
#define SOUT_OFF   0ull                   /* BW*F = 376832 */
#define XW1_OFF    376832ull              /* BW*192 */
#define G1_OFF     (XW1_OFF + 4521984ull)
#define XW2_OFF    (G1_OFF + 1507328ull)
#define G2_OFF     (XW2_OFF + 4521984ull) /* ends 12435456 < ENC_SZ */

/* ---------------- kernel 1: impute scan + global max + means ---------------- */
__global__ __launch_bounds__(256) void k_scan(
    const float* __restrict__ arr, const float* __restrict__ msk,
    const float* __restrict__ timeTB,
    float* __restrict__ cum, float* __restrict__ last,
    float* __restrict__ means, unsigned int* __restrict__ maxv) {
  int tid = blockIdx.x * 256 + threadIdx.x;     /* 0..17407, exact */
  int b = tid / VV, v = tid - b * VV;
  const int base = b * TT * VV + v;
  float x = arr[base];
  float c = 0.f, lm = 0.f, s = x;
  cum[base] = 0.f;
  last[base] = x;
  float tp = timeTB[b];                          /* time[0*B+b] */
  for (int t = 1; t < TT; ++t) {
    float tc = timeTB[t * BB + b];
    float d = tc - tp; tp = tc;
    int e = base + t * VV;
    float a = arr[e], m = msk[e];
    float miss = (m == 0.f) ? 1.f : 0.f;
    c = d + c * miss;                            /* resets at observations */
    x = (miss > 0.f) ? x : a;                    /* LOCF */
    cum[e] = c; last[e] = x;
    lm = fmaxf(lm, c);
    s += a;
  }
  means[tid] = s * (1.f / 49.f);
  #pragma unroll
  for (int off = 32; off; off >>= 1) lm = fmaxf(lm, __shfl_xor(lm, off));
  if ((threadIdx.x & 63) == 0) atomicMax(maxv, __float_as_uint(lm));  /* cum>=0 */
}

/* ---------------- kernel 2: impute finish + per-variable MLP encoder ---------------- */
__global__ __launch_bounds__(256) void k_enc(
    const float* __restrict__ arr, const float* __restrict__ msk,
    const float* __restrict__ cum, const float* __restrict__ last,
    const float* __restrict__ means, const unsigned int* __restrict__ maxv,
    const float* __restrict__ wdec, const float* __restrict__ bdec,
    const float* __restrict__ W1, const float* __restrict__ B1,
    const float* __restrict__ W2, const float* __restrict__ B2,
    float* __restrict__ enc) {
  __shared__ float w1s[VV * 2 * FF];
  __shared__ float b1s[VV * FF];
  __shared__ float w2s[VV * FF * FF];
  __shared__ float b2s[VV * FF];
  for (int i = threadIdx.x; i < VV * 2 * FF; i += 256) w1s[i] = W1[i];
  for (int i = threadIdx.x; i < VV * FF; i += 256) { b1s[i] = B1[i]; b2s[i] = B2[i]; }
  for (int i = threadIdx.x; i < VV * FF * FF; i += 256) w2s[i] = W2[i];
  __syncthreads();
  int e = blockIdx.x * 256 + threadIdx.x;        /* < 852992, exact grid */
  int v = e % VV;
  int bt = e / VV;
  int b = bt / TT;
  float inv = 1.f / __uint_as_float(*maxv);
  float cc = cum[e] * inv;
  float t = wdec[v] * cc + bdec[v];
  t = fminf(fmaxf(t, 0.f), 1000.f);
  float dec = expf(-t);
  float a = arr[e], m = msk[e];
  float xx = a * m + (1.f - m) * (dec * last[e] + (1.f - dec) * means[b * VV + v]);
  float h[FF];
  #pragma unroll
  for (int f = 0; f < FF; ++f) {
    float z = xx * w1s[(v * 2 + 0) * FF + f] + m * w1s[(v * 2 + 1) * FF + f] + b1s[v * FF + f];
    h[f] = fmaxf(z, 0.f);
  }
  float* dst = enc + (size_t)e * FF;
  #pragma unroll
  for (int g = 0; g < FF; ++g) {
    float acc = b2s[v * FF + g];
    #pragma unroll
    for (int f = 0; f < FF; ++f) acc += h[f] * w2s[(v * FF + f) * FF + g];
    dst[g] = acc;
  }
}

/* ---------------- kernel 3: time-lag attention + message passing ---------------- */
__global__ __launch_bounds__(256) void k_tla(
    const float* __restrict__ enc,
    const float* __restrict__ Wq, const float* __restrict__ bq,
    const float* __restrict__ Wk, const float* __restrict__ bk,
    const float* __restrict__ Wv, const float* __restrict__ bv,
    const float* __restrict__ adj, float* __restrict__ msg) {
  __shared__ float wall[3 * 256];
  __shared__ float ball[3 * 16];
  __shared__ float win_s[TLA_G][WWIN][FF];
  __shared__ float qkv[3][TLA_G][WWIN][FF];
  __shared__ float att_s[TLA_G][WWIN][WWIN];
  __shared__ float ao_s[TLA_G][VV][FF];
  __shared__ float pe4[WWIN][FF];
  const int tid = threadIdx.x;
  const int n0 = blockIdx.x * TLA_G;
  if (tid < WWIN * FF) {
    int l = tid >> 4, f = tid & 15;
    int f2 = f & ~1;
    float dv = expf(-logf(10000.f) * (float)f2 / (float)FF);
    float ang = (float)l * dv;
    pe4[l][f] = (f & 1) ? cosf(ang) : sinf(ang);
  }
  for (int v = 0; v < VV; ++v) {
    __syncthreads();    /* protects pe4 (first iter) and LDS reuse across v */
    for (int idx = tid; idx < 816 + TLA_G * WWIN * FF; idx += 256) {
      if (idx < 256) wall[idx] = Wq[v * 256 + idx];
      else if (idx < 512) wall[idx] = Wk[v * 256 + idx - 256];
      else if (idx < 768) wall[idx] = Wv[v * 256 + idx - 512];
      else if (idx < 816) {
        int r = idx - 768;
        ball[r] = (r < 16 ? bq[v * 16 + r] : r < 32 ? bk[v * 16 + r - 16] : bv[v * 16 + r - 32]);
      } else {
        int wi = idx - 816;
        int g = wi >> 6, l = (wi >> 4) & 3, f = wi & 15;
        int n = n0 + g, b = n / WW, w = n - b * WW;
        win_s[g][l][f] = enc[(size_t)((b * TT + w + l) * VV + v) * FF + f] + pe4[l][f];
      }
    }
    __syncthreads();
    for (int idx = tid; idx < 3 * TLA_G * WWIN * FF; idx += 256) {
      int which = idx >> 9;
      int r = idx & 511;
      int g = r >> 6, l = (r >> 4) & 3, f = r & 15;
      float acc = ball[which * 16 + f];
      #pragma unroll
      for (int i = 0; i < FF; ++i) acc += win_s[g][l][i] * wall[which * 256 + i * 16 + f];
      qkv[which][g][l][f] = acc;
    }
    __syncthreads();
    if (tid < TLA_G * WWIN) {
      int g = tid >> 2, l = tid & 3;
      float scv[4];
      #pragma unroll
      for (int m = 0; m < 4; ++m) {
        float s = 0.f;
        #pragma unroll
        for (int i = 0; i < FF; ++i) s += qkv[0][g][l][i] * qkv[1][g][m][i];
        scv[m] = s * 0.25f;     /* 1/sqrt(16) */
      }
      float mx = fmaxf(fmaxf(scv[0], scv[1]), fmaxf(scv[2], scv[3]));
      float sum = 0.f;
      #pragma unroll
      for (int m = 0; m < 4; ++m) { scv[m] = expf(scv[m] - mx); sum += scv[m]; }
      float r = 1.f / sum;
      #pragma unroll
      for (int m = 0; m < 4; ++m) att_s[g][l][m] = scv[m] * r;
    }
    __syncthreads();
    if (tid < TLA_G * FF) {
      int g = tid >> 4, f = tid & 15;
      float o = 0.f;
      #pragma unroll
      for (int m = 0; m < 4; ++m) {
        float csm = att_s[g][0][m] + att_s[g][1][m] + att_s[g][2][m] + att_s[g][3][m];
        o += csm * qkv[2][g][m][f];
      }
      ao_s[g][v][f] = o;
    }
  }
  __syncthreads();
  for (int idx = tid; idx < TLA_G * VV * FF; idx += 256) {
    int g = idx / (VV * FF);
    int r = idx - g * VV * FF;
    int u = r >> 4;
    float acc = 0.f;
    for (int v2 = 0; v2 < VV; ++v2) acc += adj[u * VV + v2] * ao_s[g][v2][r & 15];
    msg[(size_t)(n0 + g) * (VV * FF) + r] = acc;
  }
}

/* ---------------- kernel 4: signal attention (faithful scrambled reshape) ---------------- */
__global__ __launch_bounds__(256) void k_sa(
    const float* __restrict__ msg,
    const float* __restrict__ Wq, const float* __restrict__ bq,
    const float* __restrict__ Wk, const float* __restrict__ bk,
    const float* __restrict__ Wv, const float* __restrict__ bv,
    float* __restrict__ sout) {
  __shared__ float wall[768];
  __shared__ float ball[48];
  __shared__ float xs[VV][FF];
  __shared__ float QKVs[3][VV][17];   /* pad 17 to break stride-16 conflicts */
  __shared__ float sc[VV][VV];
  __shared__ float csum[VV];
  const int tid = threadIdx.x;
  const int n = blockIdx.x;
  for (int idx = tid; idx < 816 + VV * FF; idx += 256) {
    if (idx < 256) wall[idx] = Wq[idx];
    else if (idx < 512) wall[idx] = Wk[idx - 256];
    else if (idx < 768) wall[idx] = Wv[idx - 512];
    else if (idx < 816) {
      int r = idx - 768;
      ball[r] = (r < 16 ? bq[r] : r < 32 ? bk[r - 16] : bv[r - 32]);
    } else {
      int wi = idx - 816;                /* < 544 */
      int v2 = wi >> 4, f = wi & 15;
      int j = n * VV + v2;
      int b = j / (VV * WW);
      int rem = j - b * (VV * WW);
      int vv2 = rem / WW;
      int w = rem - vv2 * WW;
      int f2 = f & ~1;
      float dv = expf(-logf(10000.f) * (float)f2 / (float)FF);
      float ang = (float)vv2 * dv;
      float pe = (f & 1) ? cosf(ang) : sinf(ang);
      xs[v2][f] = msg[(size_t)((b * WW + w) * VV + vv2) * FF + f] + pe;
    }
  }
  __syncthreads();
  for (int idx = tid; idx < 3 * VV * FF; idx += 256) {
    int which = idx / (VV * FF);
    int r = idx - which * (VV * FF);
    int m = r >> 4, f = r & 15;
    float acc = ball[which * 16 + f];
    #pragma unroll
    for (int i = 0; i < FF; ++i) acc += xs[m][i] * wall[which * 256 + i * 16 + f];
    QKVs[which][m][f] = acc;
  }
  __syncthreads();
  for (int idx = tid; idx < VV * VV; idx += 256) {
    int l = idx / VV, m = idx - (idx / VV) * VV;
    float s = 0.f;
    #pragma unroll
    for (int i = 0; i < FF; ++i) s += QKVs[0][l][i] * QKVs[1][m][i];
    sc[l][m] = s * 0.25f;
  }
  __syncthreads();
  if (tid < VV) {
    float mx = -1e30f;
    for (int m = 0; m < VV; ++m) mx = fmaxf(mx, sc[tid][m]);
    float sum = 0.f;
    for (int m = 0; m < VV; ++m) { float e = expf(sc[tid][m] - mx); sc[tid][m] = e; sum += e; }
    float r = 1.f / sum;
    for (int m = 0; m < VV; ++m) sc[tid][m] *= r;
  }
  __syncthreads();
  if (tid < VV) {
    float s = 0.f;
    for (int l = 0; l < VV; ++l) s += sc[l][tid];
    csum[tid] = s;
  }
  __syncthreads();
  if (tid < FF) {
    float acc = 0.f;
    for (int m = 0; m < VV; ++m) acc += csum[m] * QKVs[2][m][tid];
    sout[(size_t)n * FF + tid] = acc;
  }
}

/* ---------------- GRU input projections ---------------- */
__global__ __launch_bounds__(256) void k_xw1(
    const float* __restrict__ x, const float* __restrict__ Wih,
    const float* __restrict__ bih, float* __restrict__ xw) {
  int t = blockIdx.x * 256 + threadIdx.x;        /* < BW*192, exact */
  int n = t / TH3, o = t - n * TH3;
  float acc = bih[o];
  const float* xr = x + (size_t)n * FF;
  #pragma unroll
  for (int i = 0; i < FF; ++i) acc += xr[i] * Wih[i * TH3 + o];
  xw[t] = acc;
}

__global__ __launch_bounds__(192) void k_xw2(
    const float* __restrict__ x, const float* __restrict__ Wih,
    const float* __restrict__ bih, float* __restrict__ xw) {
  __shared__ float xsh[16][HH];
  int n0 = blockIdx.x * 16;
  int tid = threadIdx.x;
  for (int idx = tid; idx < 16 * HH; idx += 192) {
    int ns = idx >> 6, i = idx & 63;
    xsh[ns][i] = x[(size_t)(n0 + ns) * HH + i];
  }
  __syncthreads();
  float acc[16];
  float bb = bih[tid];
  #pragma unroll
  for (int ns = 0; ns < 16; ++ns) acc[ns] = bb;
  for (int i = 0; i < HH; ++i) {
    float wv = Wih[i * TH3 + tid];
    #pragma unroll
    for (int ns = 0; ns < 16; ++ns) acc[ns] += xsh[ns][i] * wv;
  }
  #pragma unroll
  for (int ns = 0; ns < 16; ++ns) xw[(size_t)(n0 + ns) * TH3 + tid] = acc[ns];
}

/* ---------------- GRU serial scan (one block per batch) ---------------- */
__global__ __launch_bounds__(192) void k_gru(
    const float* __restrict__ xw, const float* __restrict__ Whh,
    const float* __restrict__ bhh, float* __restrict__ gout) {
  __shared__ float whh[HH * TH3];   /* 49 KB */
  __shared__ float hsh[HH];
  __shared__ float gh[TH3];
  int tid = threadIdx.x;
  int b = blockIdx.x;
  for (int i = tid; i < HH * TH3; i += 192) whh[i] = Whh[i];
  if (tid < HH) hsh[tid] = 0.f;
  float bb = bhh[tid];
  __syncthreads();
  for (int w = 0; w < WW; ++w) {
    float acc = bb;
    #pragma unroll 8
    for (int i = 0; i < HH; ++i) acc += hsh[i] * whh[i * TH3 + tid];
    gh[tid] = acc;
    __syncthreads();
    if (tid < HH) {
      const float* xr = xw + (size_t)(b * WW + w) * TH3;
      float r = 1.f / (1.f + expf(-(xr[tid] + gh[tid])));
      float z = 1.f / (1.f + expf(-(xr[HH + tid] + gh[HH + tid])));
      float nn = tanhf(xr[2 * HH + tid] + r * gh[2 * HH + tid]);
      float hn = (1.f - z) * nn + z * hsh[tid];
      hsh[tid] = hn;
      gout[(size_t)(b * WW + w) * HH + tid] = hn;
    }
    __syncthreads();
  }
}

/* ---------------- temporal attention + classifier ---------------- */
__global__ __launch_bounds__(256) void k_ta(
    const float* __restrict__ g2,
    const float* __restrict__ Wq, const float* __restrict__ bq,
    const float* __restrict__ Wk, const float* __restrict__ bk,
    const float* __restrict__ Wv, const float* __restrict__ bv,
    const float* __restrict__ cW1, const float* __restrict__ cb1,
    const float* __restrict__ cW2, const float* __restrict__ cb2,
    float* __restrict__ out) {
  __shared__ float xt[WW * 65];          /* pad 65 */
  __shared__ float QKVs[3][WW * 65];
  __shared__ float sc[WW * WW];
  __shared__ float cs[WW];
  __shared__ float tval[HH];
  __shared__ float hrelu[HH];
  int tid = threadIdx.x;
  int b = blockIdx.x;
  for (int idx = tid; idx < WW * HH; idx += 256) {
    int w = idx >> 6, d = idx & 63;
    int f2 = d & ~1;
    float dv = expf(-logf(10000.f) * (float)f2 / (float)HH);
    float ang = (float)w * dv;
    float pe = (d & 1) ? cosf(ang) : sinf(ang);
    xt[w * 65 + d] = g2[(size_t)(b * WW + w) * HH + d] + pe;
  }
  __syncthreads();
  if (tid < 192) {
    int which = tid >> 6, d = tid & 63;
    const float* Wt = which == 0 ? Wq : which == 1 ? Wk : Wv;
    float bias = (which == 0 ? bq : which == 1 ? bk : bv)[d];
    float col[HH];
    #pragma unroll
    for (int i = 0; i < HH; ++i) col[i] = Wt[i * HH + d];
    float* dst = &QKVs[which][0];
    for (int w = 0; w < WW; ++w) {
      float acc = bias;
      #pragma unroll
      for (int i = 0; i < HH; ++i) acc += xt[w * 65 + i] * col[i];
      dst[w * 65 + d] = acc;
    }
  }
  __syncthreads();
  for (int idx = tid; idx < WW * WW; idx += 256) {
    int l = idx / WW, m = idx - l * WW;
    float s = 0.f;
    #pragma unroll
    for (int i = 0; i < HH; ++i) s += QKVs[0][l * 65 + i] * QKVs[1][m * 65 + i];
    sc[idx] = s * 0.125f;                /* 1/sqrt(64) */
  }
  __syncthreads();
  if (tid < WW) {
    float mx = -1e30f;
    for (int m = 0; m < WW; ++m) mx = fmaxf(mx, sc[tid * WW + m]);
    float sum = 0.f;
    for (int m = 0; m < WW; ++m) { float e = expf(sc[tid * WW + m] - mx); sc[tid * WW + m] = e; sum += e; }
    float r = 1.f / sum;
    for (int m = 0; m < WW; ++m) sc[tid * WW + m] *= r;
  }
  __syncthreads();
  if (tid < WW) {
    float s = 0.f;
    for (int l = 0; l < WW; ++l) s += sc[l * WW + tid];
    cs[tid] = s;
  }
  __syncthreads();
  if (tid < HH) {
    float acc = 0.f;
    for (int m = 0; m < WW; ++m) acc += cs[m] * QKVs[2][m * 65 + tid];
    tval[tid] = acc;
  }
  __syncthreads();
  if (tid < HH) {
    float acc = cb1[tid];
    #pragma unroll
    for (int d = 0; d < HH; ++d) acc += tval[d] * cW1[d * HH + tid];
    hrelu[tid] = fmaxf(acc, 0.f);
  }
  __syncthreads();
  if (tid == 0) {
    float acc = cb2[0];
    for (int j = 0; j < HH; ++j) acc += hrelu[j] * cW2[j];
    out[b] = acc;
  }
}

extern "C" void kernel_launch(void* const* d_in, const int* in_sizes, int n_in,
                              void* d_out, int out_size, void* d_ws, size_t ws_size,
                              hipStream_t stream) {
  (void)in_sizes; (void)n_in; (void)out_size; (void)ws_size;
  const float* arr    = (const float*)d_in[0];
  const float* msk    = (const float*)d_in[1];
  const float* timeTB = (const float*)d_in[2];
  const float* wdec   = (const float*)d_in[3];
  const float* bdec   = (const float*)d_in[4];
  const float* encW1  = (const float*)d_in[5];
  const float* encB1  = (const float*)d_in[6];
  const float* encW2  = (const float*)d_in[7];
  const float* encB2  = (const float*)d_in[8];
  const float* tlaWq  = (const float*)d_in[9];
  const float* tlaBq  = (const float*)d_in[10];
  const float* tlaWk  = (const float*)d_in[11];
  const float* tlaBk  = (const float*)d_in[12];
  const float* tlaWv  = (const float*)d_in[13];
  const float* tlaBv  = (const float*)d_in[14];
  const float* adj    = (const float*)d_in[15];
  /* 16..19: mp_* — dead code in reference */
  const float* saWq   = (const float*)d_in[20];
  const float* saBq   = (const float*)d_in[21];
  const float* saWk   = (const float*)d_in[22];
  const float* saBk   = (const float*)d_in[23];
  const float* saWv   = (const float*)d_in[24];
  const float* saBv   = (const float*)d_in[25];
  const float* gWih0  = (const float*)d_in[26];
  const float* gWhh0  = (const float*)d_in[27];
  const float* gBih0  = (const float*)d_in[28];
  const float* gBhh0  = (const float*)d_in[29];
  const float* gWih1  = (const float*)d_in[30];
  const float* gWhh1  = (const float*)d_in[31];
  const float* gBih1  = (const float*)d_in[32];
  const float* gBhh1  = (const float*)d_in[33];
  const float* taWq   = (const float*)d_in[34];
  const float* taBq   = (const float*)d_in[35];
  const float* taWk   = (const float*)d_in[36];
  const float* taBk   = (const float*)d_in[37];
  const float* taWv   = (const float*)d_in[38];
  const float* taBv   = (const float*)d_in[39];
  const float* cW1    = (const float*)d_in[40];
  const float* cb1    = (const float*)d_in[41];
  const float* cW2    = (const float*)d_in[42];
  const float* cb2    = (const float*)d_in[43];
  float* out = (float*)d_out;
  float* ws  = (float*)d_ws;

  float* cum   = ws + CUM_OFF;
  float* last  = ws + LAST_OFF;
  float* means = ws + MEANS_OFF;
  unsigned int* maxv = (unsigned int*)(ws + MAX_OFF);
  float* enc   = ws + ENC_OFF;
  float* msg   = ws + MSG_OFF;
  float* sout  = ws + SOUT_OFF;
  float* xw1   = ws + XW1_OFF;
  float* g1    = ws + G1_OFF;
  float* xw2   = ws + XW2_OFF;
  float* g2    = ws + G2_OFF;

  hipMemsetAsync(maxv, 0, sizeof(unsigned int), stream);
  k_scan<<<68, 256, 0, stream>>>(arr, msk, timeTB, cum, last, means, maxv);
  k_enc<<<3332, 256, 0, stream>>>(arr, msk, cum, last, means, maxv,
                                  wdec, bdec, encW1, encB1, encW2, encB2, enc);
  k_tla<<<BW / TLA_G, 256, 0, stream>>>(enc, tlaWq, tlaBq, tlaWk, tlaBk,
                                        tlaWv, tlaBv, adj, msg);
  k_sa<<<BW, 256, 0, stream>>>(msg, saWq, saBq, saWk, saBk, saWv, saBv, sout);
  k_xw1<<<(BW * TH3) / 256, 256, 0, stream>>>(sout, gWih0, gBih0, xw1);
  k_gru<<<BB, 192, 0, stream>>>(xw1, gWhh0, gBhh0, g1);
  k_xw2<<<BW / 16, 192, 0, stream>>>(g1, gWih1, gBih1, xw2);
  k_gru<<<BB, 192, 0, stream>>>(xw2, gWhh1, gBhh1, g2);
  k_ta<<<BB, 256, 0, stream>>>(g2, taWq, taBq, taWk, taBk, taWv, taBv,
                               cW1, cb1, cW2, cb2, out);
}

// Round 2
// 629.430 us; speedup vs baseline: 1.5652x; 1.5652x over previous
//
#include <hip/hip_runtime.h>
#include <math.h>

#define BB 512
#define TT 49
#define VV 34
#define FF 16
#define HH 64
#define WWIN 4
#define WW 46
#define BW (BB*WW)        /* 23552 */
#define TH3 (3*HH)        /* 192 */
#define TLA_G 8
#define ROWS 25088        /* B*T */
#define PLANE (ROWS*16)   /* 401408 */

/* ---------------- old (fallback) workspace layout (float offsets) ---------------- */
#define ENC_OFF    0ull
#define ENC_SZ     13647872ull            /* B*T*V*F */
#define MSG_OFF    (ENC_OFF + ENC_SZ)
#define MSG_SZ     12812288ull            /* BW*V*F */
#define CUM_OFF    (MSG_OFF + MSG_SZ)
#define CUM_SZ     852992ull              /* B*T*V */
#define LAST_OFF   (CUM_OFF + CUM_SZ)
#define MEANS_OFF  (LAST_OFF + CUM_SZ)
#define MEANS_SZ   17408ull               /* B*V */
#define MAX_OFF    (MEANS_OFF + MEANS_SZ)
/* GRU-region reuse (both paths, region starts at 0): */
#define SOUT_OFF   0ull                   /* BW*F = 376832 */
#define XW1_OFF    376832ull              /* BW*192 */
#define G1_OFF     (XW1_OFF + 4521984ull)
#define XW2_OFF    (G1_OFF + 1507328ull)
#define G2_OFF     (XW2_OFF + 4521984ull) /* ends 12435456 */

/* ---------------- fast-path workspace layout ---------------- */
#define TENS       (34ull*PLANE)          /* 13,647,872 per eq/ek/ev tensor */
#define EQ_OFF     0ull
#define EK_OFF     TENS
#define EV_OFF     (2ull*TENS)
#define MSG2_OFF   (3ull*TENS)            /* 40,943,616 */
#define CUM2_OFF   (MSG2_OFF + MSG_SZ)    /* 53,755,904 */
#define LAST2_OFF  (CUM2_OFF + CUM_SZ)
#define MEANS2_OFF (LAST2_OFF + CUM_SZ)
#define MAX2_OFF   (MEANS2_OFF + MEANS_SZ)
#define PQ_OFF     (MAX2_OFF + 4ull)
#define WS_NEED    ((PQ_OFF + 6528ull) * 4ull)   /* ~222 MB */

/* ---------------- kernel 1: impute scan + global max + means ---------------- */
__global__ __launch_bounds__(256) void k_scan(
    const float* __restrict__ arr, const float* __restrict__ msk,
    const float* __restrict__ timeTB,
    float* __restrict__ cum, float* __restrict__ last,
    float* __restrict__ means, unsigned int* __restrict__ maxv) {
  int tid = blockIdx.x * 256 + threadIdx.x;     /* 0..17407, exact */
  int b = tid / VV, v = tid - b * VV;
  const int base = b * TT * VV + v;
  float x = arr[base];
  float c = 0.f, lm = 0.f, s = x;
  cum[base] = 0.f;
  last[base] = x;
  float tp = timeTB[b];
  for (int t = 1; t < TT; ++t) {
    float tc = timeTB[t * BB + b];
    float d = tc - tp; tp = tc;
    int e = base + t * VV;
    float a = arr[e], m = msk[e];
    float miss = (m == 0.f) ? 1.f : 0.f;
    c = d + c * miss;
    x = (miss > 0.f) ? x : a;
    cum[e] = c; last[e] = x;
    lm = fmaxf(lm, c);
    s += a;
  }
  means[tid] = s * (1.f / 49.f);
  #pragma unroll
  for (int off = 32; off; off >>= 1) lm = fmaxf(lm, __shfl_xor(lm, off));
  if ((threadIdx.x & 63) == 0) atomicMax(maxv, __float_as_uint(lm));
}

/* ---------------- fast path: PE projections pq/pk/pv[which][l][v][f] ---------------- */
__global__ __launch_bounds__(256) void k_pe(
    const float* __restrict__ Wq, const float* __restrict__ Wk,
    const float* __restrict__ Wv, float* __restrict__ pqg) {
  int idx = blockIdx.x * 256 + threadIdx.x;
  if (idx >= 6528) return;
  int which = idx / 2176;
  int r = idx - which * 2176;
  int l = r / 544;
  int rr = r - l * 544;
  int v = rr >> 4, f = rr & 15;
  const float* W = which == 0 ? Wq : which == 1 ? Wk : Wv;
  float acc = 0.f;
  #pragma unroll
  for (int i = 0; i < FF; ++i) {
    int i2 = i & ~1;
    float dv = expf(-logf(10000.f) * (float)i2 / (float)FF);
    float ang = (float)l * dv;
    float pe = (i & 1) ? cosf(ang) : sinf(ang);
    acc += pe * W[v * 256 + i * 16 + f];
  }
  pqg[idx] = acc;
}

/* ---------------- fast path: impute + encoder MLP + QKV projection fused ---------------- */
__global__ __launch_bounds__(256) void k_enc2(
    const float* __restrict__ arr, const float* __restrict__ msk,
    const float* __restrict__ cum, const float* __restrict__ last,
    const float* __restrict__ means, const unsigned int* __restrict__ maxv,
    const float* __restrict__ wdec, const float* __restrict__ bdec,
    const float* __restrict__ W1, const float* __restrict__ B1,
    const float* __restrict__ W2, const float* __restrict__ B2,
    const float* __restrict__ Wq, const float* __restrict__ Bq,
    const float* __restrict__ Wk, const float* __restrict__ Bk,
    const float* __restrict__ Wv, const float* __restrict__ Bv,
    float* __restrict__ eq, float* __restrict__ ek, float* __restrict__ ev) {
  __shared__ float w1s[32], b1s[16], w2s[256], b2s[16];
  __shared__ float wqs[256], wks[256], wvs[256], bqs[16], bks[16], bvs[16];
  const int v = blockIdx.x / 98;
  const int chunk = blockIdx.x - v * 98;
  const int tid = threadIdx.x;
  w2s[tid] = W2[v * 256 + tid];
  wqs[tid] = Wq[v * 256 + tid];
  wks[tid] = Wk[v * 256 + tid];
  wvs[tid] = Wv[v * 256 + tid];
  if (tid < 32) w1s[tid] = W1[v * 32 + tid];
  if (tid < 16) {
    b1s[tid] = B1[v * 16 + tid]; b2s[tid] = B2[v * 16 + tid];
    bqs[tid] = Bq[v * 16 + tid]; bks[tid] = Bk[v * 16 + tid]; bvs[tid] = Bv[v * 16 + tid];
  }
  __syncthreads();
  const int row = chunk * 256 + tid;            /* < 25088 exact */
  const int e = row * VV + v;
  const int b = row / TT;
  float inv = 1.f / __uint_as_float(*maxv);
  float cc = cum[e] * inv;
  float t = wdec[v] * cc + bdec[v];
  t = fminf(fmaxf(t, 0.f), 1000.f);
  float dec = expf(-t);
  float a = arr[e], m = msk[e];
  float xx = a * m + (1.f - m) * (dec * last[e] + (1.f - dec) * means[b * VV + v]);
  float h[FF];
  #pragma unroll
  for (int f = 0; f < FF; ++f)
    h[f] = fmaxf(xx * w1s[f] + m * w1s[16 + f] + b1s[f], 0.f);
  float er[FF];
  #pragma unroll
  for (int g = 0; g < FF; ++g) {
    float acc = b2s[g];
    #pragma unroll
    for (int f = 0; f < FF; ++f) acc += h[f] * w2s[f * 16 + g];
    er[g] = acc;
  }
  float qo[FF], ko[FF], vo[FF];
  #pragma unroll
  for (int f = 0; f < FF; ++f) {
    float aq = bqs[f], ak = bks[f], av = bvs[f];
    #pragma unroll
    for (int i = 0; i < FF; ++i) {
      float x2 = er[i];
      aq += x2 * wqs[i * 16 + f];
      ak += x2 * wks[i * 16 + f];
      av += x2 * wvs[i * 16 + f];
    }
    qo[f] = aq; ko[f] = ak; vo[f] = av;
  }
  size_t base = ((size_t)v * ROWS + row) * 16;
  float4* dq = (float4*)(eq + base);
  float4* dk = (float4*)(ek + base);
  float4* dv4 = (float4*)(ev + base);
  #pragma unroll
  for (int j = 0; j < 4; ++j) {
    dq[j] = make_float4(qo[4*j], qo[4*j+1], qo[4*j+2], qo[4*j+3]);
    dk[j] = make_float4(ko[4*j], ko[4*j+1], ko[4*j+2], ko[4*j+3]);
    dv4[j] = make_float4(vo[4*j], vo[4*j+1], vo[4*j+2], vo[4*j+3]);
  }
}

/* ---------------- fast path: windowed 4x4 attention + message passing ---------------- */
__global__ __launch_bounds__(256) void k_att(
    const float* __restrict__ eq, const float* __restrict__ ek,
    const float* __restrict__ ev, const float* __restrict__ pqg,
    const float* __restrict__ adj, float* __restrict__ msg) {
  __shared__ float pqs[3][4][578];   /* [which][l][v*17+f] padded */
  __shared__ float adjs[VV * VV];
  __shared__ float ao[7][578];       /* [g][v*17+f] */
  const int tid = threadIdx.x;
  for (int i = tid; i < 6528; i += 256) {
    int which = i / 2176;
    int r = i - which * 2176;
    int l = r / 544;
    int rr = r - l * 544;
    pqs[which][l][(rr >> 4) * 17 + (rr & 15)] = pqg[i];
  }
  for (int i = tid; i < VV * VV; i += 256) adjs[i] = adj[i];
  __syncthreads();
  const int g = tid / 34, v = tid - g * 34;
  const int n = blockIdx.x * 7 + g;
  if (g < 7 && n < BW) {
    int b = n / WW, w = n - b * WW;
    int row0 = b * TT + w;
    size_t base = ((size_t)v * ROWS + row0) * 16;
    const float* ekp = ek + base;
    float kk[4][16];
    #pragma unroll
    for (int m = 0; m < 4; ++m)
      #pragma unroll
      for (int f = 0; f < FF; ++f) kk[m][f] = ekp[m * 16 + f] + pqs[1][m][v * 17 + f];
    float sc[4][4];
    const float* eqp = eq + base;
    #pragma unroll
    for (int l = 0; l < 4; ++l) {
      float qv[16];
      #pragma unroll
      for (int f = 0; f < FF; ++f) qv[f] = eqp[l * 16 + f] + pqs[0][l][v * 17 + f];
      #pragma unroll
      for (int m = 0; m < 4; ++m) {
        float s = 0.f;
        #pragma unroll
        for (int f = 0; f < FF; ++f) s += qv[f] * kk[m][f];
        sc[l][m] = s * 0.25f;
      }
    }
    float csum[4] = {0.f, 0.f, 0.f, 0.f};
    #pragma unroll
    for (int l = 0; l < 4; ++l) {
      float mx = fmaxf(fmaxf(sc[l][0], sc[l][1]), fmaxf(sc[l][2], sc[l][3]));
      float sum = 0.f;
      #pragma unroll
      for (int m = 0; m < 4; ++m) { sc[l][m] = expf(sc[l][m] - mx); sum += sc[l][m]; }
      float r = 1.f / sum;
      #pragma unroll
      for (int m = 0; m < 4; ++m) csum[m] += sc[l][m] * r;
    }
    float outv[16];
    #pragma unroll
    for (int f = 0; f < FF; ++f) outv[f] = 0.f;
    const float* evp = ev + base;
    #pragma unroll
    for (int m = 0; m < 4; ++m) {
      float c = csum[m];
      #pragma unroll
      for (int f = 0; f < FF; ++f) outv[f] += c * (evp[m * 16 + f] + pqs[2][m][v * 17 + f]);
    }
    #pragma unroll
    for (int f = 0; f < FF; ++f) ao[g][v * 17 + f] = outv[f];
  }
  __syncthreads();
  for (int i = tid; i < 7 * 544; i += 256) {
    int g2 = i / 544, r = i - g2 * 544;
    int n2 = blockIdx.x * 7 + g2;
    if (n2 >= BW) continue;
    int u = r >> 4, f = r & 15;
    float acc = 0.f;
    for (int v2 = 0; v2 < VV; ++v2) acc += adjs[u * VV + v2] * ao[g2][v2 * 17 + f];
    msg[(size_t)n2 * (VV * FF) + r] = acc;
  }
}

/* ---------------- OLD fallback kernels (round-1) ---------------- */
__global__ __launch_bounds__(256) void k_enc(
    const float* __restrict__ arr, const float* __restrict__ msk,
    const float* __restrict__ cum, const float* __restrict__ last,
    const float* __restrict__ means, const unsigned int* __restrict__ maxv,
    const float* __restrict__ wdec, const float* __restrict__ bdec,
    const float* __restrict__ W1, const float* __restrict__ B1,
    const float* __restrict__ W2, const float* __restrict__ B2,
    float* __restrict__ enc) {
  __shared__ float w1s[VV * 2 * FF];
  __shared__ float b1s[VV * FF];
  __shared__ float w2s[VV * FF * FF];
  __shared__ float b2s[VV * FF];
  for (int i = threadIdx.x; i < VV * 2 * FF; i += 256) w1s[i] = W1[i];
  for (int i = threadIdx.x; i < VV * FF; i += 256) { b1s[i] = B1[i]; b2s[i] = B2[i]; }
  for (int i = threadIdx.x; i < VV * FF * FF; i += 256) w2s[i] = W2[i];
  __syncthreads();
  int e = blockIdx.x * 256 + threadIdx.x;
  int v = e % VV;
  int bt = e / VV;
  int b = bt / TT;
  float inv = 1.f / __uint_as_float(*maxv);
  float cc = cum[e] * inv;
  float t = wdec[v] * cc + bdec[v];
  t = fminf(fmaxf(t, 0.f), 1000.f);
  float dec = expf(-t);
  float a = arr[e], m = msk[e];
  float xx = a * m + (1.f - m) * (dec * last[e] + (1.f - dec) * means[b * VV + v]);
  float h[FF];
  #pragma unroll
  for (int f = 0; f < FF; ++f) {
    float z = xx * w1s[(v * 2 + 0) * FF + f] + m * w1s[(v * 2 + 1) * FF + f] + b1s[v * FF + f];
    h[f] = fmaxf(z, 0.f);
  }
  float* dst = enc + (size_t)e * FF;
  #pragma unroll
  for (int g = 0; g < FF; ++g) {
    float acc = b2s[v * FF + g];
    #pragma unroll
    for (int f = 0; f < FF; ++f) acc += h[f] * w2s[(v * FF + f) * FF + g];
    dst[g] = acc;
  }
}

__global__ __launch_bounds__(256) void k_tla(
    const float* __restrict__ enc,
    const float* __restrict__ Wq, const float* __restrict__ bq,
    const float* __restrict__ Wk, const float* __restrict__ bk,
    const float* __restrict__ Wv, const float* __restrict__ bv,
    const float* __restrict__ adj, float* __restrict__ msg) {
  __shared__ float wall[3 * 256];
  __shared__ float ball[3 * 16];
  __shared__ float win_s[TLA_G][WWIN][FF];
  __shared__ float qkv[3][TLA_G][WWIN][FF];
  __shared__ float att_s[TLA_G][WWIN][WWIN];
  __shared__ float ao_s[TLA_G][VV][FF];
  __shared__ float pe4[WWIN][FF];
  const int tid = threadIdx.x;
  const int n0 = blockIdx.x * TLA_G;
  if (tid < WWIN * FF) {
    int l = tid >> 4, f = tid & 15;
    int f2 = f & ~1;
    float dv = expf(-logf(10000.f) * (float)f2 / (float)FF);
    float ang = (float)l * dv;
    pe4[l][f] = (f & 1) ? cosf(ang) : sinf(ang);
  }
  for (int v = 0; v < VV; ++v) {
    __syncthreads();
    for (int idx = tid; idx < 816 + TLA_G * WWIN * FF; idx += 256) {
      if (idx < 256) wall[idx] = Wq[v * 256 + idx];
      else if (idx < 512) wall[idx] = Wk[v * 256 + idx - 256];
      else if (idx < 768) wall[idx] = Wv[v * 256 + idx - 512];
      else if (idx < 816) {
        int r = idx - 768;
        ball[r] = (r < 16 ? bq[v * 16 + r] : r < 32 ? bk[v * 16 + r - 16] : bv[v * 16 + r - 32]);
      } else {
        int wi = idx - 816;
        int g = wi >> 6, l = (wi >> 4) & 3, f = wi & 15;
        int n = n0 + g, b = n / WW, w = n - b * WW;
        win_s[g][l][f] = enc[(size_t)((b * TT + w + l) * VV + v) * FF + f] + pe4[l][f];
      }
    }
    __syncthreads();
    for (int idx = tid; idx < 3 * TLA_G * WWIN * FF; idx += 256) {
      int which = idx >> 9;
      int r = idx & 511;
      int g = r >> 6, l = (r >> 4) & 3, f = r & 15;
      float acc = ball[which * 16 + f];
      #pragma unroll
      for (int i = 0; i < FF; ++i) acc += win_s[g][l][i] * wall[which * 256 + i * 16 + f];
      qkv[which][g][l][f] = acc;
    }
    __syncthreads();
    if (tid < TLA_G * WWIN) {
      int g = tid >> 2, l = tid & 3;
      float scv[4];
      #pragma unroll
      for (int m = 0; m < 4; ++m) {
        float s = 0.f;
        #pragma unroll
        for (int i = 0; i < FF; ++i) s += qkv[0][g][l][i] * qkv[1][g][m][i];
        scv[m] = s * 0.25f;
      }
      float mx = fmaxf(fmaxf(scv[0], scv[1]), fmaxf(scv[2], scv[3]));
      float sum = 0.f;
      #pragma unroll
      for (int m = 0; m < 4; ++m) { scv[m] = expf(scv[m] - mx); sum += scv[m]; }
      float r = 1.f / sum;
      #pragma unroll
      for (int m = 0; m < 4; ++m) att_s[g][l][m] = scv[m] * r;
    }
    __syncthreads();
    if (tid < TLA_G * FF) {
      int g = tid >> 4, f = tid & 15;
      float o = 0.f;
      #pragma unroll
      for (int m = 0; m < 4; ++m) {
        float csm = att_s[g][0][m] + att_s[g][1][m] + att_s[g][2][m] + att_s[g][3][m];
        o += csm * qkv[2][g][m][f];
      }
      ao_s[g][v][f] = o;
    }
  }
  __syncthreads();
  for (int idx = tid; idx < TLA_G * VV * FF; idx += 256) {
    int g = idx / (VV * FF);
    int r = idx - g * VV * FF;
    int u = r >> 4;
    float acc = 0.f;
    for (int v2 = 0; v2 < VV; ++v2) acc += adj[u * VV + v2] * ao_s[g][v2][r & 15];
    msg[(size_t)(n0 + g) * (VV * FF) + r] = acc;
  }
}

/* ---------------- kernel 4: signal attention ---------------- */
__global__ __launch_bounds__(256) void k_sa(
    const float* __restrict__ msg,
    const float* __restrict__ Wq, const float* __restrict__ bq,
    const float* __restrict__ Wk, const float* __restrict__ bk,
    const float* __restrict__ Wv, const float* __restrict__ bv,
    float* __restrict__ sout) {
  __shared__ float wall[768];
  __shared__ float ball[48];
  __shared__ float xs[VV][FF];
  __shared__ float QKVs[3][VV][17];
  __shared__ float sc[VV][VV];
  __shared__ float csum[VV];
  const int tid = threadIdx.x;
  const int n = blockIdx.x;
  for (int idx = tid; idx < 816 + VV * FF; idx += 256) {
    if (idx < 256) wall[idx] = Wq[idx];
    else if (idx < 512) wall[idx] = Wk[idx - 256];
    else if (idx < 768) wall[idx] = Wv[idx - 512];
    else if (idx < 816) {
      int r = idx - 768;
      ball[r] = (r < 16 ? bq[r] : r < 32 ? bk[r - 16] : bv[r - 32]);
    } else {
      int wi = idx - 816;
      int v2 = wi >> 4, f = wi & 15;
      int j = n * VV + v2;
      int b = j / (VV * WW);
      int rem = j - b * (VV * WW);
      int vv2 = rem / WW;
      int w = rem - vv2 * WW;
      int f2 = f & ~1;
      float dv = expf(-logf(10000.f) * (float)f2 / (float)FF);
      float ang = (float)vv2 * dv;
      float pe = (f & 1) ? cosf(ang) : sinf(ang);
      xs[v2][f] = msg[(size_t)((b * WW + w) * VV + vv2) * FF + f] + pe;
    }
  }
  __syncthreads();
  for (int idx = tid; idx < 3 * VV * FF; idx += 256) {
    int which = idx / (VV * FF);
    int r = idx - which * (VV * FF);
    int m = r >> 4, f = r & 15;
    float acc = ball[which * 16 + f];
    #pragma unroll
    for (int i = 0; i < FF; ++i) acc += xs[m][i] * wall[which * 256 + i * 16 + f];
    QKVs[which][m][f] = acc;
  }
  __syncthreads();
  for (int idx = tid; idx < VV * VV; idx += 256) {
    int l = idx / VV, m = idx - (idx / VV) * VV;
    float s = 0.f;
    #pragma unroll
    for (int i = 0; i < FF; ++i) s += QKVs[0][l][i] * QKVs[1][m][i];
    sc[l][m] = s * 0.25f;
  }
  __syncthreads();
  if (tid < VV) {
    float mx = -1e30f;
    for (int m = 0; m < VV; ++m) mx = fmaxf(mx, sc[tid][m]);
    float sum = 0.f;
    for (int m = 0; m < VV; ++m) { float e = expf(sc[tid][m] - mx); sc[tid][m] = e; sum += e; }
    float r = 1.f / sum;
    for (int m = 0; m < VV; ++m) sc[tid][m] *= r;
  }
  __syncthreads();
  if (tid < VV) {
    float s = 0.f;
    for (int l = 0; l < VV; ++l) s += sc[l][tid];
    csum[tid] = s;
  }
  __syncthreads();
  if (tid < FF) {
    float acc = 0.f;
    for (int m = 0; m < VV; ++m) acc += csum[m] * QKVs[2][m][tid];
    sout[(size_t)n * FF + tid] = acc;
  }
}

/* ---------------- GRU input projections ---------------- */
__global__ __launch_bounds__(256) void k_xw1(
    const float* __restrict__ x, const float* __restrict__ Wih,
    const float* __restrict__ bih, float* __restrict__ xw) {
  int t = blockIdx.x * 256 + threadIdx.x;
  int n = t / TH3, o = t - n * TH3;
  float acc = bih[o];
  const float* xr = x + (size_t)n * FF;
  #pragma unroll
  for (int i = 0; i < FF; ++i) acc += xr[i] * Wih[i * TH3 + o];
  xw[t] = acc;
}

__global__ __launch_bounds__(192) void k_xw2(
    const float* __restrict__ x, const float* __restrict__ Wih,
    const float* __restrict__ bih, float* __restrict__ xw) {
  __shared__ float xsh[16][HH];
  int n0 = blockIdx.x * 16;
  int tid = threadIdx.x;
  for (int idx = tid; idx < 16 * HH; idx += 192) {
    int ns = idx >> 6, i = idx & 63;
    xsh[ns][i] = x[(size_t)(n0 + ns) * HH + i];
  }
  __syncthreads();
  float acc[16];
  float bb = bih[tid];
  #pragma unroll
  for (int ns = 0; ns < 16; ++ns) acc[ns] = bb;
  for (int i = 0; i < HH; ++i) {
    float wv = Wih[i * TH3 + tid];
    #pragma unroll
    for (int ns = 0; ns < 16; ++ns) acc[ns] += xsh[ns][i] * wv;
  }
  #pragma unroll
  for (int ns = 0; ns < 16; ++ns) xw[(size_t)(n0 + ns) * TH3 + tid] = acc[ns];
}

/* ---------------- GRU serial scan ---------------- */
__global__ __launch_bounds__(192) void k_gru(
    const float* __restrict__ xw, const float* __restrict__ Whh,
    const float* __restrict__ bhh, float* __restrict__ gout) {
  __shared__ float whh[HH * TH3];
  __shared__ float hsh[HH];
  __shared__ float gh[TH3];
  int tid = threadIdx.x;
  int b = blockIdx.x;
  for (int i = tid; i < HH * TH3; i += 192) whh[i] = Whh[i];
  if (tid < HH) hsh[tid] = 0.f;
  float bb = bhh[tid];
  __syncthreads();
  for (int w = 0; w < WW; ++w) {
    float acc = bb;
    #pragma unroll 8
    for (int i = 0; i < HH; ++i) acc += hsh[i] * whh[i * TH3 + tid];
    gh[tid] = acc;
    __syncthreads();
    if (tid < HH) {
      const float* xr = xw + (size_t)(b * WW + w) * TH3;
      float r = 1.f / (1.f + expf(-(xr[tid] + gh[tid])));
      float z = 1.f / (1.f + expf(-(xr[HH + tid] + gh[HH + tid])));
      float nn = tanhf(xr[2 * HH + tid] + r * gh[2 * HH + tid]);
      float hn = (1.f - z) * nn + z * hsh[tid];
      hsh[tid] = hn;
      gout[(size_t)(b * WW + w) * HH + tid] = hn;
    }
    __syncthreads();
  }
}

/* ---------------- temporal attention + classifier ---------------- */
__global__ __launch_bounds__(256) void k_ta(
    const float* __restrict__ g2,
    const float* __restrict__ Wq, const float* __restrict__ bq,
    const float* __restrict__ Wk, const float* __restrict__ bk,
    const float* __restrict__ Wv, const float* __restrict__ bv,
    const float* __restrict__ cW1, const float* __restrict__ cb1,
    const float* __restrict__ cW2, const float* __restrict__ cb2,
    float* __restrict__ out) {
  __shared__ float xt[WW * 65];
  __shared__ float QKVs[3][WW * 65];
  __shared__ float sc[WW * WW];
  __shared__ float cs[WW];
  __shared__ float tval[HH];
  __shared__ float hrelu[HH];
  int tid = threadIdx.x;
  int b = blockIdx.x;
  for (int idx = tid; idx < WW * HH; idx += 256) {
    int w = idx >> 6, d = idx & 63;
    int f2 = d & ~1;
    float dv = expf(-logf(10000.f) * (float)f2 / (float)HH);
    float ang = (float)w * dv;
    float pe = (d & 1) ? cosf(ang) : sinf(ang);
    xt[w * 65 + d] = g2[(size_t)(b * WW + w) * HH + d] + pe;
  }
  __syncthreads();
  if (tid < 192) {
    int which = tid >> 6, d = tid & 63;
    const float* Wt = which == 0 ? Wq : which == 1 ? Wk : Wv;
    float bias = (which == 0 ? bq : which == 1 ? bk : bv)[d];
    float col[HH];
    #pragma unroll
    for (int i = 0; i < HH; ++i) col[i] = Wt[i * HH + d];
    float* dst = &QKVs[which][0];
    for (int w = 0; w < WW; ++w) {
      float acc = bias;
      #pragma unroll
      for (int i = 0; i < HH; ++i) acc += xt[w * 65 + i] * col[i];
      dst[w * 65 + d] = acc;
    }
  }
  __syncthreads();
  for (int idx = tid; idx < WW * WW; idx += 256) {
    int l = idx / WW, m = idx - l * WW;
    float s = 0.f;
    #pragma unroll
    for (int i = 0; i < HH; ++i) s += QKVs[0][l * 65 + i] * QKVs[1][m * 65 + i];
    sc[idx] = s * 0.125f;
  }
  __syncthreads();
  if (tid < WW) {
    float mx = -1e30f;
    for (int m = 0; m < WW; ++m) mx = fmaxf(mx, sc[tid * WW + m]);
    float sum = 0.f;
    for (int m = 0; m < WW; ++m) { float e = expf(sc[tid * WW + m] - mx); sc[tid * WW + m] = e; sum += e; }
    float r = 1.f / sum;
    for (int m = 0; m < WW; ++m) sc[tid * WW + m] *= r;
  }
  __syncthreads();
  if (tid < WW) {
    float s = 0.f;
    for (int l = 0; l < WW; ++l) s += sc[l * WW + tid];
    cs[tid] = s;
  }
  __syncthreads();
  if (tid < HH) {
    float acc = 0.f;
    for (int m = 0; m < WW; ++m) acc += cs[m] * QKVs[2][m * 65 + tid];
    tval[tid] = acc;
  }
  __syncthreads();
  if (tid < HH) {
    float acc = cb1[tid];
    #pragma unroll
    for (int d = 0; d < HH; ++d) acc += tval[d] * cW1[d * HH + tid];
    hrelu[tid] = fmaxf(acc, 0.f);
  }
  __syncthreads();
  if (tid == 0) {
    float acc = cb2[0];
    for (int j = 0; j < HH; ++j) acc += hrelu[j] * cW2[j];
    out[b] = acc;
  }
}

extern "C" void kernel_launch(void* const* d_in, const int* in_sizes, int n_in,
                              void* d_out, int out_size, void* d_ws, size_t ws_size,
                              hipStream_t stream) {
  (void)in_sizes; (void)n_in; (void)out_size;
  const float* arr    = (const float*)d_in[0];
  const float* msk    = (const float*)d_in[1];
  const float* timeTB = (const float*)d_in[2];
  const float* wdec   = (const float*)d_in[3];
  const float* bdec   = (const float*)d_in[4];
  const float* encW1  = (const float*)d_in[5];
  const float* encB1  = (const float*)d_in[6];
  const float* encW2  = (const float*)d_in[7];
  const float* encB2  = (const float*)d_in[8];
  const float* tlaWq  = (const float*)d_in[9];
  const float* tlaBq  = (const float*)d_in[10];
  const float* tlaWk  = (const float*)d_in[11];
  const float* tlaBk  = (const float*)d_in[12];
  const float* tlaWv  = (const float*)d_in[13];
  const float* tlaBv  = (const float*)d_in[14];
  const float* adj    = (const float*)d_in[15];
  const float* saWq   = (const float*)d_in[20];
  const float* saBq   = (const float*)d_in[21];
  const float* saWk   = (const float*)d_in[22];
  const float* saBk   = (const float*)d_in[23];
  const float* saWv   = (const float*)d_in[24];
  const float* saBv   = (const float*)d_in[25];
  const float* gWih0  = (const float*)d_in[26];
  const float* gWhh0  = (const float*)d_in[27];
  const float* gBih0  = (const float*)d_in[28];
  const float* gBhh0  = (const float*)d_in[29];
  const float* gWih1  = (const float*)d_in[30];
  const float* gWhh1  = (const float*)d_in[31];
  const float* gBih1  = (const float*)d_in[32];
  const float* gBhh1  = (const float*)d_in[33];
  const float* taWq   = (const float*)d_in[34];
  const float* taBq   = (const float*)d_in[35];
  const float* taWk   = (const float*)d_in[36];
  const float* taBk   = (const float*)d_in[37];
  const float* taWv   = (const float*)d_in[38];
  const float* taBv   = (const float*)d_in[39];
  const float* cW1    = (const float*)d_in[40];
  const float* cb1    = (const float*)d_in[41];
  const float* cW2    = (const float*)d_in[42];
  const float* cb2    = (const float*)d_in[43];
  float* out = (float*)d_out;
  float* ws  = (float*)d_ws;

  float* sout = ws + SOUT_OFF;
  float* xw1  = ws + XW1_OFF;
  float* g1   = ws + G1_OFF;
  float* xw2  = ws + XW2_OFF;
  float* g2   = ws + G2_OFF;

  const float* msg_for_sa;

  if (ws_size >= WS_NEED) {
    /* fast path */
    float* eq    = ws + EQ_OFF;
    float* ek    = ws + EK_OFF;
    float* ev    = ws + EV_OFF;
    float* msg   = ws + MSG2_OFF;
    float* cum   = ws + CUM2_OFF;
    float* last  = ws + LAST2_OFF;
    float* means = ws + MEANS2_OFF;
    unsigned int* maxv = (unsigned int*)(ws + MAX2_OFF);
    float* pqg   = ws + PQ_OFF;
    hipMemsetAsync(maxv, 0, sizeof(unsigned int), stream);
    k_scan<<<68, 256, 0, stream>>>(arr, msk, timeTB, cum, last, means, maxv);
    k_pe<<<26, 256, 0, stream>>>(tlaWq, tlaWk, tlaWv, pqg);
    k_enc2<<<34 * 98, 256, 0, stream>>>(arr, msk, cum, last, means, maxv,
                                        wdec, bdec, encW1, encB1, encW2, encB2,
                                        tlaWq, tlaBq, tlaWk, tlaBk, tlaWv, tlaBv,
                                        eq, ek, ev);
    k_att<<<(BW + 6) / 7, 256, 0, stream>>>(eq, ek, ev, pqg, adj, msg);
    msg_for_sa = msg;
  } else {
    /* fallback: round-1 path */
    float* cum   = ws + CUM_OFF;
    float* last  = ws + LAST_OFF;
    float* means = ws + MEANS_OFF;
    unsigned int* maxv = (unsigned int*)(ws + MAX_OFF);
    float* enc   = ws + ENC_OFF;
    float* msg   = ws + MSG_OFF;
    hipMemsetAsync(maxv, 0, sizeof(unsigned int), stream);
    k_scan<<<68, 256, 0, stream>>>(arr, msk, timeTB, cum, last, means, maxv);
    k_enc<<<3332, 256, 0, stream>>>(arr, msk, cum, last, means, maxv,
                                    wdec, bdec, encW1, encB1, encW2, encB2, enc);
    k_tla<<<BW / TLA_G, 256, 0, stream>>>(enc, tlaWq, tlaBq, tlaWk, tlaBk,
                                          tlaWv, tlaBv, adj, msg);
    msg_for_sa = msg;
  }

  k_sa<<<BW, 256, 0, stream>>>(msg_for_sa, saWq, saBq, saWk, saBk, saWv, saBv, sout);
  k_xw1<<<(BW * TH3) / 256, 256, 0, stream>>>(sout, gWih0, gBih0, xw1);
  k_gru<<<BB, 192, 0, stream>>>(xw1, gWhh0, gBhh0, g1);
  k_xw2<<<BW / 16, 192, 0, stream>>>(g1, gWih1, gBih1, xw2);
  k_gru<<<BB, 192, 0, stream>>>(xw2, gWhh1, gBhh1, g2);
  k_ta<<<BB, 256, 0, stream>>>(g2, taWq, taBq, taWk, taBk, taWv, taBv,
                               cW1, cb1, cW2, cb2, out);
}

// Round 3
// 594.981 us; speedup vs baseline: 1.6558x; 1.0579x over previous
//
#include <hip/hip_runtime.h>
#include <math.h>

#define BB 512
#define TT 49
#define VV 34
#define FF 16
#define HH 64
#define WWIN 4
#define WW 46
#define BW (BB*WW)        /* 23552 */
#define TH3 (3*HH)        /* 192 */
#define ROWS 25088        /* B*T */
#define PLANE (ROWS*16)   /* 401408 */
#define SG 4              /* windows per k_sa2 block */

/* GRU-region reuse (region starts at 0 after msg2 is consumed... kept disjoint): */
#define SOUT_OFF   0ull                   /* BW*F = 376832 */
#define XW1_OFF    376832ull              /* BW*192 */
#define G1_OFF     (XW1_OFF + 4521984ull)
#define XW2_OFF    (G1_OFF + 1507328ull)
#define G2_OFF     (XW2_OFF + 4521984ull) /* ends 12435456 */

/* fast-path workspace layout */
#define MSG_SZ     12812288ull            /* BW*V*F */
#define CUM_SZ     852992ull              /* B*T*V */
#define MEANS_SZ   17408ull               /* B*V */
#define TENS       (34ull*PLANE)          /* 13,647,872 per eq/ek/ev tensor */
#define EQ_OFF     0ull
#define EK_OFF     TENS
#define EV_OFF     (2ull*TENS)
#define MSG2_OFF   (3ull*TENS)            /* 40,943,616 */
#define CUM2_OFF   (MSG2_OFF + MSG_SZ)
#define LAST2_OFF  (CUM2_OFF + CUM_SZ)
#define MEANS2_OFF (LAST2_OFF + CUM_SZ)
#define MAX2_OFF   (MEANS2_OFF + MEANS_SZ)
#define PQ_OFF     (MAX2_OFF + 4ull)
#define WS_NEED    ((PQ_OFF + 6528ull) * 4ull)

/* NOTE: eq/ek/ev region (0 .. 40.9M floats) overlaps the GRU region
   (0 .. 12.4M). By the time k_sa2 runs, eq/ek/ev are dead; msg2 lives at
   40.9M+ and is disjoint from the GRU region. Safe. */

/* ---------------- kernel 1: impute scan + global max + means ---------------- */
__global__ __launch_bounds__(256) void k_scan(
    const float* __restrict__ arr, const float* __restrict__ msk,
    const float* __restrict__ timeTB,
    float* __restrict__ cum, float* __restrict__ last,
    float* __restrict__ means, unsigned int* __restrict__ maxv) {
  int tid = blockIdx.x * 256 + threadIdx.x;     /* 0..17407, exact */
  int b = tid / VV, v = tid - b * VV;
  const int base = b * TT * VV + v;
  float x = arr[base];
  float c = 0.f, lm = 0.f, s = x;
  cum[base] = 0.f;
  last[base] = x;
  float tp = timeTB[b];
  for (int t = 1; t < TT; ++t) {
    float tc = timeTB[t * BB + b];
    float d = tc - tp; tp = tc;
    int e = base + t * VV;
    float a = arr[e], m = msk[e];
    float miss = (m == 0.f) ? 1.f : 0.f;
    c = d + c * miss;
    x = (miss > 0.f) ? x : a;
    cum[e] = c; last[e] = x;
    lm = fmaxf(lm, c);
    s += a;
  }
  means[tid] = s * (1.f / 49.f);
  #pragma unroll
  for (int off = 32; off; off >>= 1) lm = fmaxf(lm, __shfl_xor(lm, off));
  if ((threadIdx.x & 63) == 0) atomicMax(maxv, __float_as_uint(lm));
}

/* ---------------- PE projections pq/pk/pv[which][l][v][f] ---------------- */
__global__ __launch_bounds__(256) void k_pe(
    const float* __restrict__ Wq, const float* __restrict__ Wk,
    const float* __restrict__ Wv, float* __restrict__ pqg) {
  int idx = blockIdx.x * 256 + threadIdx.x;
  if (idx >= 6528) return;
  int which = idx / 2176;
  int r = idx - which * 2176;
  int l = r / 544;
  int rr = r - l * 544;
  int v = rr >> 4, f = rr & 15;
  const float* W = which == 0 ? Wq : which == 1 ? Wk : Wv;
  float acc = 0.f;
  #pragma unroll
  for (int i = 0; i < FF; ++i) {
    int i2 = i & ~1;
    float dv = expf(-logf(10000.f) * (float)i2 / (float)FF);
    float ang = (float)l * dv;
    float pe = (i & 1) ? cosf(ang) : sinf(ang);
    acc += pe * W[v * 256 + i * 16 + f];
  }
  pqg[idx] = acc;
}

/* ---------------- impute + encoder MLP + QKV projection fused ---------------- */
__global__ __launch_bounds__(256) void k_enc2(
    const float* __restrict__ arr, const float* __restrict__ msk,
    const float* __restrict__ cum, const float* __restrict__ last,
    const float* __restrict__ means, const unsigned int* __restrict__ maxv,
    const float* __restrict__ wdec, const float* __restrict__ bdec,
    const float* __restrict__ W1, const float* __restrict__ B1,
    const float* __restrict__ W2, const float* __restrict__ B2,
    const float* __restrict__ Wq, const float* __restrict__ Bq,
    const float* __restrict__ Wk, const float* __restrict__ Bk,
    const float* __restrict__ Wv, const float* __restrict__ Bv,
    float* __restrict__ eq, float* __restrict__ ek, float* __restrict__ ev) {
  __shared__ float w1s[32], b1s[16], w2s[256], b2s[16];
  __shared__ float wqs[256], wks[256], wvs[256], bqs[16], bks[16], bvs[16];
  const int v = blockIdx.x / 98;
  const int chunk = blockIdx.x - v * 98;
  const int tid = threadIdx.x;
  w2s[tid] = W2[v * 256 + tid];
  wqs[tid] = Wq[v * 256 + tid];
  wks[tid] = Wk[v * 256 + tid];
  wvs[tid] = Wv[v * 256 + tid];
  if (tid < 32) w1s[tid] = W1[v * 32 + tid];
  if (tid < 16) {
    b1s[tid] = B1[v * 16 + tid]; b2s[tid] = B2[v * 16 + tid];
    bqs[tid] = Bq[v * 16 + tid]; bks[tid] = Bk[v * 16 + tid]; bvs[tid] = Bv[v * 16 + tid];
  }
  __syncthreads();
  const int row = chunk * 256 + tid;            /* < 25088 exact */
  const int e = row * VV + v;
  const int b = row / TT;
  float inv = 1.f / __uint_as_float(*maxv);
  float cc = cum[e] * inv;
  float t = wdec[v] * cc + bdec[v];
  t = fminf(fmaxf(t, 0.f), 1000.f);
  float dec = expf(-t);
  float a = arr[e], m = msk[e];
  float xx = a * m + (1.f - m) * (dec * last[e] + (1.f - dec) * means[b * VV + v]);
  float h[FF];
  #pragma unroll
  for (int f = 0; f < FF; ++f)
    h[f] = fmaxf(xx * w1s[f] + m * w1s[16 + f] + b1s[f], 0.f);
  float er[FF];
  #pragma unroll
  for (int g = 0; g < FF; ++g) {
    float acc = b2s[g];
    #pragma unroll
    for (int f = 0; f < FF; ++f) acc += h[f] * w2s[f * 16 + g];
    er[g] = acc;
  }
  float qo[FF], ko[FF], vo[FF];
  #pragma unroll
  for (int f = 0; f < FF; ++f) {
    float aq = bqs[f], ak = bks[f], av = bvs[f];
    #pragma unroll
    for (int i = 0; i < FF; ++i) {
      float x2 = er[i];
      aq += x2 * wqs[i * 16 + f];
      ak += x2 * wks[i * 16 + f];
      av += x2 * wvs[i * 16 + f];
    }
    qo[f] = aq; ko[f] = ak; vo[f] = av;
  }
  size_t base = ((size_t)v * ROWS + row) * 16;
  float4* dq = (float4*)(eq + base);
  float4* dk = (float4*)(ek + base);
  float4* dv4 = (float4*)(ev + base);
  #pragma unroll
  for (int j = 0; j < 4; ++j) {
    dq[j] = make_float4(qo[4*j], qo[4*j+1], qo[4*j+2], qo[4*j+3]);
    dk[j] = make_float4(ko[4*j], ko[4*j+1], ko[4*j+2], ko[4*j+3]);
    dv4[j] = make_float4(vo[4*j], vo[4*j+1], vo[4*j+2], vo[4*j+3]);
  }
}

/* ------- windowed 4x4 attention + message passing, permuted+PE'd output -------
   msg2[((b*34+u)*46 + w)*16 + f] = MP(b,w,u,f) + pe_V(u,f)
   = exactly row j = (b*V+u)*W + w of the SA "scrambled reshape" input. */
__global__ __launch_bounds__(256) void k_att(
    const float* __restrict__ eq, const float* __restrict__ ek,
    const float* __restrict__ ev, const float* __restrict__ pqg,
    const float* __restrict__ adj, float* __restrict__ msg2) {
  __shared__ float pqs[3][4][578];   /* [which][l][v*17+f] padded */
  __shared__ float adjs[VV * VV];
  __shared__ float ao[7][578];       /* [g][v*17+f] */
  __shared__ float pes[VV][FF];
  const int tid = threadIdx.x;
  for (int i = tid; i < 6528; i += 256) {
    int which = i / 2176;
    int r = i - which * 2176;
    int l = r / 544;
    int rr = r - l * 544;
    pqs[which][l][(rr >> 4) * 17 + (rr & 15)] = pqg[i];
  }
  for (int i = tid; i < VV * VV; i += 256) adjs[i] = adj[i];
  for (int i = tid; i < VV * FF; i += 256) {
    int u = i >> 4, f = i & 15;
    int f2 = f & ~1;
    float dv = expf(-logf(10000.f) * (float)f2 / (float)FF);
    float ang = (float)u * dv;
    pes[u][f] = (f & 1) ? cosf(ang) : sinf(ang);
  }
  __syncthreads();
  const int g = tid / 34, v = tid - g * 34;
  const int n = blockIdx.x * 7 + g;
  if (g < 7 && n < BW) {
    int b = n / WW, w = n - b * WW;
    int row0 = b * TT + w;
    size_t base = ((size_t)v * ROWS + row0) * 16;
    const float* ekp = ek + base;
    float kk[4][16];
    #pragma unroll
    for (int m = 0; m < 4; ++m)
      #pragma unroll
      for (int f = 0; f < FF; ++f) kk[m][f] = ekp[m * 16 + f] + pqs[1][m][v * 17 + f];
    float sc[4][4];
    const float* eqp = eq + base;
    #pragma unroll
    for (int l = 0; l < 4; ++l) {
      float qv[16];
      #pragma unroll
      for (int f = 0; f < FF; ++f) qv[f] = eqp[l * 16 + f] + pqs[0][l][v * 17 + f];
      #pragma unroll
      for (int m = 0; m < 4; ++m) {
        float s = 0.f;
        #pragma unroll
        for (int f = 0; f < FF; ++f) s += qv[f] * kk[m][f];
        sc[l][m] = s * 0.25f;
      }
    }
    float csum[4] = {0.f, 0.f, 0.f, 0.f};
    #pragma unroll
    for (int l = 0; l < 4; ++l) {
      float mx = fmaxf(fmaxf(sc[l][0], sc[l][1]), fmaxf(sc[l][2], sc[l][3]));
      float sum = 0.f;
      #pragma unroll
      for (int m = 0; m < 4; ++m) { sc[l][m] = expf(sc[l][m] - mx); sum += sc[l][m]; }
      float r = 1.f / sum;
      #pragma unroll
      for (int m = 0; m < 4; ++m) csum[m] += sc[l][m] * r;
    }
    float outv[16];
    #pragma unroll
    for (int f = 0; f < FF; ++f) outv[f] = 0.f;
    const float* evp = ev + base;
    #pragma unroll
    for (int m = 0; m < 4; ++m) {
      float c = csum[m];
      #pragma unroll
      for (int f = 0; f < FF; ++f) outv[f] += c * (evp[m * 16 + f] + pqs[2][m][v * 17 + f]);
    }
    #pragma unroll
    for (int f = 0; f < FF; ++f) ao[g][v * 17 + f] = outv[f];
  }
  __syncthreads();
  for (int i = tid; i < 7 * 544; i += 256) {
    int g2 = i / 544, r = i - g2 * 544;
    int n2 = blockIdx.x * 7 + g2;
    if (n2 >= BW) continue;
    int b2 = n2 / WW, w2 = n2 - b2 * WW;
    int u = r >> 4, f = r & 15;
    float acc = 0.f;
    for (int v2 = 0; v2 < VV; ++v2) acc += adjs[u * VV + v2] * ao[g2][v2 * 17 + f];
    msg2[(size_t)(((b2 * VV + u) * WW) + w2) * 16 + (r & 15)] = acc + pes[u][f];
  }
}

/* ---------------- signal attention v2: contiguous input, 4 windows/block ---------------- */
__global__ __launch_bounds__(256) void k_sa2(
    const float* __restrict__ msg2,
    const float* __restrict__ Wq, const float* __restrict__ bq,
    const float* __restrict__ Wk, const float* __restrict__ bk,
    const float* __restrict__ Wv, const float* __restrict__ bv,
    float* __restrict__ sout) {
  __shared__ float wT[3][16][17];        /* transposed, padded */
  __shared__ float bs[3][16];
  __shared__ float xs[SG][VV][16];
  __shared__ float qs[SG][VV][17];
  __shared__ float ks[SG][VV][17];
  __shared__ float vs[SG][VV][17];
  __shared__ float sc[SG][VV][35];
  __shared__ float rs[SG][VV];
  __shared__ float cs[SG][VV];
  const int tid = threadIdx.x;
  const int n0 = blockIdx.x * SG;        /* grid 5888 exact */
  for (int idx = tid; idx < 768; idx += 256) {
    int which = idx >> 8, r = idx & 255;
    int i = r >> 4, f = r & 15;
    const float* W = which == 0 ? Wq : which == 1 ? Wk : Wv;
    wT[which][f][i] = W[r];
  }
  if (tid < 48) {
    int which = tid >> 4, f = tid & 15;
    bs[which][f] = (which == 0 ? bq : which == 1 ? bk : bv)[f];
  }
  {
    const float4* src = (const float4*)(msg2 + (size_t)n0 * (VV * FF));
    float4* dst = (float4*)(&xs[0][0][0]);
    for (int i = tid; i < SG * VV * 4; i += 256) dst[i] = src[i];
  }
  __syncthreads();
  /* QKV projection: share each xs read across 3 outputs */
  #pragma unroll
  for (int g = 0; g < SG; ++g) {
    for (int idx = tid; idx < VV * FF; idx += 256) {
      int m = idx >> 4, f = idx & 15;
      float aq = bs[0][f], ak = bs[1][f], av = bs[2][f];
      #pragma unroll
      for (int i = 0; i < FF; ++i) {
        float x = xs[g][m][i];
        aq += x * wT[0][f][i];
        ak += x * wT[1][f][i];
        av += x * wT[2][f][i];
      }
      qs[g][m][f] = aq; ks[g][m][f] = ak; vs[g][m][f] = av;
    }
  }
  __syncthreads();
  /* scores with 2x2 register tiles: 34 = 2*17 */
  for (int idx = tid; idx < SG * 17 * 17; idx += 256) {
    int g = idx / 289;
    int r = idx - g * 289;
    int lt = r / 17, mt = r - lt * 17;
    int l0 = lt * 2, m0 = mt * 2;
    float s00 = 0.f, s01 = 0.f, s10 = 0.f, s11 = 0.f;
    #pragma unroll
    for (int i = 0; i < FF; ++i) {
      float q0 = qs[g][l0][i], q1 = qs[g][l0 + 1][i];
      float k0 = ks[g][m0][i], k1 = ks[g][m0 + 1][i];
      s00 += q0 * k0; s01 += q0 * k1; s10 += q1 * k0; s11 += q1 * k1;
    }
    sc[g][l0][m0]     = s00 * 0.25f;
    sc[g][l0][m0 + 1] = s01 * 0.25f;
    sc[g][l0 + 1][m0]     = s10 * 0.25f;
    sc[g][l0 + 1][m0 + 1] = s11 * 0.25f;
  }
  __syncthreads();
  /* row softmax: keep exp, defer 1/sum to colsum */
  if (tid < SG * VV) {
    int g = tid / VV, l = tid - g * VV;
    float mx = -1e30f;
    for (int m = 0; m < VV; ++m) mx = fmaxf(mx, sc[g][l][m]);
    float sum = 0.f;
    for (int m = 0; m < VV; ++m) {
      float e = expf(sc[g][l][m] - mx);
      sc[g][l][m] = e; sum += e;
    }
    rs[g][l] = 1.f / sum;
  }
  __syncthreads();
  if (tid < SG * VV) {
    int g = tid / VV, m = tid - g * VV;
    float acc = 0.f;
    for (int l = 0; l < VV; ++l) acc += sc[g][l][m] * rs[g][l];
    cs[g][m] = acc;
  }
  __syncthreads();
  if (tid < SG * FF) {
    int g = tid >> 4, f = tid & 15;
    float acc = 0.f;
    for (int m = 0; m < VV; ++m) acc += cs[g][m] * vs[g][m][f];
    sout[(size_t)(n0 + g) * FF + f] = acc;
  }
}

/* ---------------- GRU input projections ---------------- */
__global__ __launch_bounds__(256) void k_xw1(
    const float* __restrict__ x, const float* __restrict__ Wih,
    const float* __restrict__ bih, float* __restrict__ xw) {
  int t = blockIdx.x * 256 + threadIdx.x;
  int n = t / TH3, o = t - n * TH3;
  float acc = bih[o];
  const float* xr = x + (size_t)n * FF;
  #pragma unroll
  for (int i = 0; i < FF; ++i) acc += xr[i] * Wih[i * TH3 + o];
  xw[t] = acc;
}

__global__ __launch_bounds__(192) void k_xw2(
    const float* __restrict__ x, const float* __restrict__ Wih,
    const float* __restrict__ bih, float* __restrict__ xw) {
  __shared__ float xsh[16][HH];
  int n0 = blockIdx.x * 16;
  int tid = threadIdx.x;
  for (int idx = tid; idx < 16 * HH; idx += 192) {
    int ns = idx >> 6, i = idx & 63;
    xsh[ns][i] = x[(size_t)(n0 + ns) * HH + i];
  }
  __syncthreads();
  float acc[16];
  float bb = bih[tid];
  #pragma unroll
  for (int ns = 0; ns < 16; ++ns) acc[ns] = bb;
  for (int i = 0; i < HH; ++i) {
    float wv = Wih[i * TH3 + tid];
    #pragma unroll
    for (int ns = 0; ns < 16; ++ns) acc[ns] += xsh[ns][i] * wv;
  }
  #pragma unroll
  for (int ns = 0; ns < 16; ++ns) xw[(size_t)(n0 + ns) * TH3 + tid] = acc[ns];
}

/* ---------------- GRU serial scan ---------------- */
__global__ __launch_bounds__(192) void k_gru(
    const float* __restrict__ xw, const float* __restrict__ Whh,
    const float* __restrict__ bhh, float* __restrict__ gout) {
  __shared__ float whh[HH * TH3];
  __shared__ float hsh[HH];
  __shared__ float gh[TH3];
  int tid = threadIdx.x;
  int b = blockIdx.x;
  for (int i = tid; i < HH * TH3; i += 192) whh[i] = Whh[i];
  if (tid < HH) hsh[tid] = 0.f;
  float bb = bhh[tid];
  __syncthreads();
  for (int w = 0; w < WW; ++w) {
    float acc = bb;
    #pragma unroll 8
    for (int i = 0; i < HH; ++i) acc += hsh[i] * whh[i * TH3 + tid];
    gh[tid] = acc;
    __syncthreads();
    if (tid < HH) {
      const float* xr = xw + (size_t)(b * WW + w) * TH3;
      float r = 1.f / (1.f + expf(-(xr[tid] + gh[tid])));
      float z = 1.f / (1.f + expf(-(xr[HH + tid] + gh[HH + tid])));
      float nn = tanhf(xr[2 * HH + tid] + r * gh[2 * HH + tid]);
      float hn = (1.f - z) * nn + z * hsh[tid];
      hsh[tid] = hn;
      gout[(size_t)(b * WW + w) * HH + tid] = hn;
    }
    __syncthreads();
  }
}

/* ---------------- temporal attention + classifier ---------------- */
__global__ __launch_bounds__(256) void k_ta(
    const float* __restrict__ g2,
    const float* __restrict__ Wq, const float* __restrict__ bq,
    const float* __restrict__ Wk, const float* __restrict__ bk,
    const float* __restrict__ Wv, const float* __restrict__ bv,
    const float* __restrict__ cW1, const float* __restrict__ cb1,
    const float* __restrict__ cW2, const float* __restrict__ cb2,
    float* __restrict__ out) {
  __shared__ float xt[WW * 65];
  __shared__ float QKVs[3][WW * 65];
  __shared__ float sc[WW * WW];
  __shared__ float cs[WW];
  __shared__ float tval[HH];
  __shared__ float hrelu[HH];
  int tid = threadIdx.x;
  int b = blockIdx.x;
  for (int idx = tid; idx < WW * HH; idx += 256) {
    int w = idx >> 6, d = idx & 63;
    int f2 = d & ~1;
    float dv = expf(-logf(10000.f) * (float)f2 / (float)HH);
    float ang = (float)w * dv;
    float pe = (d & 1) ? cosf(ang) : sinf(ang);
    xt[w * 65 + d] = g2[(size_t)(b * WW + w) * HH + d] + pe;
  }
  __syncthreads();
  if (tid < 192) {
    int which = tid >> 6, d = tid & 63;
    const float* Wt = which == 0 ? Wq : which == 1 ? Wk : Wv;
    float bias = (which == 0 ? bq : which == 1 ? bk : bv)[d];
    float col[HH];
    #pragma unroll
    for (int i = 0; i < HH; ++i) col[i] = Wt[i * HH + d];
    float* dst = &QKVs[which][0];
    for (int w = 0; w < WW; ++w) {
      float acc = bias;
      #pragma unroll
      for (int i = 0; i < HH; ++i) acc += xt[w * 65 + i] * col[i];
      dst[w * 65 + d] = acc;
    }
  }
  __syncthreads();
  for (int idx = tid; idx < WW * WW; idx += 256) {
    int l = idx / WW, m = idx - l * WW;
    float s = 0.f;
    #pragma unroll
    for (int i = 0; i < HH; ++i) s += QKVs[0][l * 65 + i] * QKVs[1][m * 65 + i];
    sc[idx] = s * 0.125f;
  }
  __syncthreads();
  if (tid < WW) {
    float mx = -1e30f;
    for (int m = 0; m < WW; ++m) mx = fmaxf(mx, sc[tid * WW + m]);
    float sum = 0.f;
    for (int m = 0; m < WW; ++m) { float e = expf(sc[tid * WW + m] - mx); sc[tid * WW + m] = e; sum += e; }
    float r = 1.f / sum;
    for (int m = 0; m < WW; ++m) sc[tid * WW + m] *= r;
  }
  __syncthreads();
  if (tid < WW) {
    float s = 0.f;
    for (int l = 0; l < WW; ++l) s += sc[l * WW + tid];
    cs[tid] = s;
  }
  __syncthreads();
  if (tid < HH) {
    float acc = 0.f;
    for (int m = 0; m < WW; ++m) acc += cs[m] * QKVs[2][m * 65 + tid];
    tval[tid] = acc;
  }
  __syncthreads();
  if (tid < HH) {
    float acc = cb1[tid];
    #pragma unroll
    for (int d = 0; d < HH; ++d) acc += tval[d] * cW1[d * HH + tid];
    hrelu[tid] = fmaxf(acc, 0.f);
  }
  __syncthreads();
  if (tid == 0) {
    float acc = cb2[0];
    for (int j = 0; j < HH; ++j) acc += hrelu[j] * cW2[j];
    out[b] = acc;
  }
}

extern "C" void kernel_launch(void* const* d_in, const int* in_sizes, int n_in,
                              void* d_out, int out_size, void* d_ws, size_t ws_size,
                              hipStream_t stream) {
  (void)in_sizes; (void)n_in; (void)out_size; (void)ws_size;
  const float* arr    = (const float*)d_in[0];
  const float* msk    = (const float*)d_in[1];
  const float* timeTB = (const float*)d_in[2];
  const float* wdec   = (const float*)d_in[3];
  const float* bdec   = (const float*)d_in[4];
  const float* encW1  = (const float*)d_in[5];
  const float* encB1  = (const float*)d_in[6];
  const float* encW2  = (const float*)d_in[7];
  const float* encB2  = (const float*)d_in[8];
  const float* tlaWq  = (const float*)d_in[9];
  const float* tlaBq  = (const float*)d_in[10];
  const float* tlaWk  = (const float*)d_in[11];
  const float* tlaBk  = (const float*)d_in[12];
  const float* tlaWv  = (const float*)d_in[13];
  const float* tlaBv  = (const float*)d_in[14];
  const float* adj    = (const float*)d_in[15];
  const float* saWq   = (const float*)d_in[20];
  const float* saBq   = (const float*)d_in[21];
  const float* saWk   = (const float*)d_in[22];
  const float* saBk   = (const float*)d_in[23];
  const float* saWv   = (const float*)d_in[24];
  const float* saBv   = (const float*)d_in[25];
  const float* gWih0  = (const float*)d_in[26];
  const float* gWhh0  = (const float*)d_in[27];
  const float* gBih0  = (const float*)d_in[28];
  const float* gBhh0  = (const float*)d_in[29];
  const float* gWih1  = (const float*)d_in[30];
  const float* gWhh1  = (const float*)d_in[31];
  const float* gBih1  = (const float*)d_in[32];
  const float* gBhh1  = (const float*)d_in[33];
  const float* taWq   = (const float*)d_in[34];
  const float* taBq   = (const float*)d_in[35];
  const float* taWk   = (const float*)d_in[36];
  const float* taBk   = (const float*)d_in[37];
  const float* taWv   = (const float*)d_in[38];
  const float* taBv   = (const float*)d_in[39];
  const float* cW1    = (const float*)d_in[40];
  const float* cb1    = (const float*)d_in[41];
  const float* cW2    = (const float*)d_in[42];
  const float* cb2    = (const float*)d_in[43];
  float* out = (float*)d_out;
  float* ws  = (float*)d_ws;

  float* eq    = ws + EQ_OFF;
  float* ek    = ws + EK_OFF;
  float* ev    = ws + EV_OFF;
  float* msg2  = ws + MSG2_OFF;
  float* cum   = ws + CUM2_OFF;
  float* last  = ws + LAST2_OFF;
  float* means = ws + MEANS2_OFF;
  unsigned int* maxv = (unsigned int*)(ws + MAX2_OFF);
  float* pqg   = ws + PQ_OFF;

  float* sout = ws + SOUT_OFF;
  float* xw1  = ws + XW1_OFF;
  float* g1   = ws + G1_OFF;
  float* xw2  = ws + XW2_OFF;
  float* g2   = ws + G2_OFF;

  hipMemsetAsync(maxv, 0, sizeof(unsigned int), stream);
  k_scan<<<68, 256, 0, stream>>>(arr, msk, timeTB, cum, last, means, maxv);
  k_pe<<<26, 256, 0, stream>>>(tlaWq, tlaWk, tlaWv, pqg);
  k_enc2<<<34 * 98, 256, 0, stream>>>(arr, msk, cum, last, means, maxv,
                                      wdec, bdec, encW1, encB1, encW2, encB2,
                                      tlaWq, tlaBq, tlaWk, tlaBk, tlaWv, tlaBv,
                                      eq, ek, ev);
  k_att<<<(BW + 6) / 7, 256, 0, stream>>>(eq, ek, ev, pqg, adj, msg2);
  k_sa2<<<BW / SG, 256, 0, stream>>>(msg2, saWq, saBq, saWk, saBk, saWv, saBv, sout);
  k_xw1<<<(BW * TH3) / 256, 256, 0, stream>>>(sout, gWih0, gBih0, xw1);
  k_gru<<<BB, 192, 0, stream>>>(xw1, gWhh0, gBhh0, g1);
  k_xw2<<<BW / 16, 192, 0, stream>>>(g1, gWih1, gBih1, xw2);
  k_gru<<<BB, 192, 0, stream>>>(xw2, gWhh1, gBhh1, g2);
  k_ta<<<BB, 256, 0, stream>>>(g2, taWq, taBq, taWk, taBk, taWv, taBv,
                               cW1, cb1, cW2, cb2, out);
}

// Round 4
// 551.056 us; speedup vs baseline: 1.7878x; 1.0797x over previous
//
#include <hip/hip_runtime.h>
#include <math.h>

#define BB 512
#define TT 49
#define VV 34
#define FF 16
#define HH 64
#define WWIN 4
#define WW 46
#define BW (BB*WW)        /* 23552 */
#define TH3 (3*HH)        /* 192 */
#define ROWS 25088        /* B*T */
#define PLANE (ROWS*16)   /* 401408 */
#define SG 4              /* windows per k_sa3 block */

/* GRU-region reuse: */
#define SOUT_OFF   0ull                   /* BW*F = 376832 */
#define XW1_OFF    376832ull              /* BW*192 */
#define G1_OFF     (XW1_OFF + 4521984ull)
#define XW2_OFF    (G1_OFF + 1507328ull)
#define G2_OFF     (XW2_OFF + 4521984ull) /* ends 12435456 */

/* fast-path workspace layout */
#define MSG_SZ     12812288ull            /* BW*V*F */
#define CUM_SZ     852992ull              /* B*T*V */
#define MEANS_SZ   17408ull               /* B*V */
#define TENS       (34ull*PLANE)          /* 13,647,872 per eq/ek/ev tensor */
#define EQ_OFF     0ull
#define EK_OFF     TENS
#define EV_OFF     (2ull*TENS)
#define MSG2_OFF   (3ull*TENS)            /* 40,943,616 */
#define CUM2_OFF   (MSG2_OFF + MSG_SZ)
#define LAST2_OFF  (CUM2_OFF + CUM_SZ)
#define MEANS2_OFF (LAST2_OFF + CUM_SZ)
#define MAX2_OFF   (MEANS2_OFF + MEANS_SZ)
#define PQ_OFF     (MAX2_OFF + 4ull)
#define SAW_OFF    (PQ_OFF + 6528ull)
#define WS_NEED    ((SAW_OFF + 289ull) * 4ull)

/* eq/ek/ev region (0..40.9M floats) overlaps the GRU region (0..12.4M);
   eq/ek/ev are dead before k_xw1 writes. msg2 at 40.9M+ is disjoint. Safe. */

/* ---------------- kernel 1: impute scan + global max + means ---------------- */
__global__ __launch_bounds__(256) void k_scan(
    const float* __restrict__ arr, const float* __restrict__ msk,
    const float* __restrict__ timeTB,
    float* __restrict__ cum, float* __restrict__ last,
    float* __restrict__ means, unsigned int* __restrict__ maxv) {
  int tid = blockIdx.x * 256 + threadIdx.x;     /* 0..17407, exact */
  int b = tid / VV, v = tid - b * VV;
  const int base = b * TT * VV + v;
  float x = arr[base];
  float c = 0.f, lm = 0.f, s = x;
  cum[base] = 0.f;
  last[base] = x;
  float tp = timeTB[b];
  for (int t = 1; t < TT; ++t) {
    float tc = timeTB[t * BB + b];
    float d = tc - tp; tp = tc;
    int e = base + t * VV;
    float a = arr[e], m = msk[e];
    float miss = (m == 0.f) ? 1.f : 0.f;
    c = d + c * miss;
    x = (miss > 0.f) ? x : a;
    cum[e] = c; last[e] = x;
    lm = fmaxf(lm, c);
    s += a;
  }
  means[tid] = s * (1.f / 49.f);
  #pragma unroll
  for (int off = 32; off; off >>= 1) lm = fmaxf(lm, __shfl_xor(lm, off));
  if ((threadIdx.x & 63) == 0) atomicMax(maxv, __float_as_uint(lm));
}

/* ---------------- PE projections pq/pk/pv[which][l][v][f] ---------------- */
__global__ __launch_bounds__(256) void k_pe(
    const float* __restrict__ Wq, const float* __restrict__ Wk,
    const float* __restrict__ Wv, float* __restrict__ pqg) {
  int idx = blockIdx.x * 256 + threadIdx.x;
  if (idx >= 6528) return;
  int which = idx / 2176;
  int r = idx - which * 2176;
  int l = r / 544;
  int rr = r - l * 544;
  int v = rr >> 4, f = rr & 15;
  const float* W = which == 0 ? Wq : which == 1 ? Wk : Wv;
  float acc = 0.f;
  #pragma unroll
  for (int i = 0; i < FF; ++i) {
    int i2 = i & ~1;
    float dv = expf(-logf(10000.f) * (float)i2 / (float)FF);
    float ang = (float)l * dv;
    float pe = (i & 1) ? cosf(ang) : sinf(ang);
    acc += pe * W[v * 256 + i * 16 + f];
  }
  pqg[idx] = acc;
}

/* ------- SA bilinear precompute: A^T[j][i]=sum_f Wq[i][f]Wk[j][f]; p; q2; c0 ------- */
__global__ __launch_bounds__(256) void k_saw(
    const float* __restrict__ Wq, const float* __restrict__ bq,
    const float* __restrict__ Wk, const float* __restrict__ bk,
    float* __restrict__ saw) {
  int t = threadIdx.x;
  int i = t & 15, j = t >> 4;
  float a = 0.f;
  #pragma unroll
  for (int f = 0; f < 16; ++f) a += Wq[i * 16 + f] * Wk[j * 16 + f];
  saw[j * 16 + i] = a;                    /* transposed store: [j][i] */
  if (t < 16) {
    float pp = 0.f, qq = 0.f;
    #pragma unroll
    for (int f = 0; f < 16; ++f) { pp += Wq[t * 16 + f] * bk[f]; qq += Wk[t * 16 + f] * bq[f]; }
    saw[256 + t] = pp;
    saw[272 + t] = qq;
  }
  if (t == 0) {
    float c = 0.f;
    #pragma unroll
    for (int f = 0; f < 16; ++f) c += bq[f] * bk[f];
    saw[288] = c;
  }
}

/* ---------------- impute + encoder MLP + QKV projection fused ---------------- */
__global__ __launch_bounds__(256) void k_enc2(
    const float* __restrict__ arr, const float* __restrict__ msk,
    const float* __restrict__ cum, const float* __restrict__ last,
    const float* __restrict__ means, const unsigned int* __restrict__ maxv,
    const float* __restrict__ wdec, const float* __restrict__ bdec,
    const float* __restrict__ W1, const float* __restrict__ B1,
    const float* __restrict__ W2, const float* __restrict__ B2,
    const float* __restrict__ Wq, const float* __restrict__ Bq,
    const float* __restrict__ Wk, const float* __restrict__ Bk,
    const float* __restrict__ Wv, const float* __restrict__ Bv,
    float* __restrict__ eq, float* __restrict__ ek, float* __restrict__ ev) {
  __shared__ float w1s[32], b1s[16], w2s[256], b2s[16];
  __shared__ float wqs[256], wks[256], wvs[256], bqs[16], bks[16], bvs[16];
  const int v = blockIdx.x / 98;
  const int chunk = blockIdx.x - v * 98;
  const int tid = threadIdx.x;
  w2s[tid] = W2[v * 256 + tid];
  wqs[tid] = Wq[v * 256 + tid];
  wks[tid] = Wk[v * 256 + tid];
  wvs[tid] = Wv[v * 256 + tid];
  if (tid < 32) w1s[tid] = W1[v * 32 + tid];
  if (tid < 16) {
    b1s[tid] = B1[v * 16 + tid]; b2s[tid] = B2[v * 16 + tid];
    bqs[tid] = Bq[v * 16 + tid]; bks[tid] = Bk[v * 16 + tid]; bvs[tid] = Bv[v * 16 + tid];
  }
  __syncthreads();
  const int row = chunk * 256 + tid;            /* < 25088 exact */
  const int e = row * VV + v;
  const int b = row / TT;
  float inv = 1.f / __uint_as_float(*maxv);
  float cc = cum[e] * inv;
  float t = wdec[v] * cc + bdec[v];
  t = fminf(fmaxf(t, 0.f), 1000.f);
  float dec = expf(-t);
  float a = arr[e], m = msk[e];
  float xx = a * m + (1.f - m) * (dec * last[e] + (1.f - dec) * means[b * VV + v]);
  float h[FF];
  #pragma unroll
  for (int f = 0; f < FF; ++f)
    h[f] = fmaxf(xx * w1s[f] + m * w1s[16 + f] + b1s[f], 0.f);
  float er[FF];
  #pragma unroll
  for (int g = 0; g < FF; ++g) {
    float acc = b2s[g];
    #pragma unroll
    for (int f = 0; f < FF; ++f) acc += h[f] * w2s[f * 16 + g];
    er[g] = acc;
  }
  float qo[FF], ko[FF], vo[FF];
  #pragma unroll
  for (int f = 0; f < FF; ++f) {
    float aq = bqs[f], ak = bks[f], av = bvs[f];
    #pragma unroll
    for (int i = 0; i < FF; ++i) {
      float x2 = er[i];
      aq += x2 * wqs[i * 16 + f];
      ak += x2 * wks[i * 16 + f];
      av += x2 * wvs[i * 16 + f];
    }
    qo[f] = aq; ko[f] = ak; vo[f] = av;
  }
  size_t base = ((size_t)v * ROWS + row) * 16;
  float4* dq = (float4*)(eq + base);
  float4* dk = (float4*)(ek + base);
  float4* dv4 = (float4*)(ev + base);
  #pragma unroll
  for (int j = 0; j < 4; ++j) {
    dq[j] = make_float4(qo[4*j], qo[4*j+1], qo[4*j+2], qo[4*j+3]);
    dk[j] = make_float4(ko[4*j], ko[4*j+1], ko[4*j+2], ko[4*j+3]);
    dv4[j] = make_float4(vo[4*j], vo[4*j+1], vo[4*j+2], vo[4*j+3]);
  }
}

/* ------- windowed 4x4 attention + message passing, permuted+PE'd output ------- */
__global__ __launch_bounds__(256) void k_att(
    const float* __restrict__ eq, const float* __restrict__ ek,
    const float* __restrict__ ev, const float* __restrict__ pqg,
    const float* __restrict__ adj, float* __restrict__ msg2) {
  __shared__ float pqs[3][4][578];   /* [which][l][v*17+f] padded */
  __shared__ float adjs[VV * VV];
  __shared__ float ao[7][578];       /* [g][v*17+f] */
  __shared__ float pes[VV][FF];
  const int tid = threadIdx.x;
  for (int i = tid; i < 6528; i += 256) {
    int which = i / 2176;
    int r = i - which * 2176;
    int l = r / 544;
    int rr = r - l * 544;
    pqs[which][l][(rr >> 4) * 17 + (rr & 15)] = pqg[i];
  }
  for (int i = tid; i < VV * VV; i += 256) adjs[i] = adj[i];
  for (int i = tid; i < VV * FF; i += 256) {
    int u = i >> 4, f = i & 15;
    int f2 = f & ~1;
    float dv = expf(-logf(10000.f) * (float)f2 / (float)FF);
    float ang = (float)u * dv;
    pes[u][f] = (f & 1) ? cosf(ang) : sinf(ang);
  }
  __syncthreads();
  const int g = tid / 34, v = tid - g * 34;
  const int n = blockIdx.x * 7 + g;
  if (g < 7 && n < BW) {
    int b = n / WW, w = n - b * WW;
    int row0 = b * TT + w;
    size_t base = ((size_t)v * ROWS + row0) * 16;
    const float* ekp = ek + base;
    float kk[4][16];
    #pragma unroll
    for (int m = 0; m < 4; ++m)
      #pragma unroll
      for (int f = 0; f < FF; ++f) kk[m][f] = ekp[m * 16 + f] + pqs[1][m][v * 17 + f];
    float sc[4][4];
    const float* eqp = eq + base;
    #pragma unroll
    for (int l = 0; l < 4; ++l) {
      float qv[16];
      #pragma unroll
      for (int f = 0; f < FF; ++f) qv[f] = eqp[l * 16 + f] + pqs[0][l][v * 17 + f];
      #pragma unroll
      for (int m = 0; m < 4; ++m) {
        float s = 0.f;
        #pragma unroll
        for (int f = 0; f < FF; ++f) s += qv[f] * kk[m][f];
        sc[l][m] = s * 0.25f;
      }
    }
    float csum[4] = {0.f, 0.f, 0.f, 0.f};
    #pragma unroll
    for (int l = 0; l < 4; ++l) {
      float mx = fmaxf(fmaxf(sc[l][0], sc[l][1]), fmaxf(sc[l][2], sc[l][3]));
      float sum = 0.f;
      #pragma unroll
      for (int m = 0; m < 4; ++m) { sc[l][m] = expf(sc[l][m] - mx); sum += sc[l][m]; }
      float r = 1.f / sum;
      #pragma unroll
      for (int m = 0; m < 4; ++m) csum[m] += sc[l][m] * r;
    }
    float outv[16];
    #pragma unroll
    for (int f = 0; f < FF; ++f) outv[f] = 0.f;
    const float* evp = ev + base;
    #pragma unroll
    for (int m = 0; m < 4; ++m) {
      float c = csum[m];
      #pragma unroll
      for (int f = 0; f < FF; ++f) outv[f] += c * (evp[m * 16 + f] + pqs[2][m][v * 17 + f]);
    }
    #pragma unroll
    for (int f = 0; f < FF; ++f) ao[g][v * 17 + f] = outv[f];
  }
  __syncthreads();
  for (int i = tid; i < 7 * 544; i += 256) {
    int g2 = i / 544, r = i - g2 * 544;
    int n2 = blockIdx.x * 7 + g2;
    if (n2 >= BW) continue;
    int b2 = n2 / WW, w2 = n2 - b2 * WW;
    int u = r >> 4, f = r & 15;
    float acc = 0.f;
    for (int v2 = 0; v2 < VV; ++v2) acc += adjs[u * VV + v2] * ao[g2][v2 * 17 + f];
    msg2[(size_t)(((b2 * VV + u) * WW) + w2) * 16 + (r & 15)] = acc + pes[u][f];
  }
}

/* ---------------- signal attention v3: bilinear trick, small LDS ---------------- */
__global__ __launch_bounds__(256) void k_sa3(
    const float* __restrict__ msg2, const float* __restrict__ saw,
    const float* __restrict__ Wv, const float* __restrict__ bv,
    float* __restrict__ sout) {
  __shared__ float As[256];              /* A^T: As[j*16+i] */
  __shared__ float ps[16], q2s[16];
  __shared__ float xs[SG][VV][20];       /* pad 20 (float4-aligned) */
  __shared__ float zs[SG][VV][17];       /* pad 17 */
  __shared__ float sc[SG][VV][VV];
  __shared__ float uws[SG][VV], vws[SG][VV];
  __shared__ float rs[SG][VV], cs[SG][VV];
  __shared__ float ys[SG][16];
  __shared__ float c0s;
  const int tid = threadIdx.x;
  const int n0 = blockIdx.x * SG;        /* grid 5888 exact */
  As[tid] = saw[tid];
  if (tid < 16) { ps[tid] = saw[256 + tid]; q2s[tid] = saw[272 + tid]; }
  if (tid == 0) c0s = saw[288];
  {
    const float4* src = (const float4*)(msg2 + (size_t)n0 * (VV * FF));
    for (int i = tid; i < SG * VV * 4; i += 256) {
      int g = i / 136, r = i - g * 136;
      int m = r >> 2, i4 = r & 3;
      float4 val = src[i];
      float* d = &xs[g][m][i4 * 4];
      d[0] = val.x; d[1] = val.y; d[2] = val.z; d[3] = val.w;
    }
  }
  __syncthreads();
  /* phase1: Z = A X^T, u = X.p, w = X.q2 */
  for (int idx = tid; idx < SG * VV * FF; idx += 256) {
    int g = idx / 544, r = idx - g * 544;
    int m = r >> 4, i = r & 15;
    float acc = 0.f;
    #pragma unroll
    for (int j = 0; j < FF; ++j) acc += As[j * 16 + i] * xs[g][m][j];
    zs[g][m][i] = acc;
  }
  if (tid < SG * VV) {
    int g = tid / VV, m = tid - g * VV;
    float pu = 0.f, pv = 0.f;
    #pragma unroll
    for (int i = 0; i < FF; ++i) { float x = xs[g][m][i]; pu += x * ps[i]; pv += x * q2s[i]; }
    uws[g][m] = pu; vws[g][m] = pv;
  }
  __syncthreads();
  /* phase2: scores sc = (X.Z + u + w + c0)/4, 2x2 register tiles */
  for (int idx = tid; idx < SG * 17 * 17; idx += 256) {
    int g = idx / 289, r = idx - g * 289;
    int lt = r / 17, mt = r - lt * 17;
    int l0 = lt * 2, m0 = mt * 2;
    float s00 = 0.f, s01 = 0.f, s10 = 0.f, s11 = 0.f;
    #pragma unroll
    for (int i = 0; i < FF; ++i) {
      float x0 = xs[g][l0][i], x1 = xs[g][l0 + 1][i];
      float z0 = zs[g][m0][i], z1 = zs[g][m0 + 1][i];
      s00 += x0 * z0; s01 += x0 * z1; s10 += x1 * z0; s11 += x1 * z1;
    }
    float c0 = c0s;
    float ul0 = uws[g][l0], ul1 = uws[g][l0 + 1];
    float vm0 = vws[g][m0], vm1 = vws[g][m0 + 1];
    sc[g][l0][m0]         = (s00 + ul0 + vm0 + c0) * 0.25f;
    sc[g][l0][m0 + 1]     = (s01 + ul0 + vm1 + c0) * 0.25f;
    sc[g][l0 + 1][m0]     = (s10 + ul1 + vm0 + c0) * 0.25f;
    sc[g][l0 + 1][m0 + 1] = (s11 + ul1 + vm1 + c0) * 0.25f;
  }
  __syncthreads();
  /* phase3: row softmax (store exp, defer 1/sum) */
  if (tid < SG * VV) {
    int g = tid / VV, l = tid - g * VV;
    float mx = -1e30f;
    for (int m = 0; m < VV; ++m) mx = fmaxf(mx, sc[g][l][m]);
    float sum = 0.f;
    for (int m = 0; m < VV; ++m) { float e = expf(sc[g][l][m] - mx); sc[g][l][m] = e; sum += e; }
    rs[g][l] = 1.f / sum;
  }
  __syncthreads();
  /* phase4: column sums of att */
  if (tid < SG * VV) {
    int g = tid / VV, m = tid - g * VV;
    float acc = 0.f;
    for (int l = 0; l < VV; ++l) acc += sc[g][l][m] * rs[g][l];
    cs[g][m] = acc;
  }
  __syncthreads();
  /* phase5: y = cs . X  (16-vec per window) */
  if (tid < SG * FF) {
    int g = tid >> 4, i = tid & 15;
    float acc = 0.f;
    for (int m = 0; m < VV; ++m) acc += cs[g][m] * xs[g][m][i];
    ys[g][i] = acc;
  }
  __syncthreads();
  /* phase6: sout = y.Wv + 34*bv */
  if (tid < SG * FF) {
    int g = tid >> 4, f = tid & 15;
    float acc = 34.f * bv[f];
    #pragma unroll
    for (int i = 0; i < FF; ++i) acc += ys[g][i] * Wv[i * 16 + f];
    sout[(size_t)(n0 + g) * FF + f] = acc;
  }
}

/* ---------------- GRU input projections ---------------- */
__global__ __launch_bounds__(256) void k_xw1(
    const float* __restrict__ x, const float* __restrict__ Wih,
    const float* __restrict__ bih, float* __restrict__ xw) {
  int t = blockIdx.x * 256 + threadIdx.x;
  int n = t / TH3, o = t - n * TH3;
  float acc = bih[o];
  const float* xr = x + (size_t)n * FF;
  #pragma unroll
  for (int i = 0; i < FF; ++i) acc += xr[i] * Wih[i * TH3 + o];
  xw[t] = acc;
}

__global__ __launch_bounds__(192) void k_xw2(
    const float* __restrict__ x, const float* __restrict__ Wih,
    const float* __restrict__ bih, float* __restrict__ xw) {
  __shared__ float xsh[16][HH];
  int n0 = blockIdx.x * 16;
  int tid = threadIdx.x;
  for (int idx = tid; idx < 16 * HH; idx += 192) {
    int ns = idx >> 6, i = idx & 63;
    xsh[ns][i] = x[(size_t)(n0 + ns) * HH + i];
  }
  __syncthreads();
  float acc[16];
  float bb = bih[tid];
  #pragma unroll
  for (int ns = 0; ns < 16; ++ns) acc[ns] = bb;
  for (int i = 0; i < HH; ++i) {
    float wv = Wih[i * TH3 + tid];
    #pragma unroll
    for (int ns = 0; ns < 16; ++ns) acc[ns] += xsh[ns][i] * wv;
  }
  #pragma unroll
  for (int ns = 0; ns < 16; ++ns) xw[(size_t)(n0 + ns) * TH3 + tid] = acc[ns];
}

/* ---------------- GRU serial scan ---------------- */
__global__ __launch_bounds__(192) void k_gru(
    const float* __restrict__ xw, const float* __restrict__ Whh,
    const float* __restrict__ bhh, float* __restrict__ gout) {
  __shared__ float whh[HH * TH3];
  __shared__ float hsh[HH];
  __shared__ float gh[TH3];
  int tid = threadIdx.x;
  int b = blockIdx.x;
  for (int i = tid; i < HH * TH3; i += 192) whh[i] = Whh[i];
  if (tid < HH) hsh[tid] = 0.f;
  float bb = bhh[tid];
  __syncthreads();
  for (int w = 0; w < WW; ++w) {
    float acc = bb;
    #pragma unroll 8
    for (int i = 0; i < HH; ++i) acc += hsh[i] * whh[i * TH3 + tid];
    gh[tid] = acc;
    __syncthreads();
    if (tid < HH) {
      const float* xr = xw + (size_t)(b * WW + w) * TH3;
      float r = 1.f / (1.f + expf(-(xr[tid] + gh[tid])));
      float z = 1.f / (1.f + expf(-(xr[HH + tid] + gh[HH + tid])));
      float nn = tanhf(xr[2 * HH + tid] + r * gh[2 * HH + tid]);
      float hn = (1.f - z) * nn + z * hsh[tid];
      hsh[tid] = hn;
      gout[(size_t)(b * WW + w) * HH + tid] = hn;
    }
    __syncthreads();
  }
}

/* ---------------- temporal attention + classifier ---------------- */
__global__ __launch_bounds__(256) void k_ta(
    const float* __restrict__ g2,
    const float* __restrict__ Wq, const float* __restrict__ bq,
    const float* __restrict__ Wk, const float* __restrict__ bk,
    const float* __restrict__ Wv, const float* __restrict__ bv,
    const float* __restrict__ cW1, const float* __restrict__ cb1,
    const float* __restrict__ cW2, const float* __restrict__ cb2,
    float* __restrict__ out) {
  __shared__ float xt[WW * 65];
  __shared__ float QKVs[3][WW * 65];
  __shared__ float sc[WW * WW];
  __shared__ float cs[WW];
  __shared__ float tval[HH];
  __shared__ float hrelu[HH];
  int tid = threadIdx.x;
  int b = blockIdx.x;
  for (int idx = tid; idx < WW * HH; idx += 256) {
    int w = idx >> 6, d = idx & 63;
    int f2 = d & ~1;
    float dv = expf(-logf(10000.f) * (float)f2 / (float)HH);
    float ang = (float)w * dv;
    float pe = (d & 1) ? cosf(ang) : sinf(ang);
    xt[w * 65 + d] = g2[(size_t)(b * WW + w) * HH + d] + pe;
  }
  __syncthreads();
  if (tid < 192) {
    int which = tid >> 6, d = tid & 63;
    const float* Wt = which == 0 ? Wq : which == 1 ? Wk : Wv;
    float bias = (which == 0 ? bq : which == 1 ? bk : bv)[d];
    float col[HH];
    #pragma unroll
    for (int i = 0; i < HH; ++i) col[i] = Wt[i * HH + d];
    float* dst = &QKVs[which][0];
    for (int w = 0; w < WW; ++w) {
      float acc = bias;
      #pragma unroll
      for (int i = 0; i < HH; ++i) acc += xt[w * 65 + i] * col[i];
      dst[w * 65 + d] = acc;
    }
  }
  __syncthreads();
  for (int idx = tid; idx < WW * WW; idx += 256) {
    int l = idx / WW, m = idx - l * WW;
    float s = 0.f;
    #pragma unroll
    for (int i = 0; i < HH; ++i) s += QKVs[0][l * 65 + i] * QKVs[1][m * 65 + i];
    sc[idx] = s * 0.125f;
  }
  __syncthreads();
  if (tid < WW) {
    float mx = -1e30f;
    for (int m = 0; m < WW; ++m) mx = fmaxf(mx, sc[tid * WW + m]);
    float sum = 0.f;
    for (int m = 0; m < WW; ++m) { float e = expf(sc[tid * WW + m] - mx); sc[tid * WW + m] = e; sum += e; }
    float r = 1.f / sum;
    for (int m = 0; m < WW; ++m) sc[tid * WW + m] *= r;
  }
  __syncthreads();
  if (tid < WW) {
    float s = 0.f;
    for (int l = 0; l < WW; ++l) s += sc[l * WW + tid];
    cs[tid] = s;
  }
  __syncthreads();
  if (tid < HH) {
    float acc = 0.f;
    for (int m = 0; m < WW; ++m) acc += cs[m] * QKVs[2][m * 65 + tid];
    tval[tid] = acc;
  }
  __syncthreads();
  if (tid < HH) {
    float acc = cb1[tid];
    #pragma unroll
    for (int d = 0; d < HH; ++d) acc += tval[d] * cW1[d * HH + tid];
    hrelu[tid] = fmaxf(acc, 0.f);
  }
  __syncthreads();
  if (tid == 0) {
    float acc = cb2[0];
    for (int j = 0; j < HH; ++j) acc += hrelu[j] * cW2[j];
    out[b] = acc;
  }
}

extern "C" void kernel_launch(void* const* d_in, const int* in_sizes, int n_in,
                              void* d_out, int out_size, void* d_ws, size_t ws_size,
                              hipStream_t stream) {
  (void)in_sizes; (void)n_in; (void)out_size; (void)ws_size;
  const float* arr    = (const float*)d_in[0];
  const float* msk    = (const float*)d_in[1];
  const float* timeTB = (const float*)d_in[2];
  const float* wdec   = (const float*)d_in[3];
  const float* bdec   = (const float*)d_in[4];
  const float* encW1  = (const float*)d_in[5];
  const float* encB1  = (const float*)d_in[6];
  const float* encW2  = (const float*)d_in[7];
  const float* encB2  = (const float*)d_in[8];
  const float* tlaWq  = (const float*)d_in[9];
  const float* tlaBq  = (const float*)d_in[10];
  const float* tlaWk  = (const float*)d_in[11];
  const float* tlaBk  = (const float*)d_in[12];
  const float* tlaWv  = (const float*)d_in[13];
  const float* tlaBv  = (const float*)d_in[14];
  const float* adj    = (const float*)d_in[15];
  const float* saWq   = (const float*)d_in[20];
  const float* saBq   = (const float*)d_in[21];
  const float* saWk   = (const float*)d_in[22];
  const float* saBk   = (const float*)d_in[23];
  const float* saWv   = (const float*)d_in[24];
  const float* saBv   = (const float*)d_in[25];
  const float* gWih0  = (const float*)d_in[26];
  const float* gWhh0  = (const float*)d_in[27];
  const float* gBih0  = (const float*)d_in[28];
  const float* gBhh0  = (const float*)d_in[29];
  const float* gWih1  = (const float*)d_in[30];
  const float* gWhh1  = (const float*)d_in[31];
  const float* gBih1  = (const float*)d_in[32];
  const float* gBhh1  = (const float*)d_in[33];
  const float* taWq   = (const float*)d_in[34];
  const float* taBq   = (const float*)d_in[35];
  const float* taWk   = (const float*)d_in[36];
  const float* taBk   = (const float*)d_in[37];
  const float* taWv   = (const float*)d_in[38];
  const float* taBv   = (const float*)d_in[39];
  const float* cW1    = (const float*)d_in[40];
  const float* cb1    = (const float*)d_in[41];
  const float* cW2    = (const float*)d_in[42];
  const float* cb2    = (const float*)d_in[43];
  float* out = (float*)d_out;
  float* ws  = (float*)d_ws;

  float* eq    = ws + EQ_OFF;
  float* ek    = ws + EK_OFF;
  float* ev    = ws + EV_OFF;
  float* msg2  = ws + MSG2_OFF;
  float* cum   = ws + CUM2_OFF;
  float* last  = ws + LAST2_OFF;
  float* means = ws + MEANS2_OFF;
  unsigned int* maxv = (unsigned int*)(ws + MAX2_OFF);
  float* pqg   = ws + PQ_OFF;
  float* saw   = ws + SAW_OFF;

  float* sout = ws + SOUT_OFF;
  float* xw1  = ws + XW1_OFF;
  float* g1   = ws + G1_OFF;
  float* xw2  = ws + XW2_OFF;
  float* g2   = ws + G2_OFF;

  hipMemsetAsync(maxv, 0, sizeof(unsigned int), stream);
  k_scan<<<68, 256, 0, stream>>>(arr, msk, timeTB, cum, last, means, maxv);
  k_pe<<<26, 256, 0, stream>>>(tlaWq, tlaWk, tlaWv, pqg);
  k_saw<<<1, 256, 0, stream>>>(saWq, saBq, saWk, saBk, saw);
  k_enc2<<<34 * 98, 256, 0, stream>>>(arr, msk, cum, last, means, maxv,
                                      wdec, bdec, encW1, encB1, encW2, encB2,
                                      tlaWq, tlaBq, tlaWk, tlaBk, tlaWv, tlaBv,
                                      eq, ek, ev);
  k_att<<<(BW + 6) / 7, 256, 0, stream>>>(eq, ek, ev, pqg, adj, msg2);
  k_sa3<<<BW / SG, 256, 0, stream>>>(msg2, saw, saWv, saBv, sout);
  k_xw1<<<(BW * TH3) / 256, 256, 0, stream>>>(sout, gWih0, gBih0, xw1);
  k_gru<<<BB, 192, 0, stream>>>(xw1, gWhh0, gBhh0, g1);
  k_xw2<<<BW / 16, 192, 0, stream>>>(g1, gWih1, gBih1, xw2);
  k_gru<<<BB, 192, 0, stream>>>(xw2, gWhh1, gBhh1, g2);
  k_ta<<<BB, 256, 0, stream>>>(g2, taWq, taBq, taWk, taBk, taWv, taBv,
                               cW1, cb1, cW2, cb2, out);
}

// Round 5
// 456.745 us; speedup vs baseline: 2.1570x; 1.2065x over previous
//
#include <hip/hip_runtime.h>
#include <math.h>

#define BB 512
#define TT 49
#define VV 34
#define FF 16
#define HH 64
#define WWIN 4
#define WW 46
#define BW (BB*WW)        /* 23552 */
#define TH3 (3*HH)        /* 192 */
#define ROWS 25088        /* B*T */
#define SG 4              /* windows per k_sa3 block */

/* GRU-region (offsets in floats, region 0 .. 12,435,456) */
#define SOUT_OFF   0ull                   /* BW*F = 376832 */
#define XW1_OFF    376832ull              /* BW*192 */
#define G1_OFF     (XW1_OFF + 4521984ull)
#define XW2_OFF    (G1_OFF + 1507328ull)
#define G2_OFF     (XW2_OFF + 4521984ull) /* ends 12435456 */

#define MSG_SZ     12812288ull            /* BW*V*F = B*V*W*F */
#define CUM_SZ     852992ull              /* B*T*V */
#define MEANS_SZ   17408ull               /* B*V */
#define AO_OFF     12435456ull
#define MSG2_OFF   (AO_OFF + MSG_SZ)      /* 25247744 */
#define CUM2_OFF   (MSG2_OFF + MSG_SZ)    /* 38060032 */
#define LAST2_OFF  (CUM2_OFF + CUM_SZ)
#define MEANS2_OFF (LAST2_OFF + CUM_SZ)
#define MAX2_OFF   (MEANS2_OFF + MEANS_SZ)
#define PQ_OFF     (MAX2_OFF + 4ull)
#define SAW_OFF    (PQ_OFF + 6528ull)     /* end ~39.8M floats = 159 MB */

/* ---------------- kernel 1: impute scan + global max + means ---------------- */
__global__ __launch_bounds__(256) void k_scan(
    const float* __restrict__ arr, const float* __restrict__ msk,
    const float* __restrict__ timeTB,
    float* __restrict__ cum, float* __restrict__ last,
    float* __restrict__ means, unsigned int* __restrict__ maxv) {
  int tid = blockIdx.x * 256 + threadIdx.x;     /* 0..17407, exact */
  int b = tid / VV, v = tid - b * VV;
  const int base = b * TT * VV + v;
  float x = arr[base];
  float c = 0.f, lm = 0.f, s = x;
  cum[base] = 0.f;
  last[base] = x;
  float tp = timeTB[b];
  for (int t = 1; t < TT; ++t) {
    float tc = timeTB[t * BB + b];
    float d = tc - tp; tp = tc;
    int e = base + t * VV;
    float a = arr[e], m = msk[e];
    float miss = (m == 0.f) ? 1.f : 0.f;
    c = d + c * miss;
    x = (miss > 0.f) ? x : a;
    cum[e] = c; last[e] = x;
    lm = fmaxf(lm, c);
    s += a;
  }
  means[tid] = s * (1.f / 49.f);
  #pragma unroll
  for (int off = 32; off; off >>= 1) lm = fmaxf(lm, __shfl_xor(lm, off));
  if ((threadIdx.x & 63) == 0) atomicMax(maxv, __float_as_uint(lm));
}

/* ---------------- PE projections pq/pk/pv[which][l][v][f] ---------------- */
__global__ __launch_bounds__(256) void k_pe(
    const float* __restrict__ Wq, const float* __restrict__ Wk,
    const float* __restrict__ Wv, float* __restrict__ pqg) {
  int idx = blockIdx.x * 256 + threadIdx.x;
  if (idx >= 6528) return;
  int which = idx / 2176;
  int r = idx - which * 2176;
  int l = r / 544;
  int rr = r - l * 544;
  int v = rr >> 4, f = rr & 15;
  const float* W = which == 0 ? Wq : which == 1 ? Wk : Wv;
  float acc = 0.f;
  #pragma unroll
  for (int i = 0; i < FF; ++i) {
    int i2 = i & ~1;
    float dv = expf(-logf(10000.f) * (float)i2 / (float)FF);
    float ang = (float)l * dv;
    float pe = (i & 1) ? cosf(ang) : sinf(ang);
    acc += pe * W[v * 256 + i * 16 + f];
  }
  pqg[idx] = acc;
}

/* ------- SA bilinear precompute: A^T[j][i]=sum_f Wq[i][f]Wk[j][f]; p; q2; c0 ------- */
__global__ __launch_bounds__(256) void k_saw(
    const float* __restrict__ Wq, const float* __restrict__ bq,
    const float* __restrict__ Wk, const float* __restrict__ bk,
    float* __restrict__ saw) {
  int t = threadIdx.x;
  int i = t & 15, j = t >> 4;
  float a = 0.f;
  #pragma unroll
  for (int f = 0; f < 16; ++f) a += Wq[i * 16 + f] * Wk[j * 16 + f];
  saw[j * 16 + i] = a;                    /* transposed store: [j][i] */
  if (t < 16) {
    float pp = 0.f, qq = 0.f;
    #pragma unroll
    for (int f = 0; f < 16; ++f) { pp += Wq[t * 16 + f] * bk[f]; qq += Wk[t * 16 + f] * bq[f]; }
    saw[256 + t] = pp;
    saw[272 + t] = qq;
  }
  if (t == 0) {
    float c = 0.f;
    #pragma unroll
    for (int f = 0; f < 16; ++f) c += bq[f] * bk[f];
    saw[288] = c;
  }
}

/* ------- fused impute + encoder MLP + QKV proj + windowed 4x4 attention -------
   one wave per (b,v); 4 batches per block sharing one v's weights.
   writes ao[((b*34+v)*46 + w)*16 + f]  (per-variable attention output) */
__global__ __launch_bounds__(256) void k_enc3(
    const float* __restrict__ arr, const float* __restrict__ msk,
    const float* __restrict__ cum, const float* __restrict__ last,
    const float* __restrict__ means, const unsigned int* __restrict__ maxv,
    const float* __restrict__ wdec, const float* __restrict__ bdec,
    const float* __restrict__ W1, const float* __restrict__ B1,
    const float* __restrict__ W2, const float* __restrict__ B2,
    const float* __restrict__ Wq, const float* __restrict__ Bq,
    const float* __restrict__ Wk, const float* __restrict__ Bk,
    const float* __restrict__ Wv, const float* __restrict__ Bv,
    const float* __restrict__ pqg, float* __restrict__ ao) {
  __shared__ float wg[1136];
  __shared__ float pqs[192];               /* [which][l][f] for this v */
  __shared__ float pkv[4][3][TT * 17];     /* per-wave P/K/V, stride 17 (bank-safe) */
  const int v = blockIdx.x % VV;
  const int bgrp = blockIdx.x / VV;        /* grid = 34*128 */
  const int tid = threadIdx.x;
  const int wave = tid >> 6, lane = tid & 63;
  const int b = bgrp * 4 + wave;
  for (int i = tid; i < 1136; i += 256) {
    float val;
    if (i < 32) val = W1[v * 32 + i];
    else if (i < 48) val = B1[v * 16 + (i - 32)];
    else if (i < 304) val = W2[v * 256 + (i - 48)];
    else if (i < 320) val = B2[v * 16 + (i - 304)];
    else if (i < 576) val = Wq[v * 256 + (i - 320)];
    else if (i < 592) val = Bq[v * 16 + (i - 576)];
    else if (i < 848) val = Wk[v * 256 + (i - 592)];
    else if (i < 864) val = Bk[v * 16 + (i - 848)];
    else if (i < 1120) val = Wv[v * 256 + (i - 864)];
    else val = Bv[v * 16 + (i - 1120)];
    wg[i] = val;
  }
  if (tid < 192) {
    int which = tid >> 6, l = (tid >> 4) & 3, f = tid & 15;
    pqs[tid] = pqg[which * 2176 + l * 544 + v * 16 + f];
  }
  __syncthreads();
  if (lane < TT) {
    const int t = lane;
    const int idx = (b * TT + t) * VV + v;
    float inv = 1.f / __uint_as_float(*maxv);
    float a = arr[idx], m = msk[idx];
    float cc = cum[idx] * inv;
    float ttc = fminf(fmaxf(wdec[v] * cc + bdec[v], 0.f), 1000.f);
    float dec = expf(-ttc);
    float xx = a * m + (1.f - m) * (dec * last[idx] + (1.f - dec) * means[b * VV + v]);
    float h[16];
    #pragma unroll
    for (int f = 0; f < 16; ++f)
      h[f] = fmaxf(xx * wg[f] + m * wg[16 + f] + wg[32 + f], 0.f);
    float er[16];
    #pragma unroll
    for (int g = 0; g < 16; ++g) {
      float acc = wg[304 + g];
      #pragma unroll
      for (int f = 0; f < 16; ++f) acc += h[f] * wg[48 + f * 16 + g];
      er[g] = acc;
    }
    #pragma unroll
    for (int which = 0; which < 3; ++which) {
      const int wo = (which == 0) ? 320 : (which == 1) ? 592 : 864;
      const int bo = (which == 0) ? 576 : (which == 1) ? 848 : 1120;
      #pragma unroll
      for (int g = 0; g < 16; ++g) {
        float acc = wg[bo + g];
        #pragma unroll
        for (int i = 0; i < 16; ++i) acc += er[i] * wg[wo + i * 16 + g];
        pkv[wave][which][t * 17 + g] = acc;
      }
    }
  }
  __syncthreads();
  if (lane < WW) {
    const int w = lane;
    const float* P = &pkv[wave][0][0];
    const float* K = &pkv[wave][1][0];
    const float* Vp = &pkv[wave][2][0];
    float kk[4][16];
    #pragma unroll
    for (int m = 0; m < 4; ++m)
      #pragma unroll
      for (int f = 0; f < 16; ++f) kk[m][f] = K[(w + m) * 17 + f] + pqs[64 + m * 16 + f];
    float sc[4][4];
    #pragma unroll
    for (int l = 0; l < 4; ++l) {
      float qv[16];
      #pragma unroll
      for (int i = 0; i < 16; ++i) qv[i] = P[(w + l) * 17 + i] + pqs[l * 16 + i];
      #pragma unroll
      for (int m = 0; m < 4; ++m) {
        float s = 0.f;
        #pragma unroll
        for (int i = 0; i < 16; ++i) s += qv[i] * kk[m][i];
        sc[l][m] = s * 0.25f;
      }
    }
    float csum[4] = {0.f, 0.f, 0.f, 0.f};
    #pragma unroll
    for (int l = 0; l < 4; ++l) {
      float mx = fmaxf(fmaxf(sc[l][0], sc[l][1]), fmaxf(sc[l][2], sc[l][3]));
      float sum = 0.f;
      #pragma unroll
      for (int m = 0; m < 4; ++m) { sc[l][m] = expf(sc[l][m] - mx); sum += sc[l][m]; }
      float r = 1.f / sum;
      #pragma unroll
      for (int m = 0; m < 4; ++m) csum[m] += sc[l][m] * r;
    }
    float outv[16];
    #pragma unroll
    for (int f = 0; f < 16; ++f) outv[f] = 0.f;
    #pragma unroll
    for (int m = 0; m < 4; ++m) {
      float c = csum[m];
      #pragma unroll
      for (int f = 0; f < 16; ++f) outv[f] += c * (Vp[(w + m) * 17 + f] + pqs[128 + m * 16 + f]);
    }
    float4* d4 = (float4*)(ao + ((size_t)(b * VV + v) * WW + w) * 16);
    #pragma unroll
    for (int j = 0; j < 4; ++j)
      d4[j] = make_float4(outv[4*j], outv[4*j+1], outv[4*j+2], outv[4*j+3]);
  }
}

/* ------- message passing (adj contraction) + V-axis PE fold, msg2 layout -------
   msg2[((b*34+u)*46+w)*16+f] = pe_V(u,f) + sum_v adj[u][v]*ao[((b*34+v)*46+w)*16+f] */
#define MPW 12
__global__ __launch_bounds__(256) void k_mp(
    const float* __restrict__ ao, const float* __restrict__ adj,
    float* __restrict__ msg2) {
  __shared__ float adjs[VV * VV];
  __shared__ __align__(16) float aos[VV][MPW * 16];
  __shared__ float pes[VV * 16];
  const int bb = blockIdx.x >> 2;          /* grid = 512*4 */
  const int wt = blockIdx.x & 3;
  const int w0 = wt * MPW;
  const int wc = (wt == 3) ? (WW - 3 * MPW) : MPW;   /* 12,12,12,10 */
  const int tid = threadIdx.x;
  for (int i = tid; i < VV * VV; i += 256) adjs[i] = adj[i];
  for (int i = tid; i < VV * 16; i += 256) {
    int u = i >> 4, f = i & 15;
    int f2 = f & ~1;
    float dv = expf(-logf(10000.f) * (float)f2 / 16.f);
    float ang = (float)u * dv;
    pes[i] = (f & 1) ? cosf(ang) : sinf(ang);
  }
  const int nq = wc * 4;
  for (int i = tid; i < VV * nq; i += 256) {
    int vv2 = i / nq, r = i - vv2 * nq;
    int wl = r >> 2, q = r & 3;
    float4 val = *(const float4*)(ao + ((size_t)(bb * VV + vv2) * WW + w0 + wl) * 16 + q * 4);
    *(float4*)&aos[vv2][wl * 16 + q * 4] = val;
  }
  __syncthreads();
  for (int i = tid; i < VV * nq; i += 256) {
    int u = i / nq, r = i - u * nq;
    int wl = r >> 2, q = r & 3;
    float a0 = 0.f, a1 = 0.f, a2 = 0.f, a3 = 0.f;
    for (int vv2 = 0; vv2 < VV; ++vv2) {
      float a = adjs[u * VV + vv2];
      float4 s = *(const float4*)&aos[vv2][wl * 16 + q * 4];
      a0 += a * s.x; a1 += a * s.y; a2 += a * s.z; a3 += a * s.w;
    }
    float4 o = make_float4(a0 + pes[u * 16 + q * 4],
                           a1 + pes[u * 16 + q * 4 + 1],
                           a2 + pes[u * 16 + q * 4 + 2],
                           a3 + pes[u * 16 + q * 4 + 3]);
    *(float4*)(msg2 + ((size_t)(bb * VV + u) * WW + w0 + wl) * 16 + q * 4) = o;
  }
}

/* ---------------- signal attention v3: bilinear trick, small LDS ---------------- */
__global__ __launch_bounds__(256) void k_sa3(
    const float* __restrict__ msg2, const float* __restrict__ saw,
    const float* __restrict__ Wv, const float* __restrict__ bv,
    float* __restrict__ sout) {
  __shared__ float As[256];              /* A^T: As[j*16+i] */
  __shared__ float ps[16], q2s[16];
  __shared__ float xs[SG][VV][20];       /* pad 20 (float4-aligned) */
  __shared__ float zs[SG][VV][17];       /* pad 17 */
  __shared__ float sc[SG][VV][VV];
  __shared__ float uws[SG][VV], vws[SG][VV];
  __shared__ float rs[SG][VV], cs[SG][VV];
  __shared__ float ys[SG][16];
  __shared__ float c0s;
  const int tid = threadIdx.x;
  const int n0 = blockIdx.x * SG;        /* grid 5888 exact */
  As[tid] = saw[tid];
  if (tid < 16) { ps[tid] = saw[256 + tid]; q2s[tid] = saw[272 + tid]; }
  if (tid == 0) c0s = saw[288];
  {
    const float4* src = (const float4*)(msg2 + (size_t)n0 * (VV * FF));
    for (int i = tid; i < SG * VV * 4; i += 256) {
      int g = i / 136, r = i - g * 136;
      int m = r >> 2, i4 = r & 3;
      float4 val = src[i];
      float* d = &xs[g][m][i4 * 4];
      d[0] = val.x; d[1] = val.y; d[2] = val.z; d[3] = val.w;
    }
  }
  __syncthreads();
  for (int idx = tid; idx < SG * VV * FF; idx += 256) {
    int g = idx / 544, r = idx - g * 544;
    int m = r >> 4, i = r & 15;
    float acc = 0.f;
    #pragma unroll
    for (int j = 0; j < FF; ++j) acc += As[j * 16 + i] * xs[g][m][j];
    zs[g][m][i] = acc;
  }
  if (tid < SG * VV) {
    int g = tid / VV, m = tid - g * VV;
    float pu = 0.f, pv = 0.f;
    #pragma unroll
    for (int i = 0; i < FF; ++i) { float x = xs[g][m][i]; pu += x * ps[i]; pv += x * q2s[i]; }
    uws[g][m] = pu; vws[g][m] = pv;
  }
  __syncthreads();
  for (int idx = tid; idx < SG * 17 * 17; idx += 256) {
    int g = idx / 289, r = idx - g * 289;
    int lt = r / 17, mt = r - lt * 17;
    int l0 = lt * 2, m0 = mt * 2;
    float s00 = 0.f, s01 = 0.f, s10 = 0.f, s11 = 0.f;
    #pragma unroll
    for (int i = 0; i < FF; ++i) {
      float x0 = xs[g][l0][i], x1 = xs[g][l0 + 1][i];
      float z0 = zs[g][m0][i], z1 = zs[g][m0 + 1][i];
      s00 += x0 * z0; s01 += x0 * z1; s10 += x1 * z0; s11 += x1 * z1;
    }
    float c0 = c0s;
    float ul0 = uws[g][l0], ul1 = uws[g][l0 + 1];
    float vm0 = vws[g][m0], vm1 = vws[g][m0 + 1];
    sc[g][l0][m0]         = (s00 + ul0 + vm0 + c0) * 0.25f;
    sc[g][l0][m0 + 1]     = (s01 + ul0 + vm1 + c0) * 0.25f;
    sc[g][l0 + 1][m0]     = (s10 + ul1 + vm0 + c0) * 0.25f;
    sc[g][l0 + 1][m0 + 1] = (s11 + ul1 + vm1 + c0) * 0.25f;
  }
  __syncthreads();
  if (tid < SG * VV) {
    int g = tid / VV, l = tid - g * VV;
    float mx = -1e30f;
    for (int m = 0; m < VV; ++m) mx = fmaxf(mx, sc[g][l][m]);
    float sum = 0.f;
    for (int m = 0; m < VV; ++m) { float e = expf(sc[g][l][m] - mx); sc[g][l][m] = e; sum += e; }
    rs[g][l] = 1.f / sum;
  }
  __syncthreads();
  if (tid < SG * VV) {
    int g = tid / VV, m = tid - g * VV;
    float acc = 0.f;
    for (int l = 0; l < VV; ++l) acc += sc[g][l][m] * rs[g][l];
    cs[g][m] = acc;
  }
  __syncthreads();
  if (tid < SG * FF) {
    int g = tid >> 4, i = tid & 15;
    float acc = 0.f;
    for (int m = 0; m < VV; ++m) acc += cs[g][m] * xs[g][m][i];
    ys[g][i] = acc;
  }
  __syncthreads();
  if (tid < SG * FF) {
    int g = tid >> 4, f = tid & 15;
    float acc = 34.f * bv[f];
    #pragma unroll
    for (int i = 0; i < FF; ++i) acc += ys[g][i] * Wv[i * 16 + f];
    sout[(size_t)(n0 + g) * FF + f] = acc;
  }
}

/* ---------------- GRU input projections ---------------- */
__global__ __launch_bounds__(256) void k_xw1(
    const float* __restrict__ x, const float* __restrict__ Wih,
    const float* __restrict__ bih, float* __restrict__ xw) {
  int t = blockIdx.x * 256 + threadIdx.x;
  int n = t / TH3, o = t - n * TH3;
  float acc = bih[o];
  const float* xr = x + (size_t)n * FF;
  #pragma unroll
  for (int i = 0; i < FF; ++i) acc += xr[i] * Wih[i * TH3 + o];
  xw[t] = acc;
}

__global__ __launch_bounds__(192) void k_xw2(
    const float* __restrict__ x, const float* __restrict__ Wih,
    const float* __restrict__ bih, float* __restrict__ xw) {
  __shared__ float xsh[16][HH];
  int n0 = blockIdx.x * 16;
  int tid = threadIdx.x;
  for (int idx = tid; idx < 16 * HH; idx += 192) {
    int ns = idx >> 6, i = idx & 63;
    xsh[ns][i] = x[(size_t)(n0 + ns) * HH + i];
  }
  __syncthreads();
  float acc[16];
  float bb = bih[tid];
  #pragma unroll
  for (int ns = 0; ns < 16; ++ns) acc[ns] = bb;
  for (int i = 0; i < HH; ++i) {
    float wv = Wih[i * TH3 + tid];
    #pragma unroll
    for (int ns = 0; ns < 16; ++ns) acc[ns] += xsh[ns][i] * wv;
  }
  #pragma unroll
  for (int ns = 0; ns < 16; ++ns) xw[(size_t)(n0 + ns) * TH3 + tid] = acc[ns];
}

/* ---------------- GRU serial scan ---------------- */
__global__ __launch_bounds__(192) void k_gru(
    const float* __restrict__ xw, const float* __restrict__ Whh,
    const float* __restrict__ bhh, float* __restrict__ gout) {
  __shared__ float whh[HH * TH3];
  __shared__ float hsh[HH];
  __shared__ float gh[TH3];
  int tid = threadIdx.x;
  int b = blockIdx.x;
  for (int i = tid; i < HH * TH3; i += 192) whh[i] = Whh[i];
  if (tid < HH) hsh[tid] = 0.f;
  float bb = bhh[tid];
  __syncthreads();
  for (int w = 0; w < WW; ++w) {
    float acc = bb;
    #pragma unroll 8
    for (int i = 0; i < HH; ++i) acc += hsh[i] * whh[i * TH3 + tid];
    gh[tid] = acc;
    __syncthreads();
    if (tid < HH) {
      const float* xr = xw + (size_t)(b * WW + w) * TH3;
      float r = 1.f / (1.f + expf(-(xr[tid] + gh[tid])));
      float z = 1.f / (1.f + expf(-(xr[HH + tid] + gh[HH + tid])));
      float nn = tanhf(xr[2 * HH + tid] + r * gh[2 * HH + tid]);
      float hn = (1.f - z) * nn + z * hsh[tid];
      hsh[tid] = hn;
      gout[(size_t)(b * WW + w) * HH + tid] = hn;
    }
    __syncthreads();
  }
}

/* ---------------- temporal attention + classifier ---------------- */
__global__ __launch_bounds__(256) void k_ta(
    const float* __restrict__ g2,
    const float* __restrict__ Wq, const float* __restrict__ bq,
    const float* __restrict__ Wk, const float* __restrict__ bk,
    const float* __restrict__ Wv, const float* __restrict__ bv,
    const float* __restrict__ cW1, const float* __restrict__ cb1,
    const float* __restrict__ cW2, const float* __restrict__ cb2,
    float* __restrict__ out) {
  __shared__ float xt[WW * 65];
  __shared__ float QKVs[3][WW * 65];
  __shared__ float sc[WW * WW];
  __shared__ float cs[WW];
  __shared__ float tval[HH];
  __shared__ float hrelu[HH];
  int tid = threadIdx.x;
  int b = blockIdx.x;
  for (int idx = tid; idx < WW * HH; idx += 256) {
    int w = idx >> 6, d = idx & 63;
    int f2 = d & ~1;
    float dv = expf(-logf(10000.f) * (float)f2 / (float)HH);
    float ang = (float)w * dv;
    float pe = (d & 1) ? cosf(ang) : sinf(ang);
    xt[w * 65 + d] = g2[(size_t)(b * WW + w) * HH + d] + pe;
  }
  __syncthreads();
  if (tid < 192) {
    int which = tid >> 6, d = tid & 63;
    const float* Wt = which == 0 ? Wq : which == 1 ? Wk : Wv;
    float bias = (which == 0 ? bq : which == 1 ? bk : bv)[d];
    float col[HH];
    #pragma unroll
    for (int i = 0; i < HH; ++i) col[i] = Wt[i * HH + d];
    float* dst = &QKVs[which][0];
    for (int w = 0; w < WW; ++w) {
      float acc = bias;
      #pragma unroll
      for (int i = 0; i < HH; ++i) acc += xt[w * 65 + i] * col[i];
      dst[w * 65 + d] = acc;
    }
  }
  __syncthreads();
  for (int idx = tid; idx < WW * WW; idx += 256) {
    int l = idx / WW, m = idx - l * WW;
    float s = 0.f;
    #pragma unroll
    for (int i = 0; i < HH; ++i) s += QKVs[0][l * 65 + i] * QKVs[1][m * 65 + i];
    sc[idx] = s * 0.125f;
  }
  __syncthreads();
  if (tid < WW) {
    float mx = -1e30f;
    for (int m = 0; m < WW; ++m) mx = fmaxf(mx, sc[tid * WW + m]);
    float sum = 0.f;
    for (int m = 0; m < WW; ++m) { float e = expf(sc[tid * WW + m] - mx); sc[tid * WW + m] = e; sum += e; }
    float r = 1.f / sum;
    for (int m = 0; m < WW; ++m) sc[tid * WW + m] *= r;
  }
  __syncthreads();
  if (tid < WW) {
    float s = 0.f;
    for (int l = 0; l < WW; ++l) s += sc[l * WW + tid];
    cs[tid] = s;
  }
  __syncthreads();
  if (tid < HH) {
    float acc = 0.f;
    for (int m = 0; m < WW; ++m) acc += cs[m] * QKVs[2][m * 65 + tid];
    tval[tid] = acc;
  }
  __syncthreads();
  if (tid < HH) {
    float acc = cb1[tid];
    #pragma unroll
    for (int d = 0; d < HH; ++d) acc += tval[d] * cW1[d * HH + tid];
    hrelu[tid] = fmaxf(acc, 0.f);
  }
  __syncthreads();
  if (tid == 0) {
    float acc = cb2[0];
    for (int j = 0; j < HH; ++j) acc += hrelu[j] * cW2[j];
    out[b] = acc;
  }
}

extern "C" void kernel_launch(void* const* d_in, const int* in_sizes, int n_in,
                              void* d_out, int out_size, void* d_ws, size_t ws_size,
                              hipStream_t stream) {
  (void)in_sizes; (void)n_in; (void)out_size; (void)ws_size;
  const float* arr    = (const float*)d_in[0];
  const float* msk    = (const float*)d_in[1];
  const float* timeTB = (const float*)d_in[2];
  const float* wdec   = (const float*)d_in[3];
  const float* bdec   = (const float*)d_in[4];
  const float* encW1  = (const float*)d_in[5];
  const float* encB1  = (const float*)d_in[6];
  const float* encW2  = (const float*)d_in[7];
  const float* encB2  = (const float*)d_in[8];
  const float* tlaWq  = (const float*)d_in[9];
  const float* tlaBq  = (const float*)d_in[10];
  const float* tlaWk  = (const float*)d_in[11];
  const float* tlaBk  = (const float*)d_in[12];
  const float* tlaWv  = (const float*)d_in[13];
  const float* tlaBv  = (const float*)d_in[14];
  const float* adj    = (const float*)d_in[15];
  const float* saWq   = (const float*)d_in[20];
  const float* saBq   = (const float*)d_in[21];
  const float* saWk   = (const float*)d_in[22];
  const float* saBk   = (const float*)d_in[23];
  const float* saWv   = (const float*)d_in[24];
  const float* saBv   = (const float*)d_in[25];
  const float* gWih0  = (const float*)d_in[26];
  const float* gWhh0  = (const float*)d_in[27];
  const float* gBih0  = (const float*)d_in[28];
  const float* gBhh0  = (const float*)d_in[29];
  const float* gWih1  = (const float*)d_in[30];
  const float* gWhh1  = (const float*)d_in[31];
  const float* gBih1  = (const float*)d_in[32];
  const float* gBhh1  = (const float*)d_in[33];
  const float* taWq   = (const float*)d_in[34];
  const float* taBq   = (const float*)d_in[35];
  const float* taWk   = (const float*)d_in[36];
  const float* taBk   = (const float*)d_in[37];
  const float* taWv   = (const float*)d_in[38];
  const float* taBv   = (const float*)d_in[39];
  const float* cW1    = (const float*)d_in[40];
  const float* cb1    = (const float*)d_in[41];
  const float* cW2    = (const float*)d_in[42];
  const float* cb2    = (const float*)d_in[43];
  float* out = (float*)d_out;
  float* ws  = (float*)d_ws;

  float* ao    = ws + AO_OFF;
  float* msg2  = ws + MSG2_OFF;
  float* cum   = ws + CUM2_OFF;
  float* last  = ws + LAST2_OFF;
  float* means = ws + MEANS2_OFF;
  unsigned int* maxv = (unsigned int*)(ws + MAX2_OFF);
  float* pqg   = ws + PQ_OFF;
  float* saw   = ws + SAW_OFF;

  float* sout = ws + SOUT_OFF;
  float* xw1  = ws + XW1_OFF;
  float* g1   = ws + G1_OFF;
  float* xw2  = ws + XW2_OFF;
  float* g2   = ws + G2_OFF;

  hipMemsetAsync(maxv, 0, sizeof(unsigned int), stream);
  k_scan<<<68, 256, 0, stream>>>(arr, msk, timeTB, cum, last, means, maxv);
  k_pe<<<26, 256, 0, stream>>>(tlaWq, tlaWk, tlaWv, pqg);
  k_saw<<<1, 256, 0, stream>>>(saWq, saBq, saWk, saBk, saw);
  k_enc3<<<VV * 128, 256, 0, stream>>>(arr, msk, cum, last, means, maxv,
                                       wdec, bdec, encW1, encB1, encW2, encB2,
                                       tlaWq, tlaBq, tlaWk, tlaBk, tlaWv, tlaBv,
                                       pqg, ao);
  k_mp<<<BB * 4, 256, 0, stream>>>(ao, adj, msg2);
  k_sa3<<<BW / SG, 256, 0, stream>>>(msg2, saw, saWv, saBv, sout);
  k_xw1<<<(BW * TH3) / 256, 256, 0, stream>>>(sout, gWih0, gBih0, xw1);
  k_gru<<<BB, 192, 0, stream>>>(xw1, gWhh0, gBhh0, g1);
  k_xw2<<<BW / 16, 192, 0, stream>>>(g1, gWih1, gBih1, xw2);
  k_gru<<<BB, 192, 0, stream>>>(xw2, gWhh1, gBhh1, g2);
  k_ta<<<BB, 256, 0, stream>>>(g2, taWq, taBq, taWk, taBk, taWv, taBv,
                               cW1, cb1, cW2, cb2, out);
}

// Round 6
// 413.225 us; speedup vs baseline: 2.3842x; 1.1053x over previous
//
#include <hip/hip_runtime.h>
#include <math.h>

#define BB 512
#define TT 49
#define VV 34
#define FF 16
#define HH 64
#define WWIN 4
#define WW 46
#define BW (BB*WW)        /* 23552 */
#define TH3 (3*HH)        /* 192 */
#define ROWS 25088        /* B*T */
#define SG 4              /* windows per k_sa3 block */

/* GRU-region (offsets in floats, region 0 .. 12,435,456) */
#define SOUT_OFF   0ull                   /* BW*F = 376832 */
#define XW1_OFF    376832ull              /* BW*192 */
#define G1_OFF     (XW1_OFF + 4521984ull)
#define XW2_OFF    (G1_OFF + 1507328ull)
#define G2_OFF     (XW2_OFF + 4521984ull) /* ends 12435456 */

#define MSG_SZ     12812288ull            /* BW*V*F = B*V*W*F */
#define CUM_SZ     852992ull              /* B*T*V */
#define MEANS_SZ   17408ull               /* B*V */
#define AO_OFF     12435456ull
#define MSG2_OFF   (AO_OFF + MSG_SZ)      /* 25247744 */
#define CUM2_OFF   (MSG2_OFF + MSG_SZ)    /* 38060032 */
#define LAST2_OFF  (CUM2_OFF + CUM_SZ)
#define MEANS2_OFF (LAST2_OFF + CUM_SZ)
#define MAX2_OFF   (MEANS2_OFF + MEANS_SZ)
#define PQ_OFF     (MAX2_OFF + 4ull)
#define SAW_OFF    (PQ_OFF + 6528ull)
#define FW_OFF     (SAW_OFF + 292ull)     /* 34*816 = 27744 floats */

/* ---------------- kernel 1: impute scan + global max + means ---------------- */
__global__ __launch_bounds__(256) void k_scan(
    const float* __restrict__ arr, const float* __restrict__ msk,
    const float* __restrict__ timeTB,
    float* __restrict__ cum, float* __restrict__ last,
    float* __restrict__ means, unsigned int* __restrict__ maxv) {
  int tid = blockIdx.x * 256 + threadIdx.x;     /* 0..17407, exact */
  int b = tid / VV, v = tid - b * VV;
  const int base = b * TT * VV + v;
  float x = arr[base];
  float c = 0.f, lm = 0.f, s = x;
  cum[base] = 0.f;
  last[base] = x;
  float tp = timeTB[b];
  for (int t = 1; t < TT; ++t) {
    float tc = timeTB[t * BB + b];
    float d = tc - tp; tp = tc;
    int e = base + t * VV;
    float a = arr[e], m = msk[e];
    float miss = (m == 0.f) ? 1.f : 0.f;
    c = d + c * miss;
    x = (miss > 0.f) ? x : a;
    cum[e] = c; last[e] = x;
    lm = fmaxf(lm, c);
    s += a;
  }
  means[tid] = s * (1.f / 49.f);
  #pragma unroll
  for (int off = 32; off; off >>= 1) lm = fmaxf(lm, __shfl_xor(lm, off));
  if ((threadIdx.x & 63) == 0) atomicMax(maxv, __float_as_uint(lm));
}

/* ---------------- prep: PE projections + SA bilinear + enc weight folding ----------------
   blocks 0..25:  pqg[which][l][v][f]  (TLA PE projections)
   block  26:     saw (SA bilinear A^T, p, q2, c0)
   blocks 27..60: fw[v][which][ C(16x16) , bias(16) ]  folded enc->QKV weights */
__global__ __launch_bounds__(256) void k_prep(
    const float* __restrict__ tlaWq, const float* __restrict__ tlaWk,
    const float* __restrict__ tlaWv,
    const float* __restrict__ tlaBq, const float* __restrict__ tlaBk,
    const float* __restrict__ tlaBv,
    const float* __restrict__ saWq, const float* __restrict__ saBq,
    const float* __restrict__ saWk, const float* __restrict__ saBk,
    const float* __restrict__ encW2, const float* __restrict__ encB2,
    float* __restrict__ pqg, float* __restrict__ saw, float* __restrict__ fw) {
  const int bid = blockIdx.x;
  const int t = threadIdx.x;
  if (bid < 26) {
    int idx = bid * 256 + t;
    if (idx >= 6528) return;
    int which = idx / 2176;
    int r = idx - which * 2176;
    int l = r / 544;
    int rr = r - l * 544;
    int v = rr >> 4, f = rr & 15;
    const float* W = which == 0 ? tlaWq : which == 1 ? tlaWk : tlaWv;
    float acc = 0.f;
    #pragma unroll
    for (int i = 0; i < FF; ++i) {
      int i2 = i & ~1;
      float dv = expf(-logf(10000.f) * (float)i2 / (float)FF);
      float ang = (float)l * dv;
      float pe = (i & 1) ? cosf(ang) : sinf(ang);
      acc += pe * W[v * 256 + i * 16 + f];
    }
    pqg[idx] = acc;
  } else if (bid == 26) {
    int i = t & 15, j = t >> 4;
    float a = 0.f;
    #pragma unroll
    for (int f = 0; f < 16; ++f) a += saWq[i * 16 + f] * saWk[j * 16 + f];
    saw[j * 16 + i] = a;                    /* transposed store: [j][i] */
    if (t < 16) {
      float pp = 0.f, qq = 0.f;
      #pragma unroll
      for (int f = 0; f < 16; ++f) { pp += saWq[t * 16 + f] * saBk[f]; qq += saWk[t * 16 + f] * saBq[f]; }
      saw[256 + t] = pp;
      saw[272 + t] = qq;
    }
    if (t == 0) {
      float c = 0.f;
      #pragma unroll
      for (int f = 0; f < 16; ++f) c += saBq[f] * saBk[f];
      saw[288] = c;
    }
  } else {
    const int v = bid - 27;
    const int f = t >> 4, o = t & 15;
    const float* W2v = encW2 + v * 256;
    float cq = 0.f, ck = 0.f, cv = 0.f;
    #pragma unroll
    for (int g = 0; g < 16; ++g) {
      float w2 = W2v[f * 16 + g];
      cq += w2 * tlaWq[v * 256 + g * 16 + o];
      ck += w2 * tlaWk[v * 256 + g * 16 + o];
      cv += w2 * tlaWv[v * 256 + g * 16 + o];
    }
    fw[v * 816 + 0 * 272 + f * 16 + o] = cq;
    fw[v * 816 + 1 * 272 + f * 16 + o] = ck;
    fw[v * 816 + 2 * 272 + f * 16 + o] = cv;
    if (t < 48) {
      int which = t >> 4, o2 = t & 15;
      const float* Wp = which == 0 ? tlaWq : which == 1 ? tlaWk : tlaWv;
      const float* Bp = which == 0 ? tlaBq : which == 1 ? tlaBk : tlaBv;
      float acc = Bp[v * 16 + o2];
      #pragma unroll
      for (int g = 0; g < 16; ++g) acc += encB2[v * 16 + g] * Wp[v * 256 + g * 16 + o2];
      fw[v * 816 + which * 272 + 256 + o2] = acc;
    }
  }
}

/* ------- fused impute + MLP + folded QKV proj + windowed 4x4 attention -------
   one wave per (b,v); 4 batches/block sharing one v. Weights read from GLOBAL
   with block-uniform indices -> scalar s_load operands (no LDS weight traffic).
   writes ao[((b*34+v)*46 + w)*16 + f] */
__global__ __launch_bounds__(256) void k_enc4(
    const float* __restrict__ arr, const float* __restrict__ msk,
    const float* __restrict__ cum, const float* __restrict__ last,
    const float* __restrict__ means, const unsigned int* __restrict__ maxv,
    const float* __restrict__ wdec, const float* __restrict__ bdec,
    const float* __restrict__ W1, const float* __restrict__ B1,
    const float* __restrict__ fw, const float* __restrict__ pqg,
    float* __restrict__ ao) {
  __shared__ float pkv[4][3][TT * 17];     /* per-wave P/K/V, stride 17 */
  const int v = blockIdx.x % VV;
  const int bgrp = blockIdx.x / VV;        /* grid = 34*128 */
  const int tid = threadIdx.x;
  const int wave = tid >> 6, lane = tid & 63;
  const int b = bgrp * 4 + wave;
  const float* fv = fw + v * 816;
  if (lane < TT) {
    const int t = lane;
    const int idx = (b * TT + t) * VV + v;
    float inv = 1.f / __uint_as_float(*maxv);
    float a = arr[idx], m = msk[idx];
    float cc = cum[idx] * inv;
    float ttc = fminf(fmaxf(wdec[v] * cc + bdec[v], 0.f), 1000.f);
    float dec = expf(-ttc);
    float xx = a * m + (1.f - m) * (dec * last[idx] + (1.f - dec) * means[b * VV + v]);
    float h[16];
    #pragma unroll
    for (int f = 0; f < 16; ++f)
      h[f] = fmaxf(xx * W1[v * 32 + f] + m * W1[v * 32 + 16 + f] + B1[v * 16 + f], 0.f);
    #pragma unroll
    for (int which = 0; which < 3; ++which) {
      const float* C = fv + which * 272;
      #pragma unroll
      for (int g = 0; g < 16; ++g) {
        float acc = C[256 + g];
        #pragma unroll
        for (int f = 0; f < 16; ++f) acc += h[f] * C[f * 16 + g];
        pkv[wave][which][t * 17 + g] = acc;
      }
    }
  }
  __syncthreads();
  if (lane < WW) {
    const int w = lane;
    const float* P = &pkv[wave][0][0];
    const float* K = &pkv[wave][1][0];
    const float* Vp = &pkv[wave][2][0];
    float kk[4][16];
    #pragma unroll
    for (int m = 0; m < 4; ++m)
      #pragma unroll
      for (int f = 0; f < 16; ++f)
        kk[m][f] = K[(w + m) * 17 + f] + pqg[2176 + m * 544 + v * 16 + f];
    float sc[4][4];
    #pragma unroll
    for (int l = 0; l < 4; ++l) {
      float qv[16];
      #pragma unroll
      for (int i = 0; i < 16; ++i)
        qv[i] = P[(w + l) * 17 + i] + pqg[l * 544 + v * 16 + i];
      #pragma unroll
      for (int m = 0; m < 4; ++m) {
        float s = 0.f;
        #pragma unroll
        for (int i = 0; i < 16; ++i) s += qv[i] * kk[m][i];
        sc[l][m] = s * 0.25f;
      }
    }
    float csum[4] = {0.f, 0.f, 0.f, 0.f};
    #pragma unroll
    for (int l = 0; l < 4; ++l) {
      float mx = fmaxf(fmaxf(sc[l][0], sc[l][1]), fmaxf(sc[l][2], sc[l][3]));
      float sum = 0.f;
      #pragma unroll
      for (int m = 0; m < 4; ++m) { sc[l][m] = expf(sc[l][m] - mx); sum += sc[l][m]; }
      float r = 1.f / sum;
      #pragma unroll
      for (int m = 0; m < 4; ++m) csum[m] += sc[l][m] * r;
    }
    float outv[16];
    #pragma unroll
    for (int f = 0; f < 16; ++f) outv[f] = 0.f;
    #pragma unroll
    for (int m = 0; m < 4; ++m) {
      float c = csum[m];
      #pragma unroll
      for (int f = 0; f < 16; ++f)
        outv[f] += c * (Vp[(w + m) * 17 + f] + pqg[2 * 2176 + m * 544 + v * 16 + f]);
    }
    float4* d4 = (float4*)(ao + ((size_t)(b * VV + v) * WW + w) * 16);
    #pragma unroll
    for (int j = 0; j < 4; ++j)
      d4[j] = make_float4(outv[4*j], outv[4*j+1], outv[4*j+2], outv[4*j+3]);
  }
}

/* ------- message passing (adj contraction) + V-axis PE fold, msg2 layout ------- */
#define MPW 12
__global__ __launch_bounds__(256) void k_mp(
    const float* __restrict__ ao, const float* __restrict__ adj,
    float* __restrict__ msg2) {
  __shared__ float adjs[VV * VV];
  __shared__ __align__(16) float aos[VV][MPW * 16];
  __shared__ float pes[VV * 16];
  const int bb = blockIdx.x >> 2;          /* grid = 512*4 */
  const int wt = blockIdx.x & 3;
  const int w0 = wt * MPW;
  const int wc = (wt == 3) ? (WW - 3 * MPW) : MPW;   /* 12,12,12,10 */
  const int tid = threadIdx.x;
  for (int i = tid; i < VV * VV; i += 256) adjs[i] = adj[i];
  for (int i = tid; i < VV * 16; i += 256) {
    int u = i >> 4, f = i & 15;
    int f2 = f & ~1;
    float dv = expf(-logf(10000.f) * (float)f2 / 16.f);
    float ang = (float)u * dv;
    pes[i] = (f & 1) ? cosf(ang) : sinf(ang);
  }
  const int nq = wc * 4;
  for (int i = tid; i < VV * nq; i += 256) {
    int vv2 = i / nq, r = i - vv2 * nq;
    int wl = r >> 2, q = r & 3;
    float4 val = *(const float4*)(ao + ((size_t)(bb * VV + vv2) * WW + w0 + wl) * 16 + q * 4);
    *(float4*)&aos[vv2][wl * 16 + q * 4] = val;
  }
  __syncthreads();
  for (int i = tid; i < VV * nq; i += 256) {
    int u = i / nq, r = i - u * nq;
    int wl = r >> 2, q = r & 3;
    float a0 = 0.f, a1 = 0.f, a2 = 0.f, a3 = 0.f;
    for (int vv2 = 0; vv2 < VV; ++vv2) {
      float a = adjs[u * VV + vv2];
      float4 s = *(const float4*)&aos[vv2][wl * 16 + q * 4];
      a0 += a * s.x; a1 += a * s.y; a2 += a * s.z; a3 += a * s.w;
    }
    float4 o = make_float4(a0 + pes[u * 16 + q * 4],
                           a1 + pes[u * 16 + q * 4 + 1],
                           a2 + pes[u * 16 + q * 4 + 2],
                           a3 + pes[u * 16 + q * 4 + 3]);
    *(float4*)(msg2 + ((size_t)(bb * VV + u) * WW + w0 + wl) * 16 + q * 4) = o;
  }
}

/* ---------------- signal attention v3: bilinear trick ---------------- */
__global__ __launch_bounds__(256) void k_sa3(
    const float* __restrict__ msg2, const float* __restrict__ saw,
    const float* __restrict__ Wv, const float* __restrict__ bv,
    float* __restrict__ sout) {
  __shared__ float As[256];              /* A^T: As[j*16+i] */
  __shared__ float ps[16], q2s[16];
  __shared__ float xs[SG][VV][20];
  __shared__ float zs[SG][VV][17];
  __shared__ float sc[SG][VV][VV];
  __shared__ float uws[SG][VV], vws[SG][VV];
  __shared__ float rs[SG][VV], cs[SG][VV];
  __shared__ float ys[SG][16];
  __shared__ float c0s;
  const int tid = threadIdx.x;
  const int n0 = blockIdx.x * SG;        /* grid 5888 exact */
  As[tid] = saw[tid];
  if (tid < 16) { ps[tid] = saw[256 + tid]; q2s[tid] = saw[272 + tid]; }
  if (tid == 0) c0s = saw[288];
  {
    const float4* src = (const float4*)(msg2 + (size_t)n0 * (VV * FF));
    for (int i = tid; i < SG * VV * 4; i += 256) {
      int g = i / 136, r = i - g * 136;
      int m = r >> 2, i4 = r & 3;
      float4 val = src[i];
      float* d = &xs[g][m][i4 * 4];
      d[0] = val.x; d[1] = val.y; d[2] = val.z; d[3] = val.w;
    }
  }
  __syncthreads();
  for (int idx = tid; idx < SG * VV * FF; idx += 256) {
    int g = idx / 544, r = idx - g * 544;
    int m = r >> 4, i = r & 15;
    float acc = 0.f;
    #pragma unroll
    for (int j = 0; j < FF; ++j) acc += As[j * 16 + i] * xs[g][m][j];
    zs[g][m][i] = acc;
  }
  if (tid < SG * VV) {
    int g = tid / VV, m = tid - g * VV;
    float pu = 0.f, pv = 0.f;
    #pragma unroll
    for (int i = 0; i < FF; ++i) { float x = xs[g][m][i]; pu += x * ps[i]; pv += x * q2s[i]; }
    uws[g][m] = pu; vws[g][m] = pv;
  }
  __syncthreads();
  for (int idx = tid; idx < SG * 17 * 17; idx += 256) {
    int g = idx / 289, r = idx - g * 289;
    int lt = r / 17, mt = r - lt * 17;
    int l0 = lt * 2, m0 = mt * 2;
    float s00 = 0.f, s01 = 0.f, s10 = 0.f, s11 = 0.f;
    #pragma unroll
    for (int i = 0; i < FF; ++i) {
      float x0 = xs[g][l0][i], x1 = xs[g][l0 + 1][i];
      float z0 = zs[g][m0][i], z1 = zs[g][m0 + 1][i];
      s00 += x0 * z0; s01 += x0 * z1; s10 += x1 * z0; s11 += x1 * z1;
    }
    float c0 = c0s;
    float ul0 = uws[g][l0], ul1 = uws[g][l0 + 1];
    float vm0 = vws[g][m0], vm1 = vws[g][m0 + 1];
    sc[g][l0][m0]         = (s00 + ul0 + vm0 + c0) * 0.25f;
    sc[g][l0][m0 + 1]     = (s01 + ul0 + vm1 + c0) * 0.25f;
    sc[g][l0 + 1][m0]     = (s10 + ul1 + vm0 + c0) * 0.25f;
    sc[g][l0 + 1][m0 + 1] = (s11 + ul1 + vm1 + c0) * 0.25f;
  }
  __syncthreads();
  if (tid < SG * VV) {
    int g = tid / VV, l = tid - g * VV;
    float mx = -1e30f;
    for (int m = 0; m < VV; ++m) mx = fmaxf(mx, sc[g][l][m]);
    float sum = 0.f;
    for (int m = 0; m < VV; ++m) { float e = expf(sc[g][l][m] - mx); sc[g][l][m] = e; sum += e; }
    rs[g][l] = 1.f / sum;
  }
  __syncthreads();
  if (tid < SG * VV) {
    int g = tid / VV, m = tid - g * VV;
    float acc = 0.f;
    for (int l = 0; l < VV; ++l) acc += sc[g][l][m] * rs[g][l];
    cs[g][m] = acc;
  }
  __syncthreads();
  if (tid < SG * FF) {
    int g = tid >> 4, i = tid & 15;
    float acc = 0.f;
    for (int m = 0; m < VV; ++m) acc += cs[g][m] * xs[g][m][i];
    ys[g][i] = acc;
  }
  __syncthreads();
  if (tid < SG * FF) {
    int g = tid >> 4, f = tid & 15;
    float acc = 34.f * bv[f];
    #pragma unroll
    for (int i = 0; i < FF; ++i) acc += ys[g][i] * Wv[i * 16 + f];
    sout[(size_t)(n0 + g) * FF + f] = acc;
  }
}

/* ---------------- GRU input projections ---------------- */
__global__ __launch_bounds__(256) void k_xw1(
    const float* __restrict__ x, const float* __restrict__ Wih,
    const float* __restrict__ bih, float* __restrict__ xw) {
  int t = blockIdx.x * 256 + threadIdx.x;
  int n = t / TH3, o = t - n * TH3;
  float acc = bih[o];
  const float* xr = x + (size_t)n * FF;
  #pragma unroll
  for (int i = 0; i < FF; ++i) acc += xr[i] * Wih[i * TH3 + o];
  xw[t] = acc;
}

__global__ __launch_bounds__(192) void k_xw2(
    const float* __restrict__ x, const float* __restrict__ Wih,
    const float* __restrict__ bih, float* __restrict__ xw) {
  __shared__ float xsh[16][HH];
  int n0 = blockIdx.x * 16;
  int tid = threadIdx.x;
  for (int idx = tid; idx < 16 * HH; idx += 192) {
    int ns = idx >> 6, i = idx & 63;
    xsh[ns][i] = x[(size_t)(n0 + ns) * HH + i];
  }
  __syncthreads();
  float acc[16];
  float bb = bih[tid];
  #pragma unroll
  for (int ns = 0; ns < 16; ++ns) acc[ns] = bb;
  for (int i = 0; i < HH; ++i) {
    float wv = Wih[i * TH3 + tid];
    #pragma unroll
    for (int ns = 0; ns < 16; ++ns) acc[ns] += xsh[ns][i] * wv;
  }
  #pragma unroll
  for (int ns = 0; ns < 16; ++ns) xw[(size_t)(n0 + ns) * TH3 + tid] = acc[ns];
}

/* ---------------- GRU serial scan ---------------- */
__global__ __launch_bounds__(192) void k_gru(
    const float* __restrict__ xw, const float* __restrict__ Whh,
    const float* __restrict__ bhh, float* __restrict__ gout) {
  __shared__ float whh[HH * TH3];
  __shared__ float hsh[HH];
  __shared__ float gh[TH3];
  int tid = threadIdx.x;
  int b = blockIdx.x;
  for (int i = tid; i < HH * TH3; i += 192) whh[i] = Whh[i];
  if (tid < HH) hsh[tid] = 0.f;
  float bb = bhh[tid];
  __syncthreads();
  for (int w = 0; w < WW; ++w) {
    float acc = bb;
    #pragma unroll 8
    for (int i = 0; i < HH; ++i) acc += hsh[i] * whh[i * TH3 + tid];
    gh[tid] = acc;
    __syncthreads();
    if (tid < HH) {
      const float* xr = xw + (size_t)(b * WW + w) * TH3;
      float r = 1.f / (1.f + expf(-(xr[tid] + gh[tid])));
      float z = 1.f / (1.f + expf(-(xr[HH + tid] + gh[HH + tid])));
      float nn = tanhf(xr[2 * HH + tid] + r * gh[2 * HH + tid]);
      float hn = (1.f - z) * nn + z * hsh[tid];
      hsh[tid] = hn;
      gout[(size_t)(b * WW + w) * HH + tid] = hn;
    }
    __syncthreads();
  }
}

/* ---------------- temporal attention + classifier ---------------- */
__global__ __launch_bounds__(256) void k_ta(
    const float* __restrict__ g2,
    const float* __restrict__ Wq, const float* __restrict__ bq,
    const float* __restrict__ Wk, const float* __restrict__ bk,
    const float* __restrict__ Wv, const float* __restrict__ bv,
    const float* __restrict__ cW1, const float* __restrict__ cb1,
    const float* __restrict__ cW2, const float* __restrict__ cb2,
    float* __restrict__ out) {
  __shared__ float xt[WW * 65];
  __shared__ float QKVs[3][WW * 65];
  __shared__ float sc[WW * WW];
  __shared__ float cs[WW];
  __shared__ float tval[HH];
  __shared__ float hrelu[HH];
  int tid = threadIdx.x;
  int b = blockIdx.x;
  for (int idx = tid; idx < WW * HH; idx += 256) {
    int w = idx >> 6, d = idx & 63;
    int f2 = d & ~1;
    float dv = expf(-logf(10000.f) * (float)f2 / (float)HH);
    float ang = (float)w * dv;
    float pe = (d & 1) ? cosf(ang) : sinf(ang);
    xt[w * 65 + d] = g2[(size_t)(b * WW + w) * HH + d] + pe;
  }
  __syncthreads();
  if (tid < 192) {
    int which = tid >> 6, d = tid & 63;
    const float* Wt = which == 0 ? Wq : which == 1 ? Wk : Wv;
    float bias = (which == 0 ? bq : which == 1 ? bk : bv)[d];
    float col[HH];
    #pragma unroll
    for (int i = 0; i < HH; ++i) col[i] = Wt[i * HH + d];
    float* dst = &QKVs[which][0];
    for (int w = 0; w < WW; ++w) {
      float acc = bias;
      #pragma unroll
      for (int i = 0; i < HH; ++i) acc += xt[w * 65 + i] * col[i];
      dst[w * 65 + d] = acc;
    }
  }
  __syncthreads();
  for (int idx = tid; idx < WW * WW; idx += 256) {
    int l = idx / WW, m = idx - l * WW;
    float s = 0.f;
    #pragma unroll
    for (int i = 0; i < HH; ++i) s += QKVs[0][l * 65 + i] * QKVs[1][m * 65 + i];
    sc[idx] = s * 0.125f;
  }
  __syncthreads();
  if (tid < WW) {
    float mx = -1e30f;
    for (int m = 0; m < WW; ++m) mx = fmaxf(mx, sc[tid * WW + m]);
    float sum = 0.f;
    for (int m = 0; m < WW; ++m) { float e = expf(sc[tid * WW + m] - mx); sc[tid * WW + m] = e; sum += e; }
    float r = 1.f / sum;
    for (int m = 0; m < WW; ++m) sc[tid * WW + m] *= r;
  }
  __syncthreads();
  if (tid < WW) {
    float s = 0.f;
    for (int l = 0; l < WW; ++l) s += sc[l * WW + tid];
    cs[tid] = s;
  }
  __syncthreads();
  if (tid < HH) {
    float acc = 0.f;
    for (int m = 0; m < WW; ++m) acc += cs[m] * QKVs[2][m * 65 + tid];
    tval[tid] = acc;
  }
  __syncthreads();
  if (tid < HH) {
    float acc = cb1[tid];
    #pragma unroll
    for (int d = 0; d < HH; ++d) acc += tval[d] * cW1[d * HH + tid];
    hrelu[tid] = fmaxf(acc, 0.f);
  }
  __syncthreads();
  if (tid == 0) {
    float acc = cb2[0];
    for (int j = 0; j < HH; ++j) acc += hrelu[j] * cW2[j];
    out[b] = acc;
  }
}

extern "C" void kernel_launch(void* const* d_in, const int* in_sizes, int n_in,
                              void* d_out, int out_size, void* d_ws, size_t ws_size,
                              hipStream_t stream) {
  (void)in_sizes; (void)n_in; (void)out_size; (void)ws_size;
  const float* arr    = (const float*)d_in[0];
  const float* msk    = (const float*)d_in[1];
  const float* timeTB = (const float*)d_in[2];
  const float* wdec   = (const float*)d_in[3];
  const float* bdec   = (const float*)d_in[4];
  const float* encW1  = (const float*)d_in[5];
  const float* encB1  = (const float*)d_in[6];
  const float* encW2  = (const float*)d_in[7];
  const float* encB2  = (const float*)d_in[8];
  const float* tlaWq  = (const float*)d_in[9];
  const float* tlaBq  = (const float*)d_in[10];
  const float* tlaWk  = (const float*)d_in[11];
  const float* tlaBk  = (const float*)d_in[12];
  const float* tlaWv  = (const float*)d_in[13];
  const float* tlaBv  = (const float*)d_in[14];
  const float* adj    = (const float*)d_in[15];
  const float* saWq   = (const float*)d_in[20];
  const float* saBq   = (const float*)d_in[21];
  const float* saWk   = (const float*)d_in[22];
  const float* saBk   = (const float*)d_in[23];
  const float* saWv   = (const float*)d_in[24];
  const float* saBv   = (const float*)d_in[25];
  const float* gWih0  = (const float*)d_in[26];
  const float* gWhh0  = (const float*)d_in[27];
  const float* gBih0  = (const float*)d_in[28];
  const float* gBhh0  = (const float*)d_in[29];
  const float* gWih1  = (const float*)d_in[30];
  const float* gWhh1  = (const float*)d_in[31];
  const float* gBih1  = (const float*)d_in[32];
  const float* gBhh1  = (const float*)d_in[33];
  const float* taWq   = (const float*)d_in[34];
  const float* taBq   = (const float*)d_in[35];
  const float* taWk   = (const float*)d_in[36];
  const float* taBk   = (const float*)d_in[37];
  const float* taWv   = (const float*)d_in[38];
  const float* taBv   = (const float*)d_in[39];
  const float* cW1    = (const float*)d_in[40];
  const float* cb1    = (const float*)d_in[41];
  const float* cW2    = (const float*)d_in[42];
  const float* cb2    = (const float*)d_in[43];
  float* out = (float*)d_out;
  float* ws  = (float*)d_ws;

  float* ao    = ws + AO_OFF;
  float* msg2  = ws + MSG2_OFF;
  float* cum   = ws + CUM2_OFF;
  float* last  = ws + LAST2_OFF;
  float* means = ws + MEANS2_OFF;
  unsigned int* maxv = (unsigned int*)(ws + MAX2_OFF);
  float* pqg   = ws + PQ_OFF;
  float* saw   = ws + SAW_OFF;
  float* fw    = ws + FW_OFF;

  float* sout = ws + SOUT_OFF;
  float* xw1  = ws + XW1_OFF;
  float* g1   = ws + G1_OFF;
  float* xw2  = ws + XW2_OFF;
  float* g2   = ws + G2_OFF;

  hipMemsetAsync(maxv, 0, sizeof(unsigned int), stream);
  k_scan<<<68, 256, 0, stream>>>(arr, msk, timeTB, cum, last, means, maxv);
  k_prep<<<61, 256, 0, stream>>>(tlaWq, tlaWk, tlaWv, tlaBq, tlaBk, tlaBv,
                                 saWq, saBq, saWk, saBk, encW2, encB2,
                                 pqg, saw, fw);
  k_enc4<<<VV * 128, 256, 0, stream>>>(arr, msk, cum, last, means, maxv,
                                       wdec, bdec, encW1, encB1, fw, pqg, ao);
  k_mp<<<BB * 4, 256, 0, stream>>>(ao, adj, msg2);
  k_sa3<<<BW / SG, 256, 0, stream>>>(msg2, saw, saWv, saBv, sout);
  k_xw1<<<(BW * TH3) / 256, 256, 0, stream>>>(sout, gWih0, gBih0, xw1);
  k_gru<<<BB, 192, 0, stream>>>(xw1, gWhh0, gBhh0, g1);
  k_xw2<<<BW / 16, 192, 0, stream>>>(g1, gWih1, gBih1, xw2);
  k_gru<<<BB, 192, 0, stream>>>(xw2, gWhh1, gBhh1, g2);
  k_ta<<<BB, 256, 0, stream>>>(g2, taWq, taBq, taWk, taBk, taWv, taBv,
                               cW1, cb1, cW2, cb2, out);
}

// Round 7
// 408.003 us; speedup vs baseline: 2.4147x; 1.0128x over previous
//
#include <hip/hip_runtime.h>
#include <math.h>

#define BB 512
#define TT 49
#define VV 34
#define FF 16
#define HH 64
#define WWIN 4
#define WW 46
#define BW (BB*WW)        /* 23552 */
#define TH3 (3*HH)        /* 192 */
#define ROWS 25088        /* B*T */
#define SG 2              /* windows per k_sa3 block */

/* GRU-region (offsets in floats, region 0 .. 12,435,456) */
#define SOUT_OFF   0ull                   /* BW*F = 376832 */
#define XW1_OFF    376832ull              /* BW*192 */
#define G1_OFF     (XW1_OFF + 4521984ull)
#define XW2_OFF    (G1_OFF + 1507328ull)
#define G2_OFF     (XW2_OFF + 4521984ull) /* ends 12435456 */

#define MSG_SZ     12812288ull            /* BW*V*F = B*V*W*F */
#define CUM_SZ     852992ull              /* B*T*V */
#define MEANS_SZ   17408ull               /* B*V */
#define AO_OFF     12435456ull
#define MSG2_OFF   (AO_OFF + MSG_SZ)      /* 25247744 */
#define CUM2_OFF   (MSG2_OFF + MSG_SZ)    /* 38060032 */
#define LAST2_OFF  (CUM2_OFF + CUM_SZ)
#define MEANS2_OFF (LAST2_OFF + CUM_SZ)
#define MAX2_OFF   (MEANS2_OFF + MEANS_SZ)
#define PQ_OFF     (MAX2_OFF + 4ull)
#define SAW_OFF    (PQ_OFF + 6528ull)
#define FW_OFF     (SAW_OFF + 292ull)     /* 34*816 = 27744 floats */

/* ---------------- kernel 1: impute scan + global max + means ---------------- */
__global__ __launch_bounds__(256) void k_scan(
    const float* __restrict__ arr, const float* __restrict__ msk,
    const float* __restrict__ timeTB,
    float* __restrict__ cum, float* __restrict__ last,
    float* __restrict__ means, unsigned int* __restrict__ maxv) {
  int tid = blockIdx.x * 256 + threadIdx.x;     /* 0..17407, exact */
  int b = tid / VV, v = tid - b * VV;
  const int base = b * TT * VV + v;
  float x = arr[base];
  float c = 0.f, lm = 0.f, s = x;
  cum[base] = 0.f;
  last[base] = x;
  float tp = timeTB[b];
  for (int t = 1; t < TT; ++t) {
    float tc = timeTB[t * BB + b];
    float d = tc - tp; tp = tc;
    int e = base + t * VV;
    float a = arr[e], m = msk[e];
    float miss = (m == 0.f) ? 1.f : 0.f;
    c = d + c * miss;
    x = (miss > 0.f) ? x : a;
    cum[e] = c; last[e] = x;
    lm = fmaxf(lm, c);
    s += a;
  }
  means[tid] = s * (1.f / 49.f);
  #pragma unroll
  for (int off = 32; off; off >>= 1) lm = fmaxf(lm, __shfl_xor(lm, off));
  if ((threadIdx.x & 63) == 0) atomicMax(maxv, __float_as_uint(lm));
}

/* ---------------- prep: PE projections + SA bilinear + enc weight folding ---------------- */
__global__ __launch_bounds__(256) void k_prep(
    const float* __restrict__ tlaWq, const float* __restrict__ tlaWk,
    const float* __restrict__ tlaWv,
    const float* __restrict__ tlaBq, const float* __restrict__ tlaBk,
    const float* __restrict__ tlaBv,
    const float* __restrict__ saWq, const float* __restrict__ saBq,
    const float* __restrict__ saWk, const float* __restrict__ saBk,
    const float* __restrict__ encW2, const float* __restrict__ encB2,
    float* __restrict__ pqg, float* __restrict__ saw, float* __restrict__ fw) {
  const int bid = blockIdx.x;
  const int t = threadIdx.x;
  if (bid < 26) {
    int idx = bid * 256 + t;
    if (idx >= 6528) return;
    int which = idx / 2176;
    int r = idx - which * 2176;
    int l = r / 544;
    int rr = r - l * 544;
    int v = rr >> 4, f = rr & 15;
    const float* W = which == 0 ? tlaWq : which == 1 ? tlaWk : tlaWv;
    float acc = 0.f;
    #pragma unroll
    for (int i = 0; i < FF; ++i) {
      int i2 = i & ~1;
      float dv = expf(-logf(10000.f) * (float)i2 / (float)FF);
      float ang = (float)l * dv;
      float pe = (i & 1) ? cosf(ang) : sinf(ang);
      acc += pe * W[v * 256 + i * 16 + f];
    }
    pqg[idx] = acc;
  } else if (bid == 26) {
    int i = t & 15, j = t >> 4;
    float a = 0.f;
    #pragma unroll
    for (int f = 0; f < 16; ++f) a += saWq[i * 16 + f] * saWk[j * 16 + f];
    saw[j * 16 + i] = a;                    /* transposed store: [j][i] */
    if (t < 16) {
      float pp = 0.f, qq = 0.f;
      #pragma unroll
      for (int f = 0; f < 16; ++f) { pp += saWq[t * 16 + f] * saBk[f]; qq += saWk[t * 16 + f] * saBq[f]; }
      saw[256 + t] = pp;
      saw[272 + t] = qq;
    }
    if (t == 0) {
      float c = 0.f;
      #pragma unroll
      for (int f = 0; f < 16; ++f) c += saBq[f] * saBk[f];
      saw[288] = c;
    }
  } else {
    const int v = bid - 27;
    const int f = t >> 4, o = t & 15;
    const float* W2v = encW2 + v * 256;
    float cq = 0.f, ck = 0.f, cv = 0.f;
    #pragma unroll
    for (int g = 0; g < 16; ++g) {
      float w2 = W2v[f * 16 + g];
      cq += w2 * tlaWq[v * 256 + g * 16 + o];
      ck += w2 * tlaWk[v * 256 + g * 16 + o];
      cv += w2 * tlaWv[v * 256 + g * 16 + o];
    }
    fw[v * 816 + 0 * 272 + f * 16 + o] = cq;
    fw[v * 816 + 1 * 272 + f * 16 + o] = ck;
    fw[v * 816 + 2 * 272 + f * 16 + o] = cv;
    if (t < 48) {
      int which = t >> 4, o2 = t & 15;
      const float* Wp = which == 0 ? tlaWq : which == 1 ? tlaWk : tlaWv;
      const float* Bp = which == 0 ? tlaBq : which == 1 ? tlaBk : tlaBv;
      float acc = Bp[v * 16 + o2];
      #pragma unroll
      for (int g = 0; g < 16; ++g) acc += encB2[v * 16 + g] * Wp[v * 256 + g * 16 + o2];
      fw[v * 816 + which * 272 + 256 + o2] = acc;
    }
  }
}

/* ------- fused impute + MLP + folded QKV proj + windowed 4x4 attention ------- */
__global__ __launch_bounds__(256) void k_enc4(
    const float* __restrict__ arr, const float* __restrict__ msk,
    const float* __restrict__ cum, const float* __restrict__ last,
    const float* __restrict__ means, const unsigned int* __restrict__ maxv,
    const float* __restrict__ wdec, const float* __restrict__ bdec,
    const float* __restrict__ W1, const float* __restrict__ B1,
    const float* __restrict__ fw, const float* __restrict__ pqg,
    float* __restrict__ ao) {
  __shared__ float pkv[4][3][TT * 17];     /* per-wave P/K/V, stride 17 */
  const int v = blockIdx.x % VV;
  const int bgrp = blockIdx.x / VV;        /* grid = 34*128 */
  const int tid = threadIdx.x;
  const int wave = tid >> 6, lane = tid & 63;
  const int b = bgrp * 4 + wave;
  const float* fv = fw + v * 816;
  if (lane < TT) {
    const int t = lane;
    const int idx = (b * TT + t) * VV + v;
    float inv = 1.f / __uint_as_float(*maxv);
    float a = arr[idx], m = msk[idx];
    float cc = cum[idx] * inv;
    float ttc = fminf(fmaxf(wdec[v] * cc + bdec[v], 0.f), 1000.f);
    float dec = expf(-ttc);
    float xx = a * m + (1.f - m) * (dec * last[idx] + (1.f - dec) * means[b * VV + v]);
    float h[16];
    #pragma unroll
    for (int f = 0; f < 16; ++f)
      h[f] = fmaxf(xx * W1[v * 32 + f] + m * W1[v * 32 + 16 + f] + B1[v * 16 + f], 0.f);
    #pragma unroll
    for (int which = 0; which < 3; ++which) {
      const float* C = fv + which * 272;
      #pragma unroll
      for (int g = 0; g < 16; ++g) {
        float acc = C[256 + g];
        #pragma unroll
        for (int f = 0; f < 16; ++f) acc += h[f] * C[f * 16 + g];
        pkv[wave][which][t * 17 + g] = acc;
      }
    }
  }
  __syncthreads();
  if (lane < WW) {
    const int w = lane;
    const float* P = &pkv[wave][0][0];
    const float* K = &pkv[wave][1][0];
    const float* Vp = &pkv[wave][2][0];
    float kk[4][16];
    #pragma unroll
    for (int m = 0; m < 4; ++m)
      #pragma unroll
      for (int f = 0; f < 16; ++f)
        kk[m][f] = K[(w + m) * 17 + f] + pqg[2176 + m * 544 + v * 16 + f];
    float sc[4][4];
    #pragma unroll
    for (int l = 0; l < 4; ++l) {
      float qv[16];
      #pragma unroll
      for (int i = 0; i < 16; ++i)
        qv[i] = P[(w + l) * 17 + i] + pqg[l * 544 + v * 16 + i];
      #pragma unroll
      for (int m = 0; m < 4; ++m) {
        float s = 0.f;
        #pragma unroll
        for (int i = 0; i < 16; ++i) s += qv[i] * kk[m][i];
        sc[l][m] = s * 0.25f;
      }
    }
    float csum[4] = {0.f, 0.f, 0.f, 0.f};
    #pragma unroll
    for (int l = 0; l < 4; ++l) {
      float mx = fmaxf(fmaxf(sc[l][0], sc[l][1]), fmaxf(sc[l][2], sc[l][3]));
      float sum = 0.f;
      #pragma unroll
      for (int m = 0; m < 4; ++m) { sc[l][m] = expf(sc[l][m] - mx); sum += sc[l][m]; }
      float r = 1.f / sum;
      #pragma unroll
      for (int m = 0; m < 4; ++m) csum[m] += sc[l][m] * r;
    }
    float outv[16];
    #pragma unroll
    for (int f = 0; f < 16; ++f) outv[f] = 0.f;
    #pragma unroll
    for (int m = 0; m < 4; ++m) {
      float c = csum[m];
      #pragma unroll
      for (int f = 0; f < 16; ++f)
        outv[f] += c * (Vp[(w + m) * 17 + f] + pqg[2 * 2176 + m * 544 + v * 16 + f]);
    }
    float4* d4 = (float4*)(ao + ((size_t)(b * VV + v) * WW + w) * 16);
    #pragma unroll
    for (int j = 0; j < 4; ++j)
      d4[j] = make_float4(outv[4*j], outv[4*j+1], outv[4*j+2], outv[4*j+3]);
  }
}

/* ------- message passing (adj contraction) + V-axis PE fold, msg2 layout ------- */
#define MPW 12
__global__ __launch_bounds__(256) void k_mp(
    const float* __restrict__ ao, const float* __restrict__ adj,
    float* __restrict__ msg2) {
  __shared__ float adjs[VV * VV];
  __shared__ __align__(16) float aos[VV][MPW * 16];
  __shared__ float pes[VV * 16];
  const int bb = blockIdx.x >> 2;          /* grid = 512*4 */
  const int wt = blockIdx.x & 3;
  const int w0 = wt * MPW;
  const int wc = (wt == 3) ? (WW - 3 * MPW) : MPW;   /* 12,12,12,10 */
  const int tid = threadIdx.x;
  for (int i = tid; i < VV * VV; i += 256) adjs[i] = adj[i];
  for (int i = tid; i < VV * 16; i += 256) {
    int u = i >> 4, f = i & 15;
    int f2 = f & ~1;
    float dv = expf(-logf(10000.f) * (float)f2 / 16.f);
    float ang = (float)u * dv;
    pes[i] = (f & 1) ? cosf(ang) : sinf(ang);
  }
  const int nq = wc * 4;
  for (int i = tid; i < VV * nq; i += 256) {
    int vv2 = i / nq, r = i - vv2 * nq;
    int wl = r >> 2, q = r & 3;
    float4 val = *(const float4*)(ao + ((size_t)(bb * VV + vv2) * WW + w0 + wl) * 16 + q * 4);
    *(float4*)&aos[vv2][wl * 16 + q * 4] = val;
  }
  __syncthreads();
  for (int i = tid; i < VV * nq; i += 256) {
    int u = i / nq, r = i - u * nq;
    int wl = r >> 2, q = r & 3;
    float a0 = 0.f, a1 = 0.f, a2 = 0.f, a3 = 0.f;
    for (int vv2 = 0; vv2 < VV; ++vv2) {
      float a = adjs[u * VV + vv2];
      float4 s = *(const float4*)&aos[vv2][wl * 16 + q * 4];
      a0 += a * s.x; a1 += a * s.y; a2 += a * s.z; a3 += a * s.w;
    }
    float4 o = make_float4(a0 + pes[u * 16 + q * 4],
                           a1 + pes[u * 16 + q * 4 + 1],
                           a2 + pes[u * 16 + q * 4 + 2],
                           a3 + pes[u * 16 + q * 4 + 3]);
    *(float4*)(msg2 + ((size_t)(bb * VV + u) * WW + w0 + wl) * 16 + q * 4) = o;
  }
}

/* ---------------- signal attention v4: SG=2, high occupancy, stride-35 sc ---------------- */
__global__ __launch_bounds__(256) void k_sa3(
    const float* __restrict__ msg2, const float* __restrict__ saw,
    const float* __restrict__ Wv, const float* __restrict__ bv,
    float* __restrict__ sout) {
  __shared__ float As[256];              /* A^T: As[j*16+i] */
  __shared__ float ps[16], q2s[16];
  __shared__ float xs[SG][VV][20];
  __shared__ float zs[SG][VV][17];
  __shared__ float sc[SG][VV][35];       /* stride 35: odd -> conflict-free walks */
  __shared__ float uws[SG][VV], vws[SG][VV];
  __shared__ float rs[SG][VV], cs[SG][VV];
  __shared__ float ys[SG][16];
  __shared__ float c0s;
  const int tid = threadIdx.x;
  const int n0 = blockIdx.x * SG;        /* grid 11776 exact */
  As[tid] = saw[tid];
  if (tid < 16) { ps[tid] = saw[256 + tid]; q2s[tid] = saw[272 + tid]; }
  if (tid == 0) c0s = saw[288];
  {
    const float4* src = (const float4*)(msg2 + (size_t)n0 * (VV * FF));
    for (int i = tid; i < SG * VV * 4; i += 256) {
      int g = i / 136, r = i - g * 136;
      int m = r >> 2, i4 = r & 3;
      float4 val = src[i];
      float* d = &xs[g][m][i4 * 4];
      d[0] = val.x; d[1] = val.y; d[2] = val.z; d[3] = val.w;
    }
  }
  __syncthreads();
  /* phase1: Z = A X^T; u,w side vectors */
  for (int idx = tid; idx < SG * VV * FF; idx += 256) {
    int g = idx / 544, r = idx - g * 544;
    int m = r >> 4, i = r & 15;
    float acc = 0.f;
    #pragma unroll
    for (int j = 0; j < FF; ++j) acc += As[j * 16 + i] * xs[g][m][j];
    zs[g][m][i] = acc;
  }
  if (tid < SG * VV) {
    int g = tid / VV, m = tid - g * VV;
    float pu = 0.f, pv = 0.f;
    #pragma unroll
    for (int i = 0; i < FF; ++i) { float x = xs[g][m][i]; pu += x * ps[i]; pv += x * q2s[i]; }
    uws[g][m] = pu; vws[g][m] = pv;
  }
  __syncthreads();
  /* phase2: scores, 2x2 register tiles */
  for (int idx = tid; idx < SG * 17 * 17; idx += 256) {
    int g = idx / 289, r = idx - g * 289;
    int lt = r / 17, mt = r - lt * 17;
    int l0 = lt * 2, m0 = mt * 2;
    float s00 = 0.f, s01 = 0.f, s10 = 0.f, s11 = 0.f;
    #pragma unroll
    for (int i = 0; i < FF; ++i) {
      float x0 = xs[g][l0][i], x1 = xs[g][l0 + 1][i];
      float z0 = zs[g][m0][i], z1 = zs[g][m0 + 1][i];
      s00 += x0 * z0; s01 += x0 * z1; s10 += x1 * z0; s11 += x1 * z1;
    }
    float c0 = c0s;
    float ul0 = uws[g][l0], ul1 = uws[g][l0 + 1];
    float vm0 = vws[g][m0], vm1 = vws[g][m0 + 1];
    sc[g][l0][m0]         = (s00 + ul0 + vm0 + c0) * 0.25f;
    sc[g][l0][m0 + 1]     = (s01 + ul0 + vm1 + c0) * 0.25f;
    sc[g][l0 + 1][m0]     = (s10 + ul1 + vm0 + c0) * 0.25f;
    sc[g][l0 + 1][m0 + 1] = (s11 + ul1 + vm1 + c0) * 0.25f;
  }
  __syncthreads();
  /* phase3: row softmax (store exp, defer 1/sum) */
  if (tid < SG * VV) {
    int g = tid / VV, l = tid - g * VV;
    float mx = -1e30f;
    for (int m = 0; m < VV; ++m) mx = fmaxf(mx, sc[g][l][m]);
    float sum = 0.f;
    for (int m = 0; m < VV; ++m) { float e = expf(sc[g][l][m] - mx); sc[g][l][m] = e; sum += e; }
    rs[g][l] = 1.f / sum;
  }
  __syncthreads();
  /* phase4: column sums */
  if (tid < SG * VV) {
    int g = tid / VV, m = tid - g * VV;
    float acc = 0.f;
    for (int l = 0; l < VV; ++l) acc += sc[g][l][m] * rs[g][l];
    cs[g][m] = acc;
  }
  __syncthreads();
  /* phase5: y = cs . X */
  if (tid < SG * FF) {
    int g = tid >> 4, i = tid & 15;
    float acc = 0.f;
    for (int m = 0; m < VV; ++m) acc += cs[g][m] * xs[g][m][i];
    ys[g][i] = acc;
  }
  __syncthreads();
  /* phase6: sout = y.Wv + 34*bv */
  if (tid < SG * FF) {
    int g = tid >> 4, f = tid & 15;
    float acc = 34.f * bv[f];
    #pragma unroll
    for (int i = 0; i < FF; ++i) acc += ys[g][i] * Wv[i * 16 + f];
    sout[(size_t)(n0 + g) * FF + f] = acc;
  }
}

/* ---------------- GRU input projections ---------------- */
__global__ __launch_bounds__(256) void k_xw1(
    const float* __restrict__ x, const float* __restrict__ Wih,
    const float* __restrict__ bih, float* __restrict__ xw) {
  int t = blockIdx.x * 256 + threadIdx.x;
  int n = t / TH3, o = t - n * TH3;
  float acc = bih[o];
  const float* xr = x + (size_t)n * FF;
  #pragma unroll
  for (int i = 0; i < FF; ++i) acc += xr[i] * Wih[i * TH3 + o];
  xw[t] = acc;
}

__global__ __launch_bounds__(192) void k_xw2(
    const float* __restrict__ x, const float* __restrict__ Wih,
    const float* __restrict__ bih, float* __restrict__ xw) {
  __shared__ float xsh[16][HH];
  int n0 = blockIdx.x * 16;
  int tid = threadIdx.x;
  for (int idx = tid; idx < 16 * HH; idx += 192) {
    int ns = idx >> 6, i = idx & 63;
    xsh[ns][i] = x[(size_t)(n0 + ns) * HH + i];
  }
  __syncthreads();
  float acc[16];
  float bb = bih[tid];
  #pragma unroll
  for (int ns = 0; ns < 16; ++ns) acc[ns] = bb;
  for (int i = 0; i < HH; ++i) {
    float wv = Wih[i * TH3 + tid];
    #pragma unroll
    for (int ns = 0; ns < 16; ++ns) acc[ns] += xsh[ns][i] * wv;
  }
  #pragma unroll
  for (int ns = 0; ns < 16; ++ns) xw[(size_t)(n0 + ns) * TH3 + tid] = acc[ns];
}

/* ---------------- GRU serial scan ---------------- */
__global__ __launch_bounds__(192) void k_gru(
    const float* __restrict__ xw, const float* __restrict__ Whh,
    const float* __restrict__ bhh, float* __restrict__ gout) {
  __shared__ float whh[HH * TH3];
  __shared__ float hsh[HH];
  __shared__ float gh[TH3];
  int tid = threadIdx.x;
  int b = blockIdx.x;
  for (int i = tid; i < HH * TH3; i += 192) whh[i] = Whh[i];
  if (tid < HH) hsh[tid] = 0.f;
  float bb = bhh[tid];
  __syncthreads();
  for (int w = 0; w < WW; ++w) {
    float acc = bb;
    #pragma unroll 8
    for (int i = 0; i < HH; ++i) acc += hsh[i] * whh[i * TH3 + tid];
    gh[tid] = acc;
    __syncthreads();
    if (tid < HH) {
      const float* xr = xw + (size_t)(b * WW + w) * TH3;
      float r = 1.f / (1.f + expf(-(xr[tid] + gh[tid])));
      float z = 1.f / (1.f + expf(-(xr[HH + tid] + gh[HH + tid])));
      float nn = tanhf(xr[2 * HH + tid] + r * gh[2 * HH + tid]);
      float hn = (1.f - z) * nn + z * hsh[tid];
      hsh[tid] = hn;
      gout[(size_t)(b * WW + w) * HH + tid] = hn;
    }
    __syncthreads();
  }
}

/* ---------------- temporal attention + classifier ---------------- */
__global__ __launch_bounds__(256) void k_ta(
    const float* __restrict__ g2,
    const float* __restrict__ Wq, const float* __restrict__ bq,
    const float* __restrict__ Wk, const float* __restrict__ bk,
    const float* __restrict__ Wv, const float* __restrict__ bv,
    const float* __restrict__ cW1, const float* __restrict__ cb1,
    const float* __restrict__ cW2, const float* __restrict__ cb2,
    float* __restrict__ out) {
  __shared__ float xt[WW * 65];
  __shared__ float QKVs[3][WW * 65];
  __shared__ float sc[WW * WW];
  __shared__ float cs[WW];
  __shared__ float tval[HH];
  __shared__ float hrelu[HH];
  int tid = threadIdx.x;
  int b = blockIdx.x;
  for (int idx = tid; idx < WW * HH; idx += 256) {
    int w = idx >> 6, d = idx & 63;
    int f2 = d & ~1;
    float dv = expf(-logf(10000.f) * (float)f2 / (float)HH);
    float ang = (float)w * dv;
    float pe = (d & 1) ? cosf(ang) : sinf(ang);
    xt[w * 65 + d] = g2[(size_t)(b * WW + w) * HH + d] + pe;
  }
  __syncthreads();
  if (tid < 192) {
    int which = tid >> 6, d = tid & 63;
    const float* Wt = which == 0 ? Wq : which == 1 ? Wk : Wv;
    float bias = (which == 0 ? bq : which == 1 ? bk : bv)[d];
    float col[HH];
    #pragma unroll
    for (int i = 0; i < HH; ++i) col[i] = Wt[i * HH + d];
    float* dst = &QKVs[which][0];
    for (int w = 0; w < WW; ++w) {
      float acc = bias;
      #pragma unroll
      for (int i = 0; i < HH; ++i) acc += xt[w * 65 + i] * col[i];
      dst[w * 65 + d] = acc;
    }
  }
  __syncthreads();
  for (int idx = tid; idx < WW * WW; idx += 256) {
    int l = idx / WW, m = idx - l * WW;
    float s = 0.f;
    #pragma unroll
    for (int i = 0; i < HH; ++i) s += QKVs[0][l * 65 + i] * QKVs[1][m * 65 + i];
    sc[idx] = s * 0.125f;
  }
  __syncthreads();
  if (tid < WW) {
    float mx = -1e30f;
    for (int m = 0; m < WW; ++m) mx = fmaxf(mx, sc[tid * WW + m]);
    float sum = 0.f;
    for (int m = 0; m < WW; ++m) { float e = expf(sc[tid * WW + m] - mx); sc[tid * WW + m] = e; sum += e; }
    float r = 1.f / sum;
    for (int m = 0; m < WW; ++m) sc[tid * WW + m] *= r;
  }
  __syncthreads();
  if (tid < WW) {
    float s = 0.f;
    for (int l = 0; l < WW; ++l) s += sc[l * WW + tid];
    cs[tid] = s;
  }
  __syncthreads();
  if (tid < HH) {
    float acc = 0.f;
    for (int m = 0; m < WW; ++m) acc += cs[m] * QKVs[2][m * 65 + tid];
    tval[tid] = acc;
  }
  __syncthreads();
  if (tid < HH) {
    float acc = cb1[tid];
    #pragma unroll
    for (int d = 0; d < HH; ++d) acc += tval[d] * cW1[d * HH + tid];
    hrelu[tid] = fmaxf(acc, 0.f);
  }
  __syncthreads();
  if (tid == 0) {
    float acc = cb2[0];
    for (int j = 0; j < HH; ++j) acc += hrelu[j] * cW2[j];
    out[b] = acc;
  }
}

extern "C" void kernel_launch(void* const* d_in, const int* in_sizes, int n_in,
                              void* d_out, int out_size, void* d_ws, size_t ws_size,
                              hipStream_t stream) {
  (void)in_sizes; (void)n_in; (void)out_size; (void)ws_size;
  const float* arr    = (const float*)d_in[0];
  const float* msk    = (const float*)d_in[1];
  const float* timeTB = (const float*)d_in[2];
  const float* wdec   = (const float*)d_in[3];
  const float* bdec   = (const float*)d_in[4];
  const float* encW1  = (const float*)d_in[5];
  const float* encB1  = (const float*)d_in[6];
  const float* encW2  = (const float*)d_in[7];
  const float* encB2  = (const float*)d_in[8];
  const float* tlaWq  = (const float*)d_in[9];
  const float* tlaBq  = (const float*)d_in[10];
  const float* tlaWk  = (const float*)d_in[11];
  const float* tlaBk  = (const float*)d_in[12];
  const float* tlaWv  = (const float*)d_in[13];
  const float* tlaBv  = (const float*)d_in[14];
  const float* adj    = (const float*)d_in[15];
  const float* saWq   = (const float*)d_in[20];
  const float* saBq   = (const float*)d_in[21];
  const float* saWk   = (const float*)d_in[22];
  const float* saBk   = (const float*)d_in[23];
  const float* saWv   = (const float*)d_in[24];
  const float* saBv   = (const float*)d_in[25];
  const float* gWih0  = (const float*)d_in[26];
  const float* gWhh0  = (const float*)d_in[27];
  const float* gBih0  = (const float*)d_in[28];
  const float* gBhh0  = (const float*)d_in[29];
  const float* gWih1  = (const float*)d_in[30];
  const float* gWhh1  = (const float*)d_in[31];
  const float* gBih1  = (const float*)d_in[32];
  const float* gBhh1  = (const float*)d_in[33];
  const float* taWq   = (const float*)d_in[34];
  const float* taBq   = (const float*)d_in[35];
  const float* taWk   = (const float*)d_in[36];
  const float* taBk   = (const float*)d_in[37];
  const float* taWv   = (const float*)d_in[38];
  const float* taBv   = (const float*)d_in[39];
  const float* cW1    = (const float*)d_in[40];
  const float* cb1    = (const float*)d_in[41];
  const float* cW2    = (const float*)d_in[42];
  const float* cb2    = (const float*)d_in[43];
  float* out = (float*)d_out;
  float* ws  = (float*)d_ws;

  float* ao    = ws + AO_OFF;
  float* msg2  = ws + MSG2_OFF;
  float* cum   = ws + CUM2_OFF;
  float* last  = ws + LAST2_OFF;
  float* means = ws + MEANS2_OFF;
  unsigned int* maxv = (unsigned int*)(ws + MAX2_OFF);
  float* pqg   = ws + PQ_OFF;
  float* saw   = ws + SAW_OFF;
  float* fw    = ws + FW_OFF;

  float* sout = ws + SOUT_OFF;
  float* xw1  = ws + XW1_OFF;
  float* g1   = ws + G1_OFF;
  float* xw2  = ws + XW2_OFF;
  float* g2   = ws + G2_OFF;

  hipMemsetAsync(maxv, 0, sizeof(unsigned int), stream);
  k_scan<<<68, 256, 0, stream>>>(arr, msk, timeTB, cum, last, means, maxv);
  k_prep<<<61, 256, 0, stream>>>(tlaWq, tlaWk, tlaWv, tlaBq, tlaBk, tlaBv,
                                 saWq, saBq, saWk, saBk, encW2, encB2,
                                 pqg, saw, fw);
  k_enc4<<<VV * 128, 256, 0, stream>>>(arr, msk, cum, last, means, maxv,
                                       wdec, bdec, encW1, encB1, fw, pqg, ao);
  k_mp<<<BB * 4, 256, 0, stream>>>(ao, adj, msg2);
  k_sa3<<<BW / SG, 256, 0, stream>>>(msg2, saw, saWv, saBv, sout);
  k_xw1<<<(BW * TH3) / 256, 256, 0, stream>>>(sout, gWih0, gBih0, xw1);
  k_gru<<<BB, 192, 0, stream>>>(xw1, gWhh0, gBhh0, g1);
  k_xw2<<<BW / 16, 192, 0, stream>>>(g1, gWih1, gBih1, xw2);
  k_gru<<<BB, 192, 0, stream>>>(xw2, gWhh1, gBhh1, g2);
  k_ta<<<BB, 256, 0, stream>>>(g2, taWq, taBq, taWk, taBk, taWv, taBv,
                               cW1, cb1, cW2, cb2, out);
}

// Round 8
// 347.106 us; speedup vs baseline: 2.8383x; 1.1754x over previous
//
#include <hip/hip_runtime.h>
#include <math.h>

#define BB 512
#define TT 49
#define VV 34
#define FF 16
#define HH 64
#define WW 46
#define BW (BB*WW)        /* 23552 */
#define TH3 (3*HH)        /* 192 */
#define ROWS 25088        /* B*T */
#define SG 2              /* windows per k_sa4 block */

/* GRU-region (offsets in floats) */
#define SOUT_OFF   0ull
#define XW1_OFF    376832ull              /* BW*192 */
#define G1_OFF     (XW1_OFF + 4521984ull)
#define XW2_OFF    (G1_OFF + 1507328ull)
#define G2_OFF     (XW2_OFF + 4521984ull) /* ends 12435456 */

#define MSG_SZ     12812288ull            /* B*V*W*F */
#define CUM_SZ     852992ull              /* B*T*V */
#define MEANS_SZ   17408ull               /* B*V */
#define AO_OFF     12435456ull
#define MSG2_OFF   (AO_OFF + MSG_SZ)      /* 25247744 */
#define CUM2_OFF   (MSG2_OFF + MSG_SZ)
#define LAST2_OFF  (CUM2_OFF + CUM_SZ)
#define MEANS2_OFF (LAST2_OFF + CUM_SZ)
#define MAX2_OFF   (MEANS2_OFF + MEANS_SZ)
#define PQ_OFF     (MAX2_OFF + 4ull)
#define SAW_OFF    (PQ_OFF + 6528ull)
#define FW_OFF     (SAW_OFF + 292ull)     /* 34*816 = 27744 */
#define WVIH_OFF   (FW_OFF + 27744ull)    /* 16*192 = 3072 */
#define BIAS2_OFF  (WVIH_OFF + 3072ull)   /* 192 */

/* ---------------- kernel 1: impute scan + global max + means ---------------- */
__global__ __launch_bounds__(256) void k_scan(
    const float* __restrict__ arr, const float* __restrict__ msk,
    const float* __restrict__ timeTB,
    float* __restrict__ cum, float* __restrict__ last,
    float* __restrict__ means, unsigned int* __restrict__ maxv) {
  int tid = blockIdx.x * 256 + threadIdx.x;     /* 0..17407, exact */
  int b = tid / VV, v = tid - b * VV;
  const int base = b * TT * VV + v;
  float x = arr[base];
  float c = 0.f, lm = 0.f, s = x;
  cum[base] = 0.f;
  last[base] = x;
  float tp = timeTB[b];
  for (int t = 1; t < TT; ++t) {
    float tc = timeTB[t * BB + b];
    float d = tc - tp; tp = tc;
    int e = base + t * VV;
    float a = arr[e], m = msk[e];
    float miss = (m == 0.f) ? 1.f : 0.f;
    c = d + c * miss;
    x = (miss > 0.f) ? x : a;
    cum[e] = c; last[e] = x;
    lm = fmaxf(lm, c);
    s += a;
  }
  means[tid] = s * (1.f / 49.f);
  #pragma unroll
  for (int off = 32; off; off >>= 1) lm = fmaxf(lm, __shfl_xor(lm, off));
  if ((threadIdx.x & 63) == 0) atomicMax(maxv, __float_as_uint(lm));
}

/* ---------------- prep: PE proj + SA bilinear + weight folds ---------------- */
__global__ __launch_bounds__(256) void k_prep(
    const float* __restrict__ tlaWq, const float* __restrict__ tlaWk,
    const float* __restrict__ tlaWv,
    const float* __restrict__ tlaBq, const float* __restrict__ tlaBk,
    const float* __restrict__ tlaBv,
    const float* __restrict__ saWq, const float* __restrict__ saBq,
    const float* __restrict__ saWk, const float* __restrict__ saBk,
    const float* __restrict__ saWv, const float* __restrict__ saBv,
    const float* __restrict__ encW2, const float* __restrict__ encB2,
    const float* __restrict__ Wih0, const float* __restrict__ bih0,
    float* __restrict__ pqg, float* __restrict__ saw, float* __restrict__ fw,
    float* __restrict__ wvih, float* __restrict__ bias2) {
  const int bid = blockIdx.x;
  const int t = threadIdx.x;
  if (bid < 26) {
    int idx = bid * 256 + t;
    if (idx >= 6528) return;
    int which = idx / 2176;
    int r = idx - which * 2176;
    int l = r / 544;
    int rr = r - l * 544;
    int v = rr >> 4, f = rr & 15;
    const float* W = which == 0 ? tlaWq : which == 1 ? tlaWk : tlaWv;
    float acc = 0.f;
    #pragma unroll
    for (int i = 0; i < FF; ++i) {
      int i2 = i & ~1;
      float dv = expf(-logf(10000.f) * (float)i2 / (float)FF);
      float ang = (float)l * dv;
      float pe = (i & 1) ? cosf(ang) : sinf(ang);
      acc += pe * W[v * 256 + i * 16 + f];
    }
    pqg[idx] = acc;
  } else if (bid == 26) {
    int i = t & 15, j = t >> 4;
    float a = 0.f;
    #pragma unroll
    for (int f = 0; f < 16; ++f) a += saWq[i * 16 + f] * saWk[j * 16 + f];
    saw[j * 16 + i] = a;                    /* A[i][j] at [j*16+i] */
    if (t < 16) {
      float pp = 0.f, qq = 0.f;
      #pragma unroll
      for (int f = 0; f < 16; ++f) { pp += saWq[t * 16 + f] * saBk[f]; qq += saWk[t * 16 + f] * saBq[f]; }
      saw[256 + t] = pp;
      saw[272 + t] = qq;
    }
    if (t == 0) {
      float c = 0.f;
      #pragma unroll
      for (int f = 0; f < 16; ++f) c += saBq[f] * saBk[f];
      saw[288] = c;
    }
  } else if (bid < 61) {
    const int v = bid - 27;
    const int f = t >> 4, o = t & 15;
    const float* W2v = encW2 + v * 256;
    float cq = 0.f, ck = 0.f, cv = 0.f;
    #pragma unroll
    for (int g = 0; g < 16; ++g) {
      float w2 = W2v[f * 16 + g];
      cq += w2 * tlaWq[v * 256 + g * 16 + o];
      ck += w2 * tlaWk[v * 256 + g * 16 + o];
      cv += w2 * tlaWv[v * 256 + g * 16 + o];
    }
    fw[v * 816 + 0 * 272 + f * 16 + o] = cq;
    fw[v * 816 + 1 * 272 + f * 16 + o] = ck;
    fw[v * 816 + 2 * 272 + f * 16 + o] = cv;
    if (t < 48) {
      int which = t >> 4, o2 = t & 15;
      const float* Wp = which == 0 ? tlaWq : which == 1 ? tlaWk : tlaWv;
      const float* Bp = which == 0 ? tlaBq : which == 1 ? tlaBk : tlaBv;
      float acc = Bp[v * 16 + o2];
      #pragma unroll
      for (int g = 0; g < 16; ++g) acc += encB2[v * 16 + g] * Wp[v * 256 + g * 16 + o2];
      fw[v * 816 + which * 272 + 256 + o2] = acc;
    }
  } else if (bid < 73) {
    int idx = (bid - 61) * 256 + t;          /* < 3072 exact */
    int i = idx / 192, o = idx - i * 192;
    float acc = 0.f;
    #pragma unroll
    for (int f = 0; f < 16; ++f) acc += saWv[i * 16 + f] * Wih0[f * 192 + o];
    wvih[idx] = acc;
  } else {
    if (t < 192) {
      float acc = bih0[t];
      #pragma unroll
      for (int f = 0; f < 16; ++f) acc += 34.f * saBv[f] * Wih0[f * 192 + t];
      bias2[t] = acc;
    }
  }
}

/* ------- fused impute + MLP + folded QKV proj + windowed 4x4 attention ------- */
__global__ __launch_bounds__(256) void k_enc4(
    const float* __restrict__ arr, const float* __restrict__ msk,
    const float* __restrict__ cum, const float* __restrict__ last,
    const float* __restrict__ means, const unsigned int* __restrict__ maxv,
    const float* __restrict__ wdec, const float* __restrict__ bdec,
    const float* __restrict__ W1, const float* __restrict__ B1,
    const float* __restrict__ fw, const float* __restrict__ pqg,
    float* __restrict__ ao) {
  __shared__ float pkv[4][3][TT * 17];
  const int v = blockIdx.x % VV;
  const int bgrp = blockIdx.x / VV;        /* grid = 34*128 */
  const int tid = threadIdx.x;
  const int wave = tid >> 6, lane = tid & 63;
  const int b = bgrp * 4 + wave;
  const float* fv = fw + v * 816;
  if (lane < TT) {
    const int t = lane;
    const int idx = (b * TT + t) * VV + v;
    float inv = 1.f / __uint_as_float(*maxv);
    float a = arr[idx], m = msk[idx];
    float cc = cum[idx] * inv;
    float ttc = fminf(fmaxf(wdec[v] * cc + bdec[v], 0.f), 1000.f);
    float dec = expf(-ttc);
    float xx = a * m + (1.f - m) * (dec * last[idx] + (1.f - dec) * means[b * VV + v]);
    float h[16];
    #pragma unroll
    for (int f = 0; f < 16; ++f)
      h[f] = fmaxf(xx * W1[v * 32 + f] + m * W1[v * 32 + 16 + f] + B1[v * 16 + f], 0.f);
    #pragma unroll
    for (int which = 0; which < 3; ++which) {
      const float* C = fv + which * 272;
      #pragma unroll
      for (int g = 0; g < 16; ++g) {
        float acc = C[256 + g];
        #pragma unroll
        for (int f = 0; f < 16; ++f) acc += h[f] * C[f * 16 + g];
        pkv[wave][which][t * 17 + g] = acc;
      }
    }
  }
  __syncthreads();
  if (lane < WW) {
    const int w = lane;
    const float* P = &pkv[wave][0][0];
    const float* K = &pkv[wave][1][0];
    const float* Vp = &pkv[wave][2][0];
    float kk[4][16];
    #pragma unroll
    for (int m = 0; m < 4; ++m)
      #pragma unroll
      for (int f = 0; f < 16; ++f)
        kk[m][f] = K[(w + m) * 17 + f] + pqg[2176 + m * 544 + v * 16 + f];
    float sc[4][4];
    #pragma unroll
    for (int l = 0; l < 4; ++l) {
      float qv[16];
      #pragma unroll
      for (int i = 0; i < 16; ++i)
        qv[i] = P[(w + l) * 17 + i] + pqg[l * 544 + v * 16 + i];
      #pragma unroll
      for (int m = 0; m < 4; ++m) {
        float s = 0.f;
        #pragma unroll
        for (int i = 0; i < 16; ++i) s += qv[i] * kk[m][i];
        sc[l][m] = s * 0.25f;
      }
    }
    float csum[4] = {0.f, 0.f, 0.f, 0.f};
    #pragma unroll
    for (int l = 0; l < 4; ++l) {
      float mx = fmaxf(fmaxf(sc[l][0], sc[l][1]), fmaxf(sc[l][2], sc[l][3]));
      float sum = 0.f;
      #pragma unroll
      for (int m = 0; m < 4; ++m) { sc[l][m] = expf(sc[l][m] - mx); sum += sc[l][m]; }
      float r = 1.f / sum;
      #pragma unroll
      for (int m = 0; m < 4; ++m) csum[m] += sc[l][m] * r;
    }
    float outv[16];
    #pragma unroll
    for (int f = 0; f < 16; ++f) outv[f] = 0.f;
    #pragma unroll
    for (int m = 0; m < 4; ++m) {
      float c = csum[m];
      #pragma unroll
      for (int f = 0; f < 16; ++f)
        outv[f] += c * (Vp[(w + m) * 17 + f] + pqg[2 * 2176 + m * 544 + v * 16 + f]);
    }
    float4* d4 = (float4*)(ao + ((size_t)(b * VV + v) * WW + w) * 16);
    #pragma unroll
    for (int j = 0; j < 4; ++j)
      d4[j] = make_float4(outv[4*j], outv[4*j+1], outv[4*j+2], outv[4*j+3]);
  }
}

/* ------- message passing + V-axis PE fold, msg2 layout ------- */
#define MPW 12
__global__ __launch_bounds__(256) void k_mp(
    const float* __restrict__ ao, const float* __restrict__ adj,
    float* __restrict__ msg2) {
  __shared__ float adjs[VV * VV];
  __shared__ __align__(16) float aos[VV][MPW * 16];
  __shared__ float pes[VV * 16];
  const int bb = blockIdx.x >> 2;
  const int wt = blockIdx.x & 3;
  const int w0 = wt * MPW;
  const int wc = (wt == 3) ? (WW - 3 * MPW) : MPW;
  const int tid = threadIdx.x;
  for (int i = tid; i < VV * VV; i += 256) adjs[i] = adj[i];
  for (int i = tid; i < VV * 16; i += 256) {
    int u = i >> 4, f = i & 15;
    int f2 = f & ~1;
    float dv = expf(-logf(10000.f) * (float)f2 / 16.f);
    float ang = (float)u * dv;
    pes[i] = (f & 1) ? cosf(ang) : sinf(ang);
  }
  const int nq = wc * 4;
  for (int i = tid; i < VV * nq; i += 256) {
    int vv2 = i / nq, r = i - vv2 * nq;
    int wl = r >> 2, q = r & 3;
    float4 val = *(const float4*)(ao + ((size_t)(bb * VV + vv2) * WW + w0 + wl) * 16 + q * 4);
    *(float4*)&aos[vv2][wl * 16 + q * 4] = val;
  }
  __syncthreads();
  for (int i = tid; i < VV * nq; i += 256) {
    int u = i / nq, r = i - u * nq;
    int wl = r >> 2, q = r & 3;
    float a0 = 0.f, a1 = 0.f, a2 = 0.f, a3 = 0.f;
    for (int vv2 = 0; vv2 < VV; ++vv2) {
      float a = adjs[u * VV + vv2];
      float4 s = *(const float4*)&aos[vv2][wl * 16 + q * 4];
      a0 += a * s.x; a1 += a * s.y; a2 += a * s.z; a3 += a * s.w;
    }
    float4 o = make_float4(a0 + pes[u * 16 + q * 4],
                           a1 + pes[u * 16 + q * 4 + 1],
                           a2 + pes[u * 16 + q * 4 + 2],
                           a3 + pes[u * 16 + q * 4 + 3]);
    *(float4*)(msg2 + ((size_t)(bb * VV + u) * WW + w0 + wl) * 16 + q * 4) = o;
  }
}

/* ---------------- signal attention v5: b128 LDS, 4x4 tiles, xw1 fused ----------------
   pad rows to 36; rows/cols 34,35 carry garbage that only reaches never-read sc cells. */
#define DOT4(a,b) ((a).x*(b).x + (a).y*(b).y + (a).z*(b).z + (a).w*(b).w)
__global__ __launch_bounds__(256) void k_sa4(
    const float* __restrict__ msg2, const float* __restrict__ saw,
    const float* __restrict__ wvih, const float* __restrict__ bias2,
    float* __restrict__ xw1) {
  __shared__ float As[256];
  __shared__ float ps[16], q2s[16];
  __shared__ __align__(16) float xs[SG][36][20];   /* 80B rows, b128-aligned */
  __shared__ __align__(16) float zs[SG][36][20];
  __shared__ float sc[SG][36][37];                 /* odd stride */
  __shared__ float uws[SG][36], vws[SG][36];
  __shared__ float rs[SG][34], cs[SG][34];
  __shared__ float ys[SG][16];
  __shared__ float c0s;
  const int tid = threadIdx.x;
  const int n0 = blockIdx.x * SG;                  /* grid 11776 exact */
  As[tid] = saw[tid];
  if (tid < 16) { ps[tid] = saw[256 + tid]; q2s[tid] = saw[272 + tid]; }
  if (tid == 0) c0s = saw[288];
  {
    const float4* src = (const float4*)(msg2 + (size_t)n0 * 544);
    for (int i = tid; i < SG * 136; i += 256) {
      int g = i / 136, r = i - g * 136;
      int m = r >> 2, q = r & 3;
      ((float4*)&xs[g][m][0])[q] = src[i];
    }
  }
  __syncthreads();
  /* phase1: z[m][i] = sum_j A[i][j] x[m][j]; 2x2 (m,i) tiles, float4 x reads */
  for (int idx = tid; idx < SG * 136; idx += 256) {
    int g = idx / 136, r = idx - g * 136;
    int m0 = (r >> 3) * 2, i0 = (r & 7) * 2;
    float z00 = 0.f, z01 = 0.f, z10 = 0.f, z11 = 0.f;
    #pragma unroll
    for (int jc = 0; jc < 4; ++jc) {
      float4 xa = ((const float4*)&xs[g][m0][0])[jc];
      float4 xb = ((const float4*)&xs[g][m0 + 1][0])[jc];
      #pragma unroll
      for (int jj = 0; jj < 4; ++jj) {
        int j = jc * 4 + jj;
        float xj0 = (jj == 0) ? xa.x : (jj == 1) ? xa.y : (jj == 2) ? xa.z : xa.w;
        float xj1 = (jj == 0) ? xb.x : (jj == 1) ? xb.y : (jj == 2) ? xb.z : xb.w;
        float a0 = As[j * 16 + i0], a1 = As[j * 16 + i0 + 1];
        z00 += a0 * xj0; z01 += a1 * xj0; z10 += a0 * xj1; z11 += a1 * xj1;
      }
    }
    zs[g][m0][i0] = z00; zs[g][m0][i0 + 1] = z01;
    zs[g][m0 + 1][i0] = z10; zs[g][m0 + 1][i0 + 1] = z11;
  }
  if (tid < SG * 34) {
    int g = tid / 34, m = tid - g * 34;
    float pu = 0.f, pv = 0.f;
    #pragma unroll
    for (int i = 0; i < 16; ++i) { float x = xs[g][m][i]; pu += x * ps[i]; pv += x * q2s[i]; }
    uws[g][m] = pu; vws[g][m] = pv;
  }
  __syncthreads();
  /* phase2: 4x4 score tiles, float4 reads of x and z rows */
  for (int idx = tid; idx < SG * 81; idx += 256) {
    int g = idx / 81, r = idx - g * 81;
    int l0 = (r / 9) * 4, m0 = (r - (r / 9) * 9) * 4;
    float s00=0,s01=0,s02=0,s03=0, s10=0,s11=0,s12=0,s13=0;
    float s20=0,s21=0,s22=0,s23=0, s30=0,s31=0,s32=0,s33=0;
    #pragma unroll
    for (int ic = 0; ic < 4; ++ic) {
      float4 x0 = ((const float4*)&xs[g][l0 + 0][0])[ic];
      float4 x1 = ((const float4*)&xs[g][l0 + 1][0])[ic];
      float4 x2 = ((const float4*)&xs[g][l0 + 2][0])[ic];
      float4 x3 = ((const float4*)&xs[g][l0 + 3][0])[ic];
      float4 z0 = ((const float4*)&zs[g][m0 + 0][0])[ic];
      float4 z1 = ((const float4*)&zs[g][m0 + 1][0])[ic];
      float4 z2 = ((const float4*)&zs[g][m0 + 2][0])[ic];
      float4 z3 = ((const float4*)&zs[g][m0 + 3][0])[ic];
      s00 += DOT4(x0,z0); s01 += DOT4(x0,z1); s02 += DOT4(x0,z2); s03 += DOT4(x0,z3);
      s10 += DOT4(x1,z0); s11 += DOT4(x1,z1); s12 += DOT4(x1,z2); s13 += DOT4(x1,z3);
      s20 += DOT4(x2,z0); s21 += DOT4(x2,z1); s22 += DOT4(x2,z2); s23 += DOT4(x2,z3);
      s30 += DOT4(x3,z0); s31 += DOT4(x3,z1); s32 += DOT4(x3,z2); s33 += DOT4(x3,z3);
    }
    float c0 = c0s;
    float u0 = uws[g][l0], u1 = uws[g][l0+1], u2 = uws[g][l0+2], u3 = uws[g][l0+3];
    float v0 = vws[g][m0], v1 = vws[g][m0+1], v2 = vws[g][m0+2], v3 = vws[g][m0+3];
    sc[g][l0+0][m0+0] = (s00+u0+v0+c0)*0.25f; sc[g][l0+0][m0+1] = (s01+u0+v1+c0)*0.25f;
    sc[g][l0+0][m0+2] = (s02+u0+v2+c0)*0.25f; sc[g][l0+0][m0+3] = (s03+u0+v3+c0)*0.25f;
    sc[g][l0+1][m0+0] = (s10+u1+v0+c0)*0.25f; sc[g][l0+1][m0+1] = (s11+u1+v1+c0)*0.25f;
    sc[g][l0+1][m0+2] = (s12+u1+v2+c0)*0.25f; sc[g][l0+1][m0+3] = (s13+u1+v3+c0)*0.25f;
    sc[g][l0+2][m0+0] = (s20+u2+v0+c0)*0.25f; sc[g][l0+2][m0+1] = (s21+u2+v1+c0)*0.25f;
    sc[g][l0+2][m0+2] = (s22+u2+v2+c0)*0.25f; sc[g][l0+2][m0+3] = (s23+u2+v3+c0)*0.25f;
    sc[g][l0+3][m0+0] = (s30+u3+v0+c0)*0.25f; sc[g][l0+3][m0+1] = (s31+u3+v1+c0)*0.25f;
    sc[g][l0+3][m0+2] = (s32+u3+v2+c0)*0.25f; sc[g][l0+3][m0+3] = (s33+u3+v3+c0)*0.25f;
  }
  __syncthreads();
  if (tid < SG * 34) {
    int g = tid / 34, l = tid - g * 34;
    float mx = -1e30f;
    for (int m = 0; m < 34; ++m) mx = fmaxf(mx, sc[g][l][m]);
    float sum = 0.f;
    for (int m = 0; m < 34; ++m) { float e = expf(sc[g][l][m] - mx); sc[g][l][m] = e; sum += e; }
    rs[g][l] = 1.f / sum;
  }
  __syncthreads();
  if (tid < SG * 34) {
    int g = tid / 34, m = tid - g * 34;
    float acc = 0.f;
    for (int l = 0; l < 34; ++l) acc += sc[g][l][m] * rs[g][l];
    cs[g][m] = acc;
  }
  __syncthreads();
  if (tid < SG * 16) {
    int g = tid >> 4, i = tid & 15;
    float acc = 0.f;
    for (int m = 0; m < 34; ++m) acc += cs[g][m] * xs[g][m][i];
    ys[g][i] = acc;
  }
  __syncthreads();
  /* phase6: xw1 = y.Wvih + bias2 (xw1-kernel fused away) */
  for (int idx = tid; idx < SG * 192; idx += 256) {
    int g = idx / 192, o = idx - g * 192;
    float acc = bias2[o];
    #pragma unroll
    for (int i = 0; i < 16; ++i) acc += ys[g][i] * wvih[i * 192 + o];
    xw1[(size_t)(n0 + g) * 192 + o] = acc;
  }
}

/* ---------------- GRU: weights in 192 VGPRs, readlane h-broadcast, no LDS ---------------- */
#define RL(x,i) __uint_as_float(__builtin_amdgcn_readlane(__float_as_uint(x), (i)))
__global__ __launch_bounds__(64) void k_gru2(
    const float* __restrict__ xw, const float* __restrict__ Whh,
    const float* __restrict__ bhh, float* __restrict__ gout) {
  const int tid = threadIdx.x;
  const int b = blockIdx.x;
  float wr[64], wz[64], wn[64];
  #pragma unroll
  for (int i = 0; i < 64; ++i) {
    wr[i] = Whh[i * 192 + tid];
    wz[i] = Whh[i * 192 + 64 + tid];
    wn[i] = Whh[i * 192 + 128 + tid];
  }
  const float br = bhh[tid], bz = bhh[64 + tid], bn = bhh[128 + tid];
  float h = 0.f;
  const float* xr = xw + (size_t)b * WW * 192;
  for (int w = 0; w < WW; ++w, xr += 192) {
    float xrv = xr[tid], xzv = xr[64 + tid], xnv = xr[128 + tid];
    float pr0 = br, pr1 = 0.f, pr2 = 0.f, pr3 = 0.f;
    float pz0 = bz, pz1 = 0.f, pz2 = 0.f, pz3 = 0.f;
    float pn0 = bn, pn1 = 0.f, pn2 = 0.f, pn3 = 0.f;
    #pragma unroll
    for (int i = 0; i < 64; i += 4) {
      float h0 = RL(h, i), h1 = RL(h, i + 1), h2 = RL(h, i + 2), h3 = RL(h, i + 3);
      pr0 += h0 * wr[i];     pr1 += h1 * wr[i + 1];
      pr2 += h2 * wr[i + 2]; pr3 += h3 * wr[i + 3];
      pz0 += h0 * wz[i];     pz1 += h1 * wz[i + 1];
      pz2 += h2 * wz[i + 2]; pz3 += h3 * wz[i + 3];
      pn0 += h0 * wn[i];     pn1 += h1 * wn[i + 1];
      pn2 += h2 * wn[i + 2]; pn3 += h3 * wn[i + 3];
    }
    float ar = (pr0 + pr1) + (pr2 + pr3);
    float az = (pz0 + pz1) + (pz2 + pz3);
    float an = (pn0 + pn1) + (pn2 + pn3);
    float r = 1.f / (1.f + expf(-(xrv + ar)));
    float z = 1.f / (1.f + expf(-(xzv + az)));
    float n = tanhf(xnv + r * an);
    h = (1.f - z) * n + z * h;
    gout[((size_t)b * WW + w) * HH + tid] = h;
  }
}

/* ---------------- GRU layer-2 input projection ---------------- */
__global__ __launch_bounds__(192) void k_xw2(
    const float* __restrict__ x, const float* __restrict__ Wih,
    const float* __restrict__ bih, float* __restrict__ xw) {
  __shared__ float xsh[16][HH];
  int n0 = blockIdx.x * 16;
  int tid = threadIdx.x;
  for (int idx = tid; idx < 16 * HH; idx += 192) {
    int ns = idx >> 6, i = idx & 63;
    xsh[ns][i] = x[(size_t)(n0 + ns) * HH + i];
  }
  __syncthreads();
  float acc[16];
  float bb = bih[tid];
  #pragma unroll
  for (int ns = 0; ns < 16; ++ns) acc[ns] = bb;
  for (int i = 0; i < HH; ++i) {
    float wv = Wih[i * TH3 + tid];
    #pragma unroll
    for (int ns = 0; ns < 16; ++ns) acc[ns] += xsh[ns][i] * wv;
  }
  #pragma unroll
  for (int ns = 0; ns < 16; ++ns) xw[(size_t)(n0 + ns) * TH3 + tid] = acc[ns];
}

/* ---------------- temporal attention + classifier ---------------- */
__global__ __launch_bounds__(256) void k_ta(
    const float* __restrict__ g2,
    const float* __restrict__ Wq, const float* __restrict__ bq,
    const float* __restrict__ Wk, const float* __restrict__ bk,
    const float* __restrict__ Wv, const float* __restrict__ bv,
    const float* __restrict__ cW1, const float* __restrict__ cb1,
    const float* __restrict__ cW2, const float* __restrict__ cb2,
    float* __restrict__ out) {
  __shared__ float xt[WW * 65];
  __shared__ float QKVs[3][WW * 65];
  __shared__ float sc[WW * WW];
  __shared__ float cs[WW];
  __shared__ float tval[HH];
  __shared__ float hrelu[HH];
  int tid = threadIdx.x;
  int b = blockIdx.x;
  for (int idx = tid; idx < WW * HH; idx += 256) {
    int w = idx >> 6, d = idx & 63;
    int f2 = d & ~1;
    float dv = expf(-logf(10000.f) * (float)f2 / (float)HH);
    float ang = (float)w * dv;
    float pe = (d & 1) ? cosf(ang) : sinf(ang);
    xt[w * 65 + d] = g2[(size_t)(b * WW + w) * HH + d] + pe;
  }
  __syncthreads();
  if (tid < 192) {
    int which = tid >> 6, d = tid & 63;
    const float* Wt = which == 0 ? Wq : which == 1 ? Wk : Wv;
    float bias = (which == 0 ? bq : which == 1 ? bk : bv)[d];
    float col[HH];
    #pragma unroll
    for (int i = 0; i < HH; ++i) col[i] = Wt[i * HH + d];
    float* dst = &QKVs[which][0];
    for (int w = 0; w < WW; ++w) {
      float acc = bias;
      #pragma unroll
      for (int i = 0; i < HH; ++i) acc += xt[w * 65 + i] * col[i];
      dst[w * 65 + d] = acc;
    }
  }
  __syncthreads();
  for (int idx = tid; idx < WW * WW; idx += 256) {
    int l = idx / WW, m = idx - l * WW;
    float s = 0.f;
    #pragma unroll
    for (int i = 0; i < HH; ++i) s += QKVs[0][l * 65 + i] * QKVs[1][m * 65 + i];
    sc[idx] = s * 0.125f;
  }
  __syncthreads();
  if (tid < WW) {
    float mx = -1e30f;
    for (int m = 0; m < WW; ++m) mx = fmaxf(mx, sc[tid * WW + m]);
    float sum = 0.f;
    for (int m = 0; m < WW; ++m) { float e = expf(sc[tid * WW + m] - mx); sc[tid * WW + m] = e; sum += e; }
    float r = 1.f / sum;
    for (int m = 0; m < WW; ++m) sc[tid * WW + m] *= r;
  }
  __syncthreads();
  if (tid < WW) {
    float s = 0.f;
    for (int l = 0; l < WW; ++l) s += sc[l * WW + tid];
    cs[tid] = s;
  }
  __syncthreads();
  if (tid < HH) {
    float acc = 0.f;
    for (int m = 0; m < WW; ++m) acc += cs[m] * QKVs[2][m * 65 + tid];
    tval[tid] = acc;
  }
  __syncthreads();
  if (tid < HH) {
    float acc = cb1[tid];
    #pragma unroll
    for (int d = 0; d < HH; ++d) acc += tval[d] * cW1[d * HH + tid];
    hrelu[tid] = fmaxf(acc, 0.f);
  }
  __syncthreads();
  if (tid == 0) {
    float acc = cb2[0];
    for (int j = 0; j < HH; ++j) acc += hrelu[j] * cW2[j];
    out[b] = acc;
  }
}

extern "C" void kernel_launch(void* const* d_in, const int* in_sizes, int n_in,
                              void* d_out, int out_size, void* d_ws, size_t ws_size,
                              hipStream_t stream) {
  (void)in_sizes; (void)n_in; (void)out_size; (void)ws_size;
  const float* arr    = (const float*)d_in[0];
  const float* msk    = (const float*)d_in[1];
  const float* timeTB = (const float*)d_in[2];
  const float* wdec   = (const float*)d_in[3];
  const float* bdec   = (const float*)d_in[4];
  const float* encW1  = (const float*)d_in[5];
  const float* encB1  = (const float*)d_in[6];
  const float* encW2  = (const float*)d_in[7];
  const float* encB2  = (const float*)d_in[8];
  const float* tlaWq  = (const float*)d_in[9];
  const float* tlaBq  = (const float*)d_in[10];
  const float* tlaWk  = (const float*)d_in[11];
  const float* tlaBk  = (const float*)d_in[12];
  const float* tlaWv  = (const float*)d_in[13];
  const float* tlaBv  = (const float*)d_in[14];
  const float* adj    = (const float*)d_in[15];
  const float* saWq   = (const float*)d_in[20];
  const float* saBq   = (const float*)d_in[21];
  const float* saWk   = (const float*)d_in[22];
  const float* saBk   = (const float*)d_in[23];
  const float* saWv   = (const float*)d_in[24];
  const float* saBv   = (const float*)d_in[25];
  const float* gWih0  = (const float*)d_in[26];
  const float* gWhh0  = (const float*)d_in[27];
  const float* gBih0  = (const float*)d_in[28];
  const float* gBhh0  = (const float*)d_in[29];
  const float* gWih1  = (const float*)d_in[30];
  const float* gWhh1  = (const float*)d_in[31];
  const float* gBih1  = (const float*)d_in[32];
  const float* gBhh1  = (const float*)d_in[33];
  const float* taWq   = (const float*)d_in[34];
  const float* taBq   = (const float*)d_in[35];
  const float* taWk   = (const float*)d_in[36];
  const float* taBk   = (const float*)d_in[37];
  const float* taWv   = (const float*)d_in[38];
  const float* taBv   = (const float*)d_in[39];
  const float* cW1    = (const float*)d_in[40];
  const float* cb1    = (const float*)d_in[41];
  const float* cW2    = (const float*)d_in[42];
  const float* cb2    = (const float*)d_in[43];
  float* out = (float*)d_out;
  float* ws  = (float*)d_ws;

  float* ao    = ws + AO_OFF;
  float* msg2  = ws + MSG2_OFF;
  float* cum   = ws + CUM2_OFF;
  float* last  = ws + LAST2_OFF;
  float* means = ws + MEANS2_OFF;
  unsigned int* maxv = (unsigned int*)(ws + MAX2_OFF);
  float* pqg   = ws + PQ_OFF;
  float* saw   = ws + SAW_OFF;
  float* fw    = ws + FW_OFF;
  float* wvih  = ws + WVIH_OFF;
  float* bias2 = ws + BIAS2_OFF;

  float* xw1  = ws + XW1_OFF;
  float* g1   = ws + G1_OFF;
  float* xw2  = ws + XW2_OFF;
  float* g2   = ws + G2_OFF;

  hipMemsetAsync(maxv, 0, sizeof(unsigned int), stream);
  k_scan<<<68, 256, 0, stream>>>(arr, msk, timeTB, cum, last, means, maxv);
  k_prep<<<74, 256, 0, stream>>>(tlaWq, tlaWk, tlaWv, tlaBq, tlaBk, tlaBv,
                                 saWq, saBq, saWk, saBk, saWv, saBv,
                                 encW2, encB2, gWih0, gBih0,
                                 pqg, saw, fw, wvih, bias2);
  k_enc4<<<VV * 128, 256, 0, stream>>>(arr, msk, cum, last, means, maxv,
                                       wdec, bdec, encW1, encB1, fw, pqg, ao);
  k_mp<<<BB * 4, 256, 0, stream>>>(ao, adj, msg2);
  k_sa4<<<BW / SG, 256, 0, stream>>>(msg2, saw, wvih, bias2, xw1);
  k_gru2<<<BB, 64, 0, stream>>>(xw1, gWhh0, gBhh0, g1);
  k_xw2<<<BW / 16, 192, 0, stream>>>(g1, gWih1, gBih1, xw2);
  k_gru2<<<BB, 64, 0, stream>>>(xw2, gWhh1, gBhh1, g2);
  k_ta<<<BB, 256, 0, stream>>>(g2, taWq, taBq, taWk, taBk, taWv, taBv,
                               cW1, cb1, cW2, cb2, out);
}

// Round 9
// 338.076 us; speedup vs baseline: 2.9141x; 1.0267x over previous
//
#include <hip/hip_runtime.h>
#include <math.h>

#define BB 512
#define TT 49
#define VV 34
#define FF 16
#define HH 64
#define WW 46
#define BW (BB*WW)        /* 23552 */
#define TH3 (3*HH)        /* 192 */
#define ROWS 25088        /* B*T */

/* GRU-region (offsets in floats) */
#define SOUT_OFF   0ull
#define XW1_OFF    376832ull              /* BW*192 */
#define G1_OFF     (XW1_OFF + 4521984ull)
#define XW2_OFF    (G1_OFF + 1507328ull)
#define G2_OFF     (XW2_OFF + 4521984ull) /* ends 12435456 */

#define MSG_SZ     12812288ull            /* B*V*W*F */
#define CUM_SZ     852992ull              /* B*T*V */
#define MEANS_SZ   17408ull               /* B*V */
#define AO_OFF     12435456ull
#define MSG2_OFF   (AO_OFF + MSG_SZ)      /* 25247744 */
#define CUM2_OFF   (MSG2_OFF + MSG_SZ)
#define LAST2_OFF  (CUM2_OFF + CUM_SZ)
#define MEANS2_OFF (LAST2_OFF + CUM_SZ)
#define MAX2_OFF   (MEANS2_OFF + MEANS_SZ)
#define PQ_OFF     (MAX2_OFF + 4ull)
#define SAW_OFF    (PQ_OFF + 6528ull)
#define FW_OFF     (SAW_OFF + 292ull)     /* 34*816 = 27744 */
#define WVIH_OFF   (FW_OFF + 27744ull)    /* 16*192 = 3072 */
#define BIAS2_OFF  (WVIH_OFF + 3072ull)   /* 192 */

/* ---------------- kernel 1: impute scan + global max + means ---------------- */
__global__ __launch_bounds__(256) void k_scan(
    const float* __restrict__ arr, const float* __restrict__ msk,
    const float* __restrict__ timeTB,
    float* __restrict__ cum, float* __restrict__ last,
    float* __restrict__ means, unsigned int* __restrict__ maxv) {
  int tid = blockIdx.x * 256 + threadIdx.x;     /* 0..17407, exact */
  int b = tid / VV, v = tid - b * VV;
  const int base = b * TT * VV + v;
  float x = arr[base];
  float c = 0.f, lm = 0.f, s = x;
  cum[base] = 0.f;
  last[base] = x;
  float tp = timeTB[b];
  for (int t = 1; t < TT; ++t) {
    float tc = timeTB[t * BB + b];
    float d = tc - tp; tp = tc;
    int e = base + t * VV;
    float a = arr[e], m = msk[e];
    float miss = (m == 0.f) ? 1.f : 0.f;
    c = d + c * miss;
    x = (miss > 0.f) ? x : a;
    cum[e] = c; last[e] = x;
    lm = fmaxf(lm, c);
    s += a;
  }
  means[tid] = s * (1.f / 49.f);
  #pragma unroll
  for (int off = 32; off; off >>= 1) lm = fmaxf(lm, __shfl_xor(lm, off));
  if ((threadIdx.x & 63) == 0) atomicMax(maxv, __float_as_uint(lm));
}

/* ---------------- prep: PE proj + SA bilinear + weight folds ---------------- */
__global__ __launch_bounds__(256) void k_prep(
    const float* __restrict__ tlaWq, const float* __restrict__ tlaWk,
    const float* __restrict__ tlaWv,
    const float* __restrict__ tlaBq, const float* __restrict__ tlaBk,
    const float* __restrict__ tlaBv,
    const float* __restrict__ saWq, const float* __restrict__ saBq,
    const float* __restrict__ saWk, const float* __restrict__ saBk,
    const float* __restrict__ saWv, const float* __restrict__ saBv,
    const float* __restrict__ encW2, const float* __restrict__ encB2,
    const float* __restrict__ Wih0, const float* __restrict__ bih0,
    float* __restrict__ pqg, float* __restrict__ saw, float* __restrict__ fw,
    float* __restrict__ wvih, float* __restrict__ bias2) {
  const int bid = blockIdx.x;
  const int t = threadIdx.x;
  if (bid < 26) {
    int idx = bid * 256 + t;
    if (idx >= 6528) return;
    int which = idx / 2176;
    int r = idx - which * 2176;
    int l = r / 544;
    int rr = r - l * 544;
    int v = rr >> 4, f = rr & 15;
    const float* W = which == 0 ? tlaWq : which == 1 ? tlaWk : tlaWv;
    float acc = 0.f;
    #pragma unroll
    for (int i = 0; i < FF; ++i) {
      int i2 = i & ~1;
      float dv = expf(-logf(10000.f) * (float)i2 / (float)FF);
      float ang = (float)l * dv;
      float pe = (i & 1) ? cosf(ang) : sinf(ang);
      acc += pe * W[v * 256 + i * 16 + f];
    }
    pqg[idx] = acc;
  } else if (bid == 26) {
    int i = t & 15, j = t >> 4;
    float a = 0.f;
    #pragma unroll
    for (int f = 0; f < 16; ++f) a += saWq[i * 16 + f] * saWk[j * 16 + f];
    saw[j * 16 + i] = a;                    /* A[i][j] at [j*16+i] */
    if (t < 16) {
      float pp = 0.f, qq = 0.f;
      #pragma unroll
      for (int f = 0; f < 16; ++f) { pp += saWq[t * 16 + f] * saBk[f]; qq += saWk[t * 16 + f] * saBq[f]; }
      saw[256 + t] = pp;
      saw[272 + t] = qq;
    }
    if (t == 0) {
      float c = 0.f;
      #pragma unroll
      for (int f = 0; f < 16; ++f) c += saBq[f] * saBk[f];
      saw[288] = c;
    }
  } else if (bid < 61) {
    const int v = bid - 27;
    const int f = t >> 4, o = t & 15;
    const float* W2v = encW2 + v * 256;
    float cq = 0.f, ck = 0.f, cv = 0.f;
    #pragma unroll
    for (int g = 0; g < 16; ++g) {
      float w2 = W2v[f * 16 + g];
      cq += w2 * tlaWq[v * 256 + g * 16 + o];
      ck += w2 * tlaWk[v * 256 + g * 16 + o];
      cv += w2 * tlaWv[v * 256 + g * 16 + o];
    }
    fw[v * 816 + 0 * 272 + f * 16 + o] = cq;
    fw[v * 816 + 1 * 272 + f * 16 + o] = ck;
    fw[v * 816 + 2 * 272 + f * 16 + o] = cv;
    if (t < 48) {
      int which = t >> 4, o2 = t & 15;
      const float* Wp = which == 0 ? tlaWq : which == 1 ? tlaWk : tlaWv;
      const float* Bp = which == 0 ? tlaBq : which == 1 ? tlaBk : tlaBv;
      float acc = Bp[v * 16 + o2];
      #pragma unroll
      for (int g = 0; g < 16; ++g) acc += encB2[v * 16 + g] * Wp[v * 256 + g * 16 + o2];
      fw[v * 816 + which * 272 + 256 + o2] = acc;
    }
  } else if (bid < 73) {
    int idx = (bid - 61) * 256 + t;          /* < 3072 exact */
    int i = idx / 192, o = idx - i * 192;
    float acc = 0.f;
    #pragma unroll
    for (int f = 0; f < 16; ++f) acc += saWv[i * 16 + f] * Wih0[f * 192 + o];
    wvih[idx] = acc;
  } else {
    if (t < 192) {
      float acc = bih0[t];
      #pragma unroll
      for (int f = 0; f < 16; ++f) acc += 34.f * saBv[f] * Wih0[f * 192 + t];
      bias2[t] = acc;
    }
  }
}

/* ------- fused impute + MLP + folded QKV proj + windowed 4x4 attention ------- */
__global__ __launch_bounds__(256) void k_enc4(
    const float* __restrict__ arr, const float* __restrict__ msk,
    const float* __restrict__ cum, const float* __restrict__ last,
    const float* __restrict__ means, const unsigned int* __restrict__ maxv,
    const float* __restrict__ wdec, const float* __restrict__ bdec,
    const float* __restrict__ W1, const float* __restrict__ B1,
    const float* __restrict__ fw, const float* __restrict__ pqg,
    float* __restrict__ ao) {
  __shared__ float pkv[4][3][TT * 17];
  const int v = blockIdx.x % VV;
  const int bgrp = blockIdx.x / VV;        /* grid = 34*128 */
  const int tid = threadIdx.x;
  const int wave = tid >> 6, lane = tid & 63;
  const int b = bgrp * 4 + wave;
  const float* fv = fw + v * 816;
  if (lane < TT) {
    const int t = lane;
    const int idx = (b * TT + t) * VV + v;
    float inv = 1.f / __uint_as_float(*maxv);
    float a = arr[idx], m = msk[idx];
    float cc = cum[idx] * inv;
    float ttc = fminf(fmaxf(wdec[v] * cc + bdec[v], 0.f), 1000.f);
    float dec = expf(-ttc);
    float xx = a * m + (1.f - m) * (dec * last[idx] + (1.f - dec) * means[b * VV + v]);
    float h[16];
    #pragma unroll
    for (int f = 0; f < 16; ++f)
      h[f] = fmaxf(xx * W1[v * 32 + f] + m * W1[v * 32 + 16 + f] + B1[v * 16 + f], 0.f);
    #pragma unroll
    for (int which = 0; which < 3; ++which) {
      const float* C = fv + which * 272;
      #pragma unroll
      for (int g = 0; g < 16; ++g) {
        float acc = C[256 + g];
        #pragma unroll
        for (int f = 0; f < 16; ++f) acc += h[f] * C[f * 16 + g];
        pkv[wave][which][t * 17 + g] = acc;
      }
    }
  }
  __syncthreads();
  if (lane < WW) {
    const int w = lane;
    const float* P = &pkv[wave][0][0];
    const float* K = &pkv[wave][1][0];
    const float* Vp = &pkv[wave][2][0];
    float kk[4][16];
    #pragma unroll
    for (int m = 0; m < 4; ++m)
      #pragma unroll
      for (int f = 0; f < 16; ++f)
        kk[m][f] = K[(w + m) * 17 + f] + pqg[2176 + m * 544 + v * 16 + f];
    float sc[4][4];
    #pragma unroll
    for (int l = 0; l < 4; ++l) {
      float qv[16];
      #pragma unroll
      for (int i = 0; i < 16; ++i)
        qv[i] = P[(w + l) * 17 + i] + pqg[l * 544 + v * 16 + i];
      #pragma unroll
      for (int m = 0; m < 4; ++m) {
        float s = 0.f;
        #pragma unroll
        for (int i = 0; i < 16; ++i) s += qv[i] * kk[m][i];
        sc[l][m] = s * 0.25f;
      }
    }
    float csum[4] = {0.f, 0.f, 0.f, 0.f};
    #pragma unroll
    for (int l = 0; l < 4; ++l) {
      float mx = fmaxf(fmaxf(sc[l][0], sc[l][1]), fmaxf(sc[l][2], sc[l][3]));
      float sum = 0.f;
      #pragma unroll
      for (int m = 0; m < 4; ++m) { sc[l][m] = expf(sc[l][m] - mx); sum += sc[l][m]; }
      float r = 1.f / sum;
      #pragma unroll
      for (int m = 0; m < 4; ++m) csum[m] += sc[l][m] * r;
    }
    float outv[16];
    #pragma unroll
    for (int f = 0; f < 16; ++f) outv[f] = 0.f;
    #pragma unroll
    for (int m = 0; m < 4; ++m) {
      float c = csum[m];
      #pragma unroll
      for (int f = 0; f < 16; ++f)
        outv[f] += c * (Vp[(w + m) * 17 + f] + pqg[2 * 2176 + m * 544 + v * 16 + f]);
    }
    float4* d4 = (float4*)(ao + ((size_t)(b * VV + v) * WW + w) * 16);
    #pragma unroll
    for (int j = 0; j < 4; ++j)
      d4[j] = make_float4(outv[4*j], outv[4*j+1], outv[4*j+2], outv[4*j+3]);
  }
}

/* ------- message passing + V-axis PE fold, msg2 layout ------- */
#define MPW 12
__global__ __launch_bounds__(256) void k_mp(
    const float* __restrict__ ao, const float* __restrict__ adj,
    float* __restrict__ msg2) {
  __shared__ float adjs[VV * VV];
  __shared__ __align__(16) float aos[VV][MPW * 16];
  __shared__ float pes[VV * 16];
  const int bb = blockIdx.x >> 2;
  const int wt = blockIdx.x & 3;
  const int w0 = wt * MPW;
  const int wc = (wt == 3) ? (WW - 3 * MPW) : MPW;
  const int tid = threadIdx.x;
  for (int i = tid; i < VV * VV; i += 256) adjs[i] = adj[i];
  for (int i = tid; i < VV * 16; i += 256) {
    int u = i >> 4, f = i & 15;
    int f2 = f & ~1;
    float dv = expf(-logf(10000.f) * (float)f2 / 16.f);
    float ang = (float)u * dv;
    pes[i] = (f & 1) ? cosf(ang) : sinf(ang);
  }
  const int nq = wc * 4;
  for (int i = tid; i < VV * nq; i += 256) {
    int vv2 = i / nq, r = i - vv2 * nq;
    int wl = r >> 2, q = r & 3;
    float4 val = *(const float4*)(ao + ((size_t)(bb * VV + vv2) * WW + w0 + wl) * 16 + q * 4);
    *(float4*)&aos[vv2][wl * 16 + q * 4] = val;
  }
  __syncthreads();
  for (int i = tid; i < VV * nq; i += 256) {
    int u = i / nq, r = i - u * nq;
    int wl = r >> 2, q = r & 3;
    float a0 = 0.f, a1 = 0.f, a2 = 0.f, a3 = 0.f;
    for (int vv2 = 0; vv2 < VV; ++vv2) {
      float a = adjs[u * VV + vv2];
      float4 s = *(const float4*)&aos[vv2][wl * 16 + q * 4];
      a0 += a * s.x; a1 += a * s.y; a2 += a * s.z; a3 += a * s.w;
    }
    float4 o = make_float4(a0 + pes[u * 16 + q * 4],
                           a1 + pes[u * 16 + q * 4 + 1],
                           a2 + pes[u * 16 + q * 4 + 2],
                           a3 + pes[u * 16 + q * 4 + 3]);
    *(float4*)(msg2 + ((size_t)(bb * VV + u) * WW + w0 + wl) * 16 + q * 4) = o;
  }
}

/* ---------------- signal attention v6: one WAVE per window ----------------
   lane l = row l; A/p/q2/c0 via uniform s_loads; x_m via broadcast b128;
   row softmax in registers; LDS only for the colsum transpose. */
__global__ __launch_bounds__(256) void k_sa5(
    const float* __restrict__ msg2, const float* __restrict__ saw,
    const float* __restrict__ wvih, const float* __restrict__ bias2,
    float* __restrict__ xw1) {
  __shared__ __align__(16) float xs[4][VV * 20];   /* 80B rows */
  __shared__ float esc[4][VV * 35];                /* stride 35 */
  __shared__ float wsL[4][VV];
  __shared__ float csL[4][VV];
  __shared__ __align__(16) float ybL[4][16];
  const int tid = threadIdx.x;
  const int g = tid >> 6, lane = tid & 63;
  const int n = blockIdx.x * 4 + g;                /* grid 5888 exact */
  /* stage X for 4 windows, coalesced */
  {
    const float4* src = (const float4*)(msg2 + (size_t)blockIdx.x * 4 * 544);
    for (int i = tid; i < 544; i += 256) {
      int gg = i / 136, r = i - gg * 136;
      int m = r >> 2, q = r & 3;
      ((float4*)&xs[gg][m * 20])[q] = src[i];
    }
  }
  __syncthreads();
  /* phase B: z = A^T x_l (SGPR weights), u = p.x, w = q2.x */
  float z[16];
  float u = 0.f;
  if (lane < VV) {
    float x[16];
    const float4* xr = (const float4*)&xs[g][lane * 20];
    float4 a0 = xr[0], a1 = xr[1], a2 = xr[2], a3 = xr[3];
    x[0]=a0.x; x[1]=a0.y; x[2]=a0.z; x[3]=a0.w;
    x[4]=a1.x; x[5]=a1.y; x[6]=a1.z; x[7]=a1.w;
    x[8]=a2.x; x[9]=a2.y; x[10]=a2.z; x[11]=a2.w;
    x[12]=a3.x; x[13]=a3.y; x[14]=a3.z; x[15]=a3.w;
    #pragma unroll
    for (int j = 0; j < 16; ++j) {
      float acc = 0.f;
      #pragma unroll
      for (int i = 0; i < 16; ++i) acc += saw[j * 16 + i] * x[i];
      z[j] = acc;
    }
    float w = 0.f;
    #pragma unroll
    for (int i = 0; i < 16; ++i) { u += saw[256 + i] * x[i]; w += saw[272 + i] * x[i]; }
    wsL[g][lane] = w;
  }
  __syncthreads();
  /* phase C: scores via broadcast x_m, softmax in registers */
  if (lane < VV) {
    const float c0 = saw[288];
    float e[VV];
    #pragma unroll
    for (int m = 0; m < VV; ++m) {
      const float4* xm = (const float4*)&xs[g][m * 20];
      float4 b0 = xm[0], b1 = xm[1], b2 = xm[2], b3 = xm[3];
      float p0 = z[0]*b0.x + z[1]*b0.y + z[2]*b0.z + z[3]*b0.w;
      float p1 = z[4]*b1.x + z[5]*b1.y + z[6]*b1.z + z[7]*b1.w;
      float p2 = z[8]*b2.x + z[9]*b2.y + z[10]*b2.z + z[11]*b2.w;
      float p3 = z[12]*b3.x + z[13]*b3.y + z[14]*b3.z + z[15]*b3.w;
      e[m] = (((p0 + p1) + (p2 + p3)) + u + wsL[g][m] + c0) * 0.25f;
    }
    float mx = e[0];
    #pragma unroll
    for (int m = 1; m < VV; ++m) mx = fmaxf(mx, e[m]);
    float sum = 0.f;
    #pragma unroll
    for (int m = 0; m < VV; ++m) { e[m] = expf(e[m] - mx); sum += e[m]; }
    float rr = 1.f / sum;
    #pragma unroll
    for (int m = 0; m < VV; ++m) esc[g][lane * 35 + m] = e[m] * rr;
  }
  __syncthreads();
  /* colsum transpose: lane m sums column m */
  if (lane < VV) {
    float cs = 0.f;
    #pragma unroll
    for (int l = 0; l < VV; ++l) cs += esc[g][l * 35 + lane];
    csL[g][lane] = cs;
  }
  __syncthreads();
  /* y = cs . X */
  if (lane < 16) {
    float acc = 0.f;
    #pragma unroll
    for (int m = 0; m < VV; ++m) acc += csL[g][m] * xs[g][m * 20 + lane];
    ybL[g][lane] = acc;
  }
  __syncthreads();
  /* xw1 = y.Wvih + bias2, all 64 lanes, 3 outputs each */
  {
    const float4* yr = (const float4*)&ybL[g][0];
    float4 y0 = yr[0], y1 = yr[1], y2 = yr[2], y3 = yr[3];
    float yv[16];
    yv[0]=y0.x; yv[1]=y0.y; yv[2]=y0.z; yv[3]=y0.w;
    yv[4]=y1.x; yv[5]=y1.y; yv[6]=y1.z; yv[7]=y1.w;
    yv[8]=y2.x; yv[9]=y2.y; yv[10]=y2.z; yv[11]=y2.w;
    yv[12]=y3.x; yv[13]=y3.y; yv[14]=y3.z; yv[15]=y3.w;
    #pragma unroll
    for (int k = 0; k < 3; ++k) {
      int o = lane + k * 64;
      float acc = bias2[o];
      #pragma unroll
      for (int i = 0; i < 16; ++i) acc += yv[i] * wvih[i * 192 + o];
      xw1[(size_t)n * 192 + o] = acc;
    }
  }
}

/* ---------------- GRU: weights in 192 VGPRs, readlane h-broadcast, no LDS ---------------- */
#define RL(x,i) __uint_as_float(__builtin_amdgcn_readlane(__float_as_uint(x), (i)))
__global__ __launch_bounds__(64) void k_gru2(
    const float* __restrict__ xw, const float* __restrict__ Whh,
    const float* __restrict__ bhh, float* __restrict__ gout) {
  const int tid = threadIdx.x;
  const int b = blockIdx.x;
  float wr[64], wz[64], wn[64];
  #pragma unroll
  for (int i = 0; i < 64; ++i) {
    wr[i] = Whh[i * 192 + tid];
    wz[i] = Whh[i * 192 + 64 + tid];
    wn[i] = Whh[i * 192 + 128 + tid];
  }
  const float br = bhh[tid], bz = bhh[64 + tid], bn = bhh[128 + tid];
  float h = 0.f;
  const float* xr = xw + (size_t)b * WW * 192;
  for (int w = 0; w < WW; ++w, xr += 192) {
    float xrv = xr[tid], xzv = xr[64 + tid], xnv = xr[128 + tid];
    float pr0 = br, pr1 = 0.f, pr2 = 0.f, pr3 = 0.f;
    float pz0 = bz, pz1 = 0.f, pz2 = 0.f, pz3 = 0.f;
    float pn0 = bn, pn1 = 0.f, pn2 = 0.f, pn3 = 0.f;
    #pragma unroll
    for (int i = 0; i < 64; i += 4) {
      float h0 = RL(h, i), h1 = RL(h, i + 1), h2 = RL(h, i + 2), h3 = RL(h, i + 3);
      pr0 += h0 * wr[i];     pr1 += h1 * wr[i + 1];
      pr2 += h2 * wr[i + 2]; pr3 += h3 * wr[i + 3];
      pz0 += h0 * wz[i];     pz1 += h1 * wz[i + 1];
      pz2 += h2 * wz[i + 2]; pz3 += h3 * wz[i + 3];
      pn0 += h0 * wn[i];     pn1 += h1 * wn[i + 1];
      pn2 += h2 * wn[i + 2]; pn3 += h3 * wn[i + 3];
    }
    float ar = (pr0 + pr1) + (pr2 + pr3);
    float az = (pz0 + pz1) + (pz2 + pz3);
    float an = (pn0 + pn1) + (pn2 + pn3);
    float r = 1.f / (1.f + expf(-(xrv + ar)));
    float z = 1.f / (1.f + expf(-(xzv + az)));
    float n = tanhf(xnv + r * an);
    h = (1.f - z) * n + z * h;
    gout[((size_t)b * WW + w) * HH + tid] = h;
  }
}

/* ---------------- GRU layer-2 input projection ---------------- */
__global__ __launch_bounds__(192) void k_xw2(
    const float* __restrict__ x, const float* __restrict__ Wih,
    const float* __restrict__ bih, float* __restrict__ xw) {
  __shared__ float xsh[16][HH];
  int n0 = blockIdx.x * 16;
  int tid = threadIdx.x;
  for (int idx = tid; idx < 16 * HH; idx += 192) {
    int ns = idx >> 6, i = idx & 63;
    xsh[ns][i] = x[(size_t)(n0 + ns) * HH + i];
  }
  __syncthreads();
  float acc[16];
  float bb = bih[tid];
  #pragma unroll
  for (int ns = 0; ns < 16; ++ns) acc[ns] = bb;
  for (int i = 0; i < HH; ++i) {
    float wv = Wih[i * TH3 + tid];
    #pragma unroll
    for (int ns = 0; ns < 16; ++ns) acc[ns] += xsh[ns][i] * wv;
  }
  #pragma unroll
  for (int ns = 0; ns < 16; ++ns) xw[(size_t)(n0 + ns) * TH3 + tid] = acc[ns];
}

/* ---------------- temporal attention + classifier ---------------- */
__global__ __launch_bounds__(256) void k_ta(
    const float* __restrict__ g2,
    const float* __restrict__ Wq, const float* __restrict__ bq,
    const float* __restrict__ Wk, const float* __restrict__ bk,
    const float* __restrict__ Wv, const float* __restrict__ bv,
    const float* __restrict__ cW1, const float* __restrict__ cb1,
    const float* __restrict__ cW2, const float* __restrict__ cb2,
    float* __restrict__ out) {
  __shared__ float xt[WW * 65];
  __shared__ float QKVs[3][WW * 65];
  __shared__ float sc[WW * WW];
  __shared__ float cs[WW];
  __shared__ float tval[HH];
  __shared__ float hrelu[HH];
  int tid = threadIdx.x;
  int b = blockIdx.x;
  for (int idx = tid; idx < WW * HH; idx += 256) {
    int w = idx >> 6, d = idx & 63;
    int f2 = d & ~1;
    float dv = expf(-logf(10000.f) * (float)f2 / (float)HH);
    float ang = (float)w * dv;
    float pe = (d & 1) ? cosf(ang) : sinf(ang);
    xt[w * 65 + d] = g2[(size_t)(b * WW + w) * HH + d] + pe;
  }
  __syncthreads();
  if (tid < 192) {
    int which = tid >> 6, d = tid & 63;
    const float* Wt = which == 0 ? Wq : which == 1 ? Wk : Wv;
    float bias = (which == 0 ? bq : which == 1 ? bk : bv)[d];
    float col[HH];
    #pragma unroll
    for (int i = 0; i < HH; ++i) col[i] = Wt[i * HH + d];
    float* dst = &QKVs[which][0];
    for (int w = 0; w < WW; ++w) {
      float acc = bias;
      #pragma unroll
      for (int i = 0; i < HH; ++i) acc += xt[w * 65 + i] * col[i];
      dst[w * 65 + d] = acc;
    }
  }
  __syncthreads();
  for (int idx = tid; idx < WW * WW; idx += 256) {
    int l = idx / WW, m = idx - l * WW;
    float s = 0.f;
    #pragma unroll
    for (int i = 0; i < HH; ++i) s += QKVs[0][l * 65 + i] * QKVs[1][m * 65 + i];
    sc[idx] = s * 0.125f;
  }
  __syncthreads();
  if (tid < WW) {
    float mx = -1e30f;
    for (int m = 0; m < WW; ++m) mx = fmaxf(mx, sc[tid * WW + m]);
    float sum = 0.f;
    for (int m = 0; m < WW; ++m) { float e = expf(sc[tid * WW + m] - mx); sc[tid * WW + m] = e; sum += e; }
    float r = 1.f / sum;
    for (int m = 0; m < WW; ++m) sc[tid * WW + m] *= r;
  }
  __syncthreads();
  if (tid < WW) {
    float s = 0.f;
    for (int l = 0; l < WW; ++l) s += sc[l * WW + tid];
    cs[tid] = s;
  }
  __syncthreads();
  if (tid < HH) {
    float acc = 0.f;
    for (int m = 0; m < WW; ++m) acc += cs[m] * QKVs[2][m * 65 + tid];
    tval[tid] = acc;
  }
  __syncthreads();
  if (tid < HH) {
    float acc = cb1[tid];
    #pragma unroll
    for (int d = 0; d < HH; ++d) acc += tval[d] * cW1[d * HH + tid];
    hrelu[tid] = fmaxf(acc, 0.f);
  }
  __syncthreads();
  if (tid == 0) {
    float acc = cb2[0];
    for (int j = 0; j < HH; ++j) acc += hrelu[j] * cW2[j];
    out[b] = acc;
  }
}

extern "C" void kernel_launch(void* const* d_in, const int* in_sizes, int n_in,
                              void* d_out, int out_size, void* d_ws, size_t ws_size,
                              hipStream_t stream) {
  (void)in_sizes; (void)n_in; (void)out_size; (void)ws_size;
  const float* arr    = (const float*)d_in[0];
  const float* msk    = (const float*)d_in[1];
  const float* timeTB = (const float*)d_in[2];
  const float* wdec   = (const float*)d_in[3];
  const float* bdec   = (const float*)d_in[4];
  const float* encW1  = (const float*)d_in[5];
  const float* encB1  = (const float*)d_in[6];
  const float* encW2  = (const float*)d_in[7];
  const float* encB2  = (const float*)d_in[8];
  const float* tlaWq  = (const float*)d_in[9];
  const float* tlaBq  = (const float*)d_in[10];
  const float* tlaWk  = (const float*)d_in[11];
  const float* tlaBk  = (const float*)d_in[12];
  const float* tlaWv  = (const float*)d_in[13];
  const float* tlaBv  = (const float*)d_in[14];
  const float* adj    = (const float*)d_in[15];
  const float* saWq   = (const float*)d_in[20];
  const float* saBq   = (const float*)d_in[21];
  const float* saWk   = (const float*)d_in[22];
  const float* saBk   = (const float*)d_in[23];
  const float* saWv   = (const float*)d_in[24];
  const float* saBv   = (const float*)d_in[25];
  const float* gWih0  = (const float*)d_in[26];
  const float* gWhh0  = (const float*)d_in[27];
  const float* gBih0  = (const float*)d_in[28];
  const float* gBhh0  = (const float*)d_in[29];
  const float* gWih1  = (const float*)d_in[30];
  const float* gWhh1  = (const float*)d_in[31];
  const float* gBih1  = (const float*)d_in[32];
  const float* gBhh1  = (const float*)d_in[33];
  const float* taWq   = (const float*)d_in[34];
  const float* taBq   = (const float*)d_in[35];
  const float* taWk   = (const float*)d_in[36];
  const float* taBk   = (const float*)d_in[37];
  const float* taWv   = (const float*)d_in[38];
  const float* taBv   = (const float*)d_in[39];
  const float* cW1    = (const float*)d_in[40];
  const float* cb1    = (const float*)d_in[41];
  const float* cW2    = (const float*)d_in[42];
  const float* cb2    = (const float*)d_in[43];
  float* out = (float*)d_out;
  float* ws  = (float*)d_ws;

  float* ao    = ws + AO_OFF;
  float* msg2  = ws + MSG2_OFF;
  float* cum   = ws + CUM2_OFF;
  float* last  = ws + LAST2_OFF;
  float* means = ws + MEANS2_OFF;
  unsigned int* maxv = (unsigned int*)(ws + MAX2_OFF);
  float* pqg   = ws + PQ_OFF;
  float* saw   = ws + SAW_OFF;
  float* fw    = ws + FW_OFF;
  float* wvih  = ws + WVIH_OFF;
  float* bias2 = ws + BIAS2_OFF;

  float* xw1  = ws + XW1_OFF;
  float* g1   = ws + G1_OFF;
  float* xw2  = ws + XW2_OFF;
  float* g2   = ws + G2_OFF;

  hipMemsetAsync(maxv, 0, sizeof(unsigned int), stream);
  k_scan<<<68, 256, 0, stream>>>(arr, msk, timeTB, cum, last, means, maxv);
  k_prep<<<74, 256, 0, stream>>>(tlaWq, tlaWk, tlaWv, tlaBq, tlaBk, tlaBv,
                                 saWq, saBq, saWk, saBk, saWv, saBv,
                                 encW2, encB2, gWih0, gBih0,
                                 pqg, saw, fw, wvih, bias2);
  k_enc4<<<VV * 128, 256, 0, stream>>>(arr, msk, cum, last, means, maxv,
                                       wdec, bdec, encW1, encB1, fw, pqg, ao);
  k_mp<<<BB * 4, 256, 0, stream>>>(ao, adj, msg2);
  k_sa5<<<BW / 4, 256, 0, stream>>>(msg2, saw, wvih, bias2, xw1);
  k_gru2<<<BB, 64, 0, stream>>>(xw1, gWhh0, gBhh0, g1);
  k_xw2<<<BW / 16, 192, 0, stream>>>(g1, gWih1, gBih1, xw2);
  k_gru2<<<BB, 64, 0, stream>>>(xw2, gWhh1, gBhh1, g2);
  k_ta<<<BB, 256, 0, stream>>>(g2, taWq, taBq, taWk, taBk, taWv, taBv,
                               cW1, cb1, cW2, cb2, out);
}